// Round 3
// baseline (466.800 us; speedup 1.0000x reference)
//
#include <hip/hip_runtime.h>
#include <stdint.h>
#include <stddef.h>

// ---------------------------------------------------------------------------
// Fully fake-quantized transformer block on MI355X (gfx950).
// i8 MFMA GEMMs (exact i32 acc), flash-style fused attention.
// R10: gemm_i8 counted-vmcnt depth-2 pipeline (T3/T4-lite). The N=1024 GEMMs
// run at grid 256 = 1 block/CU; __syncthreads' vmcnt(0) drain exposed ~700
// cycles of HBM latency per k-step (W2 GEMM: 52us for 2.2us of MFMA). Now:
// 3 LDS buffers, prefetch 2 tiles ahead, s_waitcnt vmcnt(4) + raw s_barrier
// per iter (drain only at the last tile). Bit-identical math.
// R9 (kept): attn block=(b,h,pair,rowhalf), swapped QK^T, register P-transpose.
// ---------------------------------------------------------------------------

typedef unsigned short u16;
typedef __attribute__((ext_vector_type(4))) int   i32x4;
typedef __attribute__((ext_vector_type(4))) float f32x4;

#define DEV __device__ __forceinline__

DEV float bf2f(u16 u) { return __uint_as_float(((unsigned)u) << 16); }
DEV void atomicMaxF(float* p, float v) { atomicMax((unsigned*)p, __float_as_uint(v)); }
DEV float waveMax(float v) {
#pragma unroll
  for (int o = 32; o; o >>= 1) v = fmaxf(v, __shfl_xor(v, o, 64));
  return v;
}
DEV float waveSum(float v) {
#pragma unroll
  for (int o = 32; o; o >>= 1) v += __shfl_xor(v, o, 64);
  return v;
}
DEV int waveSumI(int v) {
#pragma unroll
  for (int o = 32; o; o >>= 1) v += __shfl_xor(v, o, 64);
  return v;
}
DEV void blockStatMax(float v, float* __restrict__ slot64, float* sred4, int flatBlk) {
  v = waveMax(v);
  const int tid = threadIdx.x;
  if ((tid & 63) == 0) sred4[tid >> 6] = v;
  __syncthreads();
  if (tid == 0) {
    float m = fmaxf(fmaxf(sred4[0], sred4[1]), fmaxf(sred4[2], sred4[3]));
    atomicMaxF(&slot64[flatBlk & 63], m);
  }
}
DEV float slotMax64(const float* __restrict__ s) {
  float m = 0.f;
#pragma unroll
  for (int i = 0; i < 64; ++i) m = fmaxf(m, s[i]);
  return m;
}
DEV f32x4 ld4(const void* p, int i4, int isf32) {
  if (isf32) return ((const f32x4*)p)[i4];
  ushort4 u = ((const ushort4*)p)[i4];
  return (f32x4){bf2f(u.x), bf2f(u.y), bf2f(u.z), bf2f(u.w)};
}
DEV void gll16(const void* g, void* l) {
  __builtin_amdgcn_global_load_lds((__attribute__((address_space(1))) void*)(g),
                                   (__attribute__((address_space(3))) void*)(l),
                                   16, 0, 0);
}
DEV unsigned quadsel(unsigned a, unsigned b, unsigned c, unsigned d, int idx) {
  unsigned lo = (idx & 1) ? b : a;
  unsigned hi = (idx & 1) ? d : c;
  return (idx & 2) ? hi : lo;
}

__global__ void detect_f32(const u16* __restrict__ x, int* __restrict__ flag) {
  const int tid = threadIdx.x;
  int cnt = 0;
#pragma unroll
  for (int i = 0; i < 16; ++i) {
    u16 u = x[tid * 16 + i];
    if ((u & 0x7f80u) >= 0x4380u) ++cnt;
  }
  cnt = waveSumI(cnt);
  if (tid == 0) flag[0] = (cnt > 16) ? 1 : 0;
}

struct AJobs { const void* p[13]; int n4[13]; int bstart[14]; };

__global__ __launch_bounds__(256) void absmax_multi(AJobs J, float* __restrict__ M,
                                                    const int* __restrict__ flagp) {
  __shared__ float sred[4];
  const int isf32 = flagp[0];
  const int blk = blockIdx.x, tid = threadIdx.x;
  int j = 0;
  while (j < 12 && blk >= J.bstart[j + 1]) ++j;
  const int lb = blk - J.bstart[j];
  const int nb = J.bstart[j + 1] - J.bstart[j];
  float mx = 0.f;
  const void* p = J.p[j];
  for (int i = lb * 256 + tid; i < J.n4[j]; i += nb * 256) {
    f32x4 v = ld4(p, i, isf32);
    mx = fmaxf(mx, fmaxf(fmaxf(fabsf(v.x), fabsf(v.y)),
                         fmaxf(fabsf(v.z), fabsf(v.w))));
  }
  blockStatMax(mx, M + j * 64, sred, lb);
}

__global__ __launch_bounds__(256) void quant_in_signed(
    const void* __restrict__ in, int8_t* __restrict__ out,
    const float* __restrict__ mp, const int* __restrict__ flagp, int n4) {
  const int isf32 = flagp[0];
  const float s = fmaxf(slotMax64(mp), 1e-8f) / 127.0f;
  char4* op = (char4*)out;
  for (int i = blockIdx.x * 256 + threadIdx.x; i < n4; i += gridDim.x * 256) {
    f32x4 v = ld4(in, i, isf32);
    char4 q;
    q.x = (signed char)fminf(fmaxf(rintf(v.x / s), -128.f), 127.f);
    q.y = (signed char)fminf(fmaxf(rintf(v.y / s), -128.f), 127.f);
    q.z = (signed char)fminf(fmaxf(rintf(v.z / s), -128.f), 127.f);
    q.w = (signed char)fminf(fmaxf(rintf(v.w / s), -128.f), 127.f);
    op[i] = q;
  }
}

struct WJobs { const void* in[5]; int8_t* out[5]; int mslot[5]; int n4[5]; int bstart[6]; };

__global__ __launch_bounds__(256) void quant_w_multi(WJobs J, const float* __restrict__ M,
                                                     const int* __restrict__ flagp) {
  const int isf32 = flagp[0];
  const int blk = blockIdx.x, tid = threadIdx.x;
  int j = 0;
  while (j < 4 && blk >= J.bstart[j + 1]) ++j;
  const int lb = blk - J.bstart[j];
  const int nb = J.bstart[j + 1] - J.bstart[j];
  const float s = fmaxf(slotMax64(M + J.mslot[j] * 64), 1e-8f) / 127.0f;
  const void* p = J.in[j];
  char4* o = (char4*)J.out[j];
  for (int i = lb * 256 + tid; i < J.n4[j]; i += nb * 256) {
    f32x4 v = ld4(p, i, isf32);
    char4 q;
    q.x = (signed char)fminf(fmaxf(rintf(v.x / s), -127.f), 127.f);
    q.y = (signed char)fminf(fmaxf(rintf(v.y / s), -127.f), 127.f);
    q.z = (signed char)fminf(fmaxf(rintf(v.z / s), -127.f), 127.f);
    q.w = (signed char)fminf(fmaxf(rintf(v.w / s), -127.f), 127.f);
    o[i] = q;
  }
}

__global__ __launch_bounds__(256) void quant_w2_rs(
    const void* __restrict__ w2, int8_t* __restrict__ out,
    const float* __restrict__ mp, const int* __restrict__ flagp,
    int* __restrict__ rowsum) {
  const int isf32 = flagp[0];
  const int row = blockIdx.x, tid = threadIdx.x;
  const float s = fmaxf(slotMax64(mp), 1e-8f) / 127.0f;
  char4* op = (char4*)(out + (size_t)row * 4096);
  int sum = 0;
  for (int i = tid; i < 1024; i += 256) {
    f32x4 v = ld4(w2, row * 1024 + i, isf32);
    char4 q;
    q.x = (signed char)fminf(fmaxf(rintf(v.x / s), -127.f), 127.f);
    q.y = (signed char)fminf(fmaxf(rintf(v.y / s), -127.f), 127.f);
    q.z = (signed char)fminf(fmaxf(rintf(v.z / s), -127.f), 127.f);
    q.w = (signed char)fminf(fmaxf(rintf(v.w / s), -127.f), 127.f);
    op[i] = q;
    sum += (int)q.x + (int)q.y + (int)q.z + (int)q.w;
  }
  sum = waveSumI(sum);
  __shared__ int rs4[4];
  if ((tid & 63) == 0) rs4[tid >> 6] = sum;
  __syncthreads();
  if (tid == 0) rowsum[row] = rs4[0] + rs4[1] + rs4[2] + rs4[3];
}

struct BJobs { const void* in[6]; float* out[6]; int mslot[6]; int n4[6]; };

__global__ __launch_bounds__(256) void fq_bias_multi(BJobs J, const float* __restrict__ M,
                                                     const int* __restrict__ flagp) {
  const int isf32 = flagp[0];
  const int j = blockIdx.x;
  const float s = fmaxf(slotMax64(M + J.mslot[j] * 64), 1e-8f) / 127.0f;
  float* o = J.out[j];
  for (int i = threadIdx.x; i < J.n4[j]; i += 256) {
    f32x4 v = ld4(J.in[j], i, isf32);
    f32x4 r;
    r.x = fminf(fmaxf(rintf(v.x / s), -128.f), 127.f) * s;
    r.y = fminf(fmaxf(rintf(v.y / s), -128.f), 127.f) * s;
    r.z = fminf(fmaxf(rintf(v.z / s), -128.f), 127.f) * s;
    r.w = fminf(fmaxf(rintf(v.w / s), -128.f), 127.f) * s;
    *(f32x4*)(o + i * 4) = r;
  }
}

__global__ __launch_bounds__(256) void quant_f32_signed(
    const float* __restrict__ in, int8_t* __restrict__ out,
    const float* __restrict__ mp, float pre, int n4) {
  const float s = fmaxf(slotMax64(mp) * pre, 1e-8f) / 127.0f;
  const f32x4* ip = (const f32x4*)in;
  char4* op = (char4*)out;
  for (int i = blockIdx.x * 256 + threadIdx.x; i < n4; i += gridDim.x * 256) {
    f32x4 v = ip[i];
    char4 q;
    q.x = (signed char)fminf(fmaxf(rintf(v.x * pre / s), -128.f), 127.f);
    q.y = (signed char)fminf(fmaxf(rintf(v.y * pre / s), -128.f), 127.f);
    q.z = (signed char)fminf(fmaxf(rintf(v.z * pre / s), -128.f), 127.f);
    q.w = (signed char)fminf(fmaxf(rintf(v.w * pre / s), -128.f), 127.f);
    op[i] = q;
  }
}

__global__ __launch_bounds__(256) void quant_v_t(
    const float* __restrict__ V, int8_t* __restrict__ Vt,
    const float* __restrict__ mp) {
  __shared__ float tile[64][65];
  const int bh = blockIdx.x, st = blockIdx.y;
  const int b = bh >> 4, h = bh & 15;
  const int tid = threadIdx.x;
  const float s = fmaxf(slotMax64(mp), 1e-8f) / 127.0f;
  const int r = tid >> 2, c = (tid & 3) * 16;
  const float* src = V + ((size_t)(b * 1024 + st * 64 + r)) * 1024 + h * 64 + c;
#pragma unroll
  for (int g = 0; g < 4; ++g) {
    f32x4 v = *(const f32x4*)(src + g * 4);
    tile[r][c + g * 4 + 0] = v.x;
    tile[r][c + g * 4 + 1] = v.y;
    tile[r][c + g * 4 + 2] = v.z;
    tile[r][c + g * 4 + 3] = v.w;
  }
  __syncthreads();
  unsigned wds[4];
#pragma unroll
  for (int g = 0; g < 4; ++g) {
    unsigned wd = 0;
#pragma unroll
    for (int k = 0; k < 4; ++k) {
      float v = tile[c + g * 4 + k][r];
      int q = (int)fminf(fmaxf(rintf(v / s), -128.f), 127.f);
      wd |= ((unsigned)(unsigned char)(signed char)q) << (8 * k);
    }
    wds[g] = wd;
  }
  i32x4 ov = {(int)wds[0], (int)wds[1], (int)wds[2], (int)wds[3]};
  *(i32x4*)(Vt + ((size_t)((b * 16 + h) * 64 + r)) * 1024 + st * 64 + c) = ov;
}

// ------------------- int8 GEMM (counted-vmcnt depth-2 pipeline) --------------
// mode 0: store f32 Cf, stat->mOut ; mode 1: stats only ; mode 2: requant u8-128
// 3 LDS buffers, prefetch 2 k-tiles ahead; per-iter s_waitcnt vmcnt(4) + raw
// s_barrier keeps the NEXT tile's 4 loads in flight across the barrier.
// Safety: tile k+2 overwrites buf[(k-1)%3]; all waves' reads of tile k-1
// (their MFMAs consumed the ds_reads) complete before the iter-k barrier.
__global__ __launch_bounds__(256) void gemm_i8(
    const int8_t* __restrict__ A, const int8_t* __restrict__ B,
    float* __restrict__ Cf, int8_t* __restrict__ Cq,
    const float* __restrict__ mA, float preA, float qmaxA,
    const float* __restrict__ mB,
    const float* __restrict__ bias, const int* __restrict__ extra,
    int relu, int mode, float* __restrict__ mOut, int K, int O) {
  __shared__ __align__(16) int8_t At[3][8192];
  __shared__ __align__(16) int8_t Bt[3][8192];
  __shared__ float sred[4];
  const int tid = threadIdx.x;
  const int nb = blockIdx.x, ob = blockIdx.y;
  const int w = tid >> 6, lane = tid & 63, l15 = lane & 15, quad = lane >> 4;
  const int wr = w >> 1, wc = w & 1;
  i32x4 acc[4][4];
#pragma unroll
  for (int i = 0; i < 4; ++i)
#pragma unroll
    for (int j = 0; j < 4; ++j) acc[i][j] = (i32x4){0, 0, 0, 0};
  const int r0 = tid >> 2, c0 = (tid & 3) * 16;
  const int8_t* Ab = A + (size_t)(nb * 128) * K;
  const int8_t* Bb = B + (size_t)(ob * 128) * K;
  const int nk = K >> 6;
  // prologue: stage tiles 0 and 1
  gll16(Ab + (size_t)r0 * K + c0, At[0] + tid * 16);
  gll16(Ab + (size_t)(r0 + 64) * K + c0, At[0] + 4096 + tid * 16);
  gll16(Bb + (size_t)r0 * K + c0, Bt[0] + tid * 16);
  gll16(Bb + (size_t)(r0 + 64) * K + c0, Bt[0] + 4096 + tid * 16);
  if (nk > 1) {
    gll16(Ab + (size_t)r0 * K + 64 + c0, At[1] + tid * 16);
    gll16(Ab + (size_t)(r0 + 64) * K + 64 + c0, At[1] + 4096 + tid * 16);
    gll16(Bb + (size_t)r0 * K + 64 + c0, Bt[1] + tid * 16);
    gll16(Bb + (size_t)(r0 + 64) * K + 64 + c0, Bt[1] + 4096 + tid * 16);
  }
  int cb = 0, ib = 2;
  for (int i = 0; i < nk; ++i) {
    // wait for tile i's 4 loads only; tile i+1's stay in flight
    if (i + 1 < nk) asm volatile("s_waitcnt vmcnt(4)" ::: "memory");
    else            asm volatile("s_waitcnt vmcnt(0)" ::: "memory");
    asm volatile("s_barrier" ::: "memory");
    if (i + 2 < nk) {
      const size_t kt = (size_t)(i + 2) << 6;
      gll16(Ab + (size_t)r0 * K + kt + c0, At[ib] + tid * 16);
      gll16(Ab + (size_t)(r0 + 64) * K + kt + c0, At[ib] + 4096 + tid * 16);
      gll16(Bb + (size_t)r0 * K + kt + c0, Bt[ib] + tid * 16);
      gll16(Bb + (size_t)(r0 + 64) * K + kt + c0, Bt[ib] + 4096 + tid * 16);
      ib = (ib == 2) ? 0 : ib + 1;
    }
    const int8_t* Ac = At[cb];
    const int8_t* Bc = Bt[cb];
    cb = (cb == 2) ? 0 : cb + 1;
    i32x4 af[4], bf[4];
#pragma unroll
    for (int mt = 0; mt < 4; ++mt)
      af[mt] = *(const i32x4*)(Ac + (wr * 64 + mt * 16 + l15) * 64 + quad * 16);
#pragma unroll
    for (int nt = 0; nt < 4; ++nt)
      bf[nt] = *(const i32x4*)(Bc + (wc * 64 + nt * 16 + l15) * 64 + quad * 16);
#pragma unroll
    for (int mt = 0; mt < 4; ++mt)
#pragma unroll
      for (int nt = 0; nt < 4; ++nt)
        acc[mt][nt] = __builtin_amdgcn_mfma_i32_16x16x64_i8(af[mt], bf[nt], acc[mt][nt], 0, 0, 0);
  }
  const float sA = fmaxf(slotMax64(mA) * preA, 1e-8f) / qmaxA;
  const float sB = fmaxf(slotMax64(mB), 1e-8f) / 127.0f;
  const float sAB = sA * sB;
  const float sq = (mode == 2) ? (fmaxf(slotMax64(mOut), 1e-8f) / 255.0f) : 1.0f;
  float lmax = 0.f;
#pragma unroll
  for (int mt = 0; mt < 4; ++mt) {
    const int n = nb * 128 + wr * 64 + mt * 16 + quad * 4;
#pragma unroll
    for (int nt = 0; nt < 4; ++nt) {
      const int o = ob * 128 + wc * 64 + nt * 16 + l15;
      const int ext = extra ? 128 * extra[o] : 0;
      const float bv = bias[o];
#pragma unroll
      for (int r = 0; r < 4; ++r) {
        float v = sAB * (float)(acc[mt][nt][r] + ext) + bv;
        if (relu) v = fmaxf(v, 0.f);
        if (mode == 0) Cf[(size_t)(n + r) * O + o] = v;
        else if (mode == 2) {
          int q = (int)fminf(fmaxf(rintf(v / sq), 0.f), 255.f) - 128;
          Cq[(size_t)(n + r) * O + o] = (int8_t)q;
        }
        lmax = fmaxf(lmax, fabsf(v));
      }
    }
  }
  if (mode != 2)
    blockStatMax(lmax, mOut, sred, nb + ob * gridDim.x);
}

// --------------------------- fused causal attention --------------------------
// R9: grid 1024 = (b, h, pair p, rowhalf). Waves 0-1: hi tile (qt=15-p) rows
// rh*32+{0,16}; waves 2-3: lo tile (qt=p), same rows. Shared K/V staging over
// kt=0..15-p (lo range is a subset). Swapped QK^T -> lane-local softmax row,
// register quad-transpose of quantized P (no ptile LDS).
__global__ __launch_bounds__(256, 4) void attn_fused(
    const int8_t* __restrict__ Qq, const int8_t* __restrict__ Kq,
    const int8_t* __restrict__ Vt, float* __restrict__ ctx,
    const float* __restrict__ M, float* __restrict__ mOut) {
  __shared__ __align__(16) int8_t qtile[4096];
  __shared__ __align__(16) int8_t ktile[2][4096];
  __shared__ __align__(16) int8_t vtile[2][4096];
  __shared__ float sred[4];
  const int tid = threadIdx.x, bid = blockIdx.x;
  const int pidx = bid & 7, rh = (bid >> 3) & 1, h = (bid >> 4) & 15, b = bid >> 8;
  const int qthi = 15 - pidx, qtlo = pidx, ktmax = qthi;
  const int w = tid >> 6, lane = tid & 63, l15 = lane & 15, quad = lane >> 4;
  const int wqt = (w < 2) ? qthi : qtlo;
  const int wrow0 = rh * 32 + (w & 1) * 16;
  const float sqs = fmaxf(slotMax64(M + 13 * 64) * 0.125f, 1e-8f) / 127.0f;
  const float sk = fmaxf(slotMax64(M + 14 * 64), 1e-8f) / 127.0f;
  const float sv = fmaxf(slotMax64(M + 15 * 64), 1e-8f) / 127.0f;
  const float sqk = sqs * sk;
  const float s_attn = 1.0f / 127.0f;  // softmax global max == 1.0 exactly
  const int r0 = tid >> 2, c0 = (tid & 3) * 16;
  const int8_t* Kbase = Kq + (size_t)(b * 1024) * 1024 + h * 64 + c0;
  const int8_t* Vbase = Vt + (size_t)((b * 16 + h) * 64 + r0) * 1024 + c0;

  // stage Q: staging rows 0..31 -> hi tile rows rh*32+(0..31); 32..63 -> lo
  {
    const int qt_s = (r0 < 32) ? qthi : qtlo;
    const int qrow_g = qt_s * 64 + rh * 32 + (r0 & 31);
    gll16(Qq + ((size_t)(b * 1024 + qrow_g)) * 1024 + h * 64 + c0, qtile + tid * 16);
  }
  gll16(Kbase + (size_t)r0 * 1024, ktile[0] + tid * 16);
  __syncthreads();
  const i32x4 aq = *(const i32x4*)(qtile + (w * 16 + l15) * 64 + quad * 16);
  const int qrow = wqt * 64 + wrow0 + l15;  // this lane's q-row (0..1023)

  // ---- Phase A: swapped QK^T; per-lane online (m,l) over 16 kcols per kt ----
  float m_l = -1e30f, l_l = 0.f;
  for (int kt = 0; kt <= ktmax; ++kt) {
    if (kt) __syncthreads();
    if (kt < ktmax)
      gll16(Kbase + (size_t)((kt + 1) * 64 + r0) * 1024, ktile[(kt + 1) & 1] + tid * 16);
    if (kt <= wqt) {
      const int8_t* kc = ktile[kt & 1];
      const int kc0 = kt * 64 + quad * 4;
      float sc[4][4];
#pragma unroll
      for (int nt = 0; nt < 4; ++nt) {
        i32x4 z = {0, 0, 0, 0};
        i32x4 bk = *(const i32x4*)(kc + (nt * 16 + l15) * 64 + quad * 16);
        i32x4 d = __builtin_amdgcn_mfma_i32_16x16x64_i8(bk, aq, z, 0, 0, 0);
        if (kt == wqt) {
#pragma unroll
          for (int r = 0; r < 4; ++r)
            sc[nt][r] = (kc0 + nt * 16 + r <= qrow) ? sqk * (float)d[r] : -1e30f;
        } else {
#pragma unroll
          for (int r = 0; r < 4; ++r) sc[nt][r] = sqk * (float)d[r];
        }
      }
      float vm = sc[0][0];
#pragma unroll
      for (int nt = 0; nt < 4; ++nt)
#pragma unroll
        for (int r = 0; r < 4; ++r) vm = fmaxf(vm, sc[nt][r]);
      const float mn = fmaxf(m_l, vm);
      float sum = 0.f;
#pragma unroll
      for (int nt = 0; nt < 4; ++nt)
#pragma unroll
        for (int r = 0; r < 4; ++r) sum += __expf(sc[nt][r] - mn);
      l_l = l_l * __expf(m_l - mn) + sum;
      m_l = mn;
    }
  }
  // merge the 4 quads (lanes sharing l15 hold the same q-row)
#pragma unroll
  for (int off = 16; off <= 32; off <<= 1) {
    float om = __shfl_xor(m_l, off, 64);
    float ol = __shfl_xor(l_l, off, 64);
    float mn = fmaxf(m_l, om);
    l_l = l_l * __expf(m_l - mn) + ol * __expf(om - mn);
    m_l = mn;
  }
  const float rl127 = 127.0f / l_l;  // P*127 in [0,127] exactly -> no clamps

  // ---- Phase B: recompute, quantize P in-register, quad-transpose, PV ----
  __syncthreads();
  gll16(Kbase + (size_t)r0 * 1024, ktile[0] + tid * 16);
  gll16(Vbase, vtile[0] + tid * 16);
  i32x4 cacc[4] = {{0, 0, 0, 0}, {0, 0, 0, 0}, {0, 0, 0, 0}, {0, 0, 0, 0}};
  for (int kt = 0; kt <= ktmax; ++kt) {
    __syncthreads();
    if (kt < ktmax) {
      gll16(Kbase + (size_t)((kt + 1) * 64 + r0) * 1024, ktile[(kt + 1) & 1] + tid * 16);
      gll16(Vbase + (kt + 1) * 64, vtile[(kt + 1) & 1] + tid * 16);
    }
    if (kt <= wqt) {
      const int8_t* kc = ktile[kt & 1];
      const int kc0 = kt * 64 + quad * 4;
      unsigned Dw[4];
#pragma unroll
      for (int nt = 0; nt < 4; ++nt) {
        i32x4 z = {0, 0, 0, 0};
        i32x4 bk = *(const i32x4*)(kc + (nt * 16 + l15) * 64 + quad * 16);
        i32x4 d = __builtin_amdgcn_mfma_i32_16x16x64_i8(bk, aq, z, 0, 0, 0);
        unsigned wd = 0;
        if (kt == wqt) {
#pragma unroll
          for (int r = 0; r < 4; ++r) {
            float e = (kc0 + nt * 16 + r <= qrow)
                          ? __expf(sqk * (float)d[r] - m_l) * rl127 : 0.f;
            wd |= ((unsigned)(int)rintf(e)) << (8 * r);
          }
        } else {
#pragma unroll
          for (int r = 0; r < 4; ++r) {
            float e = __expf(sqk * (float)d[r] - m_l) * rl127;
            wd |= ((unsigned)(int)rintf(e)) << (8 * r);
          }
        }
        Dw[nt] = wd;
      }
      // 4x4 quad-transpose: pf[j] (k=quad*16+4j..) <- Dw[quad] @ lane quad'=j
      unsigned selfv = quadsel(Dw[0], Dw[1], Dw[2], Dw[3], quad);
      unsigned rv1 = (unsigned)__shfl_xor(
          (int)quadsel(Dw[0], Dw[1], Dw[2], Dw[3], quad ^ 1), 16, 64);
      unsigned rv2 = (unsigned)__shfl_xor(
          (int)quadsel(Dw[0], Dw[1], Dw[2], Dw[3], quad ^ 2), 32, 64);
      unsigned rv3 = (unsigned)__shfl_xor(
          (int)quadsel(Dw[0], Dw[1], Dw[2], Dw[3], quad ^ 3), 48, 64);
      i32x4 pf;
#pragma unroll
      for (int j = 0; j < 4; ++j) {
        const int t = j ^ quad;
        pf[j] = (int)((t == 0) ? selfv : (t == 1) ? rv1 : (t == 2) ? rv2 : rv3);
      }
      const int8_t* vc = vtile[kt & 1];
#pragma unroll
      for (int nt = 0; nt < 4; ++nt) {
        i32x4 bv = *(const i32x4*)(vc + (nt * 16 + l15) * 64 + quad * 16);
        cacc[nt] = __builtin_amdgcn_mfma_i32_16x16x64_i8(pf, bv, cacc[nt], 0, 0, 0);
      }
    }
  }
  const float sc2 = s_attn * sv;
  float lmax = 0.f;
  const int orow0 = wqt * 64 + wrow0 + quad * 4;
#pragma unroll
  for (int nt = 0; nt < 4; ++nt) {
    const int d = nt * 16 + l15;
#pragma unroll
    for (int r = 0; r < 4; ++r) {
      float v = sc2 * (float)cacc[nt][r];
      ctx[((size_t)(b * 1024 + orow0 + r)) * 1024 + h * 64 + d] = v;
      lmax = fmaxf(lmax, fabsf(v));
    }
  }
  blockStatMax(lmax, mOut, sred, bid);
}

// --------------------------- residual + layernorm ---------------------------
__global__ __launch_bounds__(256) void ln_res(
    const int8_t* __restrict__ xq, const float* __restrict__ mx,
    const float* __restrict__ ao, const float* __restrict__ ma,
    float* __restrict__ x1, float* __restrict__ mOut) {
  __shared__ float red[8];
  __shared__ float sred[4];
  const int row = blockIdx.x, tid = threadIdx.x;
  const float sx = fmaxf(slotMax64(mx), 1e-8f) / 127.0f;
  const float sa = fmaxf(slotMax64(ma), 1e-8f) / 127.0f;
  char4 xv = *(const char4*)(xq + (size_t)row * 1024 + tid * 4);
  f32x4 av = *(const f32x4*)(ao + (size_t)row * 1024 + tid * 4);
  float t[4];
  t[0] = (float)xv.x * sx + fminf(fmaxf(rintf(av.x / sa), -128.f), 127.f) * sa;
  t[1] = (float)xv.y * sx + fminf(fmaxf(rintf(av.y / sa), -128.f), 127.f) * sa;
  t[2] = (float)xv.z * sx + fminf(fmaxf(rintf(av.z / sa), -128.f), 127.f) * sa;
  t[3] = (float)xv.w * sx + fminf(fmaxf(rintf(av.w / sa), -128.f), 127.f) * sa;
  float s = waveSum(t[0] + t[1] + t[2] + t[3]);
  if ((tid & 63) == 0) red[tid >> 6] = s;
  __syncthreads();
  const float mean = (red[0] + red[1] + red[2] + red[3]) * (1.0f / 1024.0f);
  float vs = 0.f;
#pragma unroll
  for (int i = 0; i < 4; ++i) { float d = t[i] - mean; vs += d * d; }
  vs = waveSum(vs);
  if ((tid & 63) == 0) red[4 + (tid >> 6)] = vs;
  __syncthreads();
  const float var = (red[4] + red[5] + red[6] + red[7]) * (1.0f / 1024.0f);
  const float rs = sqrtf(var + 1e-5f);
  f32x4 o;
  o.x = (t[0] - mean) / rs;
  o.y = (t[1] - mean) / rs;
  o.z = (t[2] - mean) / rs;
  o.w = (t[3] - mean) / rs;
  *(f32x4*)(x1 + (size_t)row * 1024 + tid * 4) = o;
  float lmax = fmaxf(fmaxf(fabsf(o.x), fabsf(o.y)), fmaxf(fabsf(o.z), fabsf(o.w)));
  blockStatMax(lmax, mOut, sred, row);
}

__global__ __launch_bounds__(256) void ln_final(
    const int8_t* __restrict__ x1q, const float* __restrict__ mx1,
    const float* __restrict__ h2, const float* __restrict__ mh2,
    float* __restrict__ out) {
  __shared__ float red[8];
  const int row = blockIdx.x, tid = threadIdx.x;
  const float s1 = fmaxf(slotMax64(mx1), 1e-8f) / 127.0f;
  const float s2 = fmaxf(slotMax64(mh2), 1e-8f) / 127.0f;
  char4 xv = *(const char4*)(x1q + (size_t)row * 1024 + tid * 4);
  f32x4 hv = *(const f32x4*)(h2 + (size_t)row * 1024 + tid * 4);
  float t[4];
  t[0] = (float)xv.x * s1 + fminf(fmaxf(rintf(hv.x / s2), -128.f), 127.f) * s2;
  t[1] = (float)xv.y * s1 + fminf(fmaxf(rintf(hv.y / s2), -128.f), 127.f) * s2;
  t[2] = (float)xv.z * s1 + fminf(fmaxf(rintf(hv.z / s2), -128.f), 127.f) * s2;
  t[3] = (float)xv.w * s1 + fminf(fmaxf(rintf(hv.w / s2), -128.f), 127.f) * s2;
  float s = waveSum(t[0] + t[1] + t[2] + t[3]);
  if ((tid & 63) == 0) red[tid >> 6] = s;
  __syncthreads();
  const float mean = (red[0] + red[1] + red[2] + red[3]) * (1.0f / 1024.0f);
  float vs = 0.f;
#pragma unroll
  for (int i = 0; i < 4; ++i) { float d = t[i] - mean; vs += d * d; }
  vs = waveSum(vs);
  if ((tid & 63) == 0) red[4 + (tid >> 6)] = vs;
  __syncthreads();
  const float var = (red[4] + red[5] + red[6] + red[7]) * (1.0f / 1024.0f);
  const float rs = sqrtf(var + 1e-5f);
  f32x4 o;
  o.x = (t[0] - mean) / rs;
  o.y = (t[1] - mean) / rs;
  o.z = (t[2] - mean) / rs;
  o.w = (t[3] - mean) / rs;
  *(f32x4*)(out + (size_t)row * 1024 + tid * 4) = o;
}

// --------------------------- workspace layout (52.07 MB peak) ----------------
static constexpr size_t MB = 1u << 20;
static constexpr size_t OFF_M     = 0;          // 21 stats x 64 f32 slots
static constexpr size_t OFF_FLAG  = 6400;
static constexpr size_t OFF_BIASQ = 8192;
static constexpr size_t OFF_BIASK = OFF_BIASQ + 4096;
static constexpr size_t OFF_BIASV = OFF_BIASK + 4096;
static constexpr size_t OFF_BIASO = OFF_BIASV + 4096;
static constexpr size_t OFF_BIAS1 = OFF_BIASO + 4096;
static constexpr size_t OFF_BIAS2 = OFF_BIAS1 + 16384;
static constexpr size_t OFF_RS    = OFF_BIAS2 + 4096;
static constexpr size_t OFF_XQ    = 65536;
static constexpr size_t OFF_WQQ   = OFF_XQ  + 4 * MB;
static constexpr size_t OFF_WKQ   = OFF_WQQ + 1 * MB;
static constexpr size_t OFF_WVQ   = OFF_WKQ + 1 * MB;
static constexpr size_t OFF_WOQ   = OFF_WVQ + 1 * MB;
static constexpr size_t OFF_W1Q   = OFF_WOQ + 1 * MB;
static constexpr size_t OFF_W2Q   = OFF_W1Q + 4 * MB;
static constexpr size_t OFF_X1Q   = OFF_W2Q + 4 * MB;
static constexpr size_t OFF_A1    = OFF_X1Q + 4 * MB;     // arena1, 16 MB
static constexpr size_t OFF_A2    = OFF_A1 + 16 * MB;     // arena2 (f32), 16 MB

extern "C" void kernel_launch(void* const* d_in, const int* in_sizes, int n_in,
                              void* d_out, int out_size, void* d_ws, size_t ws_size,
                              hipStream_t stream) {
  (void)n_in; (void)out_size; (void)ws_size;
  char* ws = (char*)d_ws;
  float* M = (float*)(ws + OFF_M);
  int* FLAG = (int*)(ws + OFF_FLAG);
  float* BIASQ = (float*)(ws + OFF_BIASQ);
  float* BIASK = (float*)(ws + OFF_BIASK);
  float* BIASV = (float*)(ws + OFF_BIASV);
  float* BIASO = (float*)(ws + OFF_BIASO);
  float* BIAS1 = (float*)(ws + OFF_BIAS1);
  float* BIAS2 = (float*)(ws + OFF_BIAS2);
  int* RS = (int*)(ws + OFF_RS);
  int8_t* XQ  = (int8_t*)(ws + OFF_XQ);
  int8_t* WQQ = (int8_t*)(ws + OFF_WQQ);
  int8_t* WKQ = (int8_t*)(ws + OFF_WKQ);
  int8_t* WVQ = (int8_t*)(ws + OFF_WVQ);
  int8_t* WOQ = (int8_t*)(ws + OFF_WOQ);
  int8_t* W1Q = (int8_t*)(ws + OFF_W1Q);
  int8_t* W2Q = (int8_t*)(ws + OFF_W2Q);
  int8_t* X1Q = (int8_t*)(ws + OFF_X1Q);
  int8_t* QQ   = (int8_t*)(ws + OFF_A1);
  int8_t* KQQ  = (int8_t*)(ws + OFF_A1 + 4 * MB);
  int8_t* VT   = (int8_t*)(ws + OFF_A1 + 8 * MB);
  int8_t* CTXQ = (int8_t*)(ws + OFF_A1 + 12 * MB);
  float*  X1F  = (float*)(ws + OFF_A1);
  int8_t* HQ   = (int8_t*)(ws + OFF_A1);
  float* FBUF = (float*)(ws + OFF_A2);   // serial reuse: QF/KF/VF/ctx/ao/h2

  hipMemsetAsync(M, 0, 8192, stream);
  detect_f32<<<1, 64, 0, stream>>>((const u16*)d_in[0], FLAG);

  AJobs aj;
  const int ablk[13] = {512, 128, 1, 128, 1, 128, 1, 128, 1, 512, 2, 512, 1};
  int bs = 0;
  for (int i = 0; i < 13; ++i) {
    aj.p[i] = d_in[i];
    aj.n4[i] = in_sizes[i] / 4;
    aj.bstart[i] = bs;
    bs += ablk[i];
  }
  aj.bstart[13] = bs;
  absmax_multi<<<bs, 256, 0, stream>>>(aj, M, FLAG);

  quant_in_signed<<<1024, 256, 0, stream>>>(d_in[0], XQ, M + 0 * 64, FLAG, in_sizes[0] / 4);

  WJobs wj;
  const int widx[5] = {1, 3, 5, 7, 9};
  int8_t* wout[5] = {WQQ, WKQ, WVQ, WOQ, W1Q};
  const int wblk[5] = {128, 128, 128, 128, 512};
  int wb = 0;
  for (int j = 0; j < 5; ++j) {
    wj.in[j] = d_in[widx[j]];
    wj.out[j] = wout[j];
    wj.mslot[j] = widx[j];
    wj.n4[j] = in_sizes[widx[j]] / 4;
    wj.bstart[j] = wb;
    wb += wblk[j];
  }
  wj.bstart[5] = wb;
  quant_w_multi<<<wb, 256, 0, stream>>>(wj, M, FLAG);
  quant_w2_rs<<<1024, 256, 0, stream>>>(d_in[11], W2Q, M + 11 * 64, FLAG, RS);

  BJobs bj;
  const int bidx[6] = {2, 4, 6, 8, 10, 12};
  float* bout[6] = {BIASQ, BIASK, BIASV, BIASO, BIAS1, BIAS2};
  for (int j = 0; j < 6; ++j) {
    bj.in[j] = d_in[bidx[j]];
    bj.out[j] = bout[j];
    bj.mslot[j] = bidx[j];
    bj.n4[j] = in_sizes[bidx[j]] / 4;
  }
  fq_bias_multi<<<6, 256, 0, stream>>>(bj, M, FLAG);

  // Q/K/V projections through the 16MB f32 arena, strictly serial
  gemm_i8<<<dim3(32, 8), 256, 0, stream>>>(XQ, WQQ, FBUF, nullptr, M + 0 * 64, 1.f, 127.f, M + 1 * 64, BIASQ, nullptr, 0, 0, M + 13 * 64, 1024, 1024);
  quant_f32_signed<<<2048, 256, 0, stream>>>(FBUF, QQ, M + 13 * 64, 0.125f, 1024 * 1024);
  gemm_i8<<<dim3(32, 8), 256, 0, stream>>>(XQ, WKQ, FBUF, nullptr, M + 0 * 64, 1.f, 127.f, M + 3 * 64, BIASK, nullptr, 0, 0, M + 14 * 64, 1024, 1024);
  quant_f32_signed<<<2048, 256, 0, stream>>>(FBUF, KQQ, M + 14 * 64, 1.0f, 1024 * 1024);
  gemm_i8<<<dim3(32, 8), 256, 0, stream>>>(XQ, WVQ, FBUF, nullptr, M + 0 * 64, 1.f, 127.f, M + 5 * 64, BIASV, nullptr, 0, 0, M + 15 * 64, 1024, 1024);
  quant_v_t<<<dim3(64, 16), 256, 0, stream>>>(FBUF, VT, M + 15 * 64);

  attn_fused<<<1024, 256, 0, stream>>>(QQ, KQQ, VT, FBUF, M, M + 16 * 64);
  quant_f32_signed<<<2048, 256, 0, stream>>>(FBUF, CTXQ, M + 16 * 64, 1.0f, 1024 * 1024);

  gemm_i8<<<dim3(32, 8), 256, 0, stream>>>(CTXQ, WOQ, FBUF, nullptr, M + 16 * 64, 1.f, 127.f, M + 7 * 64, BIASO, nullptr, 0, 0, M + 17 * 64, 1024, 1024);

  ln_res<<<4096, 256, 0, stream>>>(XQ, M + 0 * 64, FBUF, M + 17 * 64, X1F, M + 18 * 64);
  quant_f32_signed<<<2048, 256, 0, stream>>>(X1F, X1Q, M + 18 * 64, 1.0f, 1024 * 1024);

  gemm_i8<<<dim3(32, 32), 256, 0, stream>>>(X1Q, W1Q, nullptr, nullptr, M + 18 * 64, 1.f, 127.f, M + 9 * 64, BIAS1, nullptr, 1, 1, M + 19 * 64, 1024, 4096);
  gemm_i8<<<dim3(32, 32), 256, 0, stream>>>(X1Q, W1Q, nullptr, HQ,      M + 18 * 64, 1.f, 127.f, M + 9 * 64, BIAS1, nullptr, 1, 2, M + 19 * 64, 1024, 4096);

  gemm_i8<<<dim3(32, 8), 256, 0, stream>>>(HQ, W2Q, FBUF, nullptr, M + 19 * 64, 1.f, 255.f, M + 11 * 64, BIAS2, RS, 0, 0, M + 20 * 64, 4096, 1024);

  ln_final<<<4096, 256, 0, stream>>>(X1Q, M + 18 * 64, FBUF, M + 20 * 64, (float*)d_out);
}

// Round 4
// 437.832 us; speedup vs baseline: 1.0662x; 1.0662x over previous
//
#include <hip/hip_runtime.h>
#include <stdint.h>
#include <stddef.h>

// ---------------------------------------------------------------------------
// Fully fake-quantized transformer block on MI355X (gfx950).
// i8 MFMA GEMMs (exact i32 acc), flash-style fused attention.
// R11: gemm_i8 pipeline FIX. R10's counted vmcnt was defeated: compiler-visible
// ds_reads may alias the global_load_lds DMA, so hipcc inserted its own
// s_waitcnt vmcnt(0) before them (drain moved, not removed; R10 == R9).
// Now: inline-asm ds_read_b128 on explicit LDS offsets (invisible to the
// aliaser) + own lgkmcnt(0) + sched_barrier(0) before MFMAs (rule #18), and
// 4-buffer distance-3 prefetch: steady-state s_waitcnt vmcnt(8) covers
// ~3 iters (~900cy) of HBM latency. Barrier AFTER each wave's counted wait
// guarantees all waves' tile-i DMA landed before any wave reads it.
// R10/R9 (kept): attn block=(b,h,pair,rowhalf), swapped QK^T, reg P-transpose.
// ---------------------------------------------------------------------------

typedef unsigned short u16;
typedef __attribute__((ext_vector_type(4))) int   i32x4;
typedef __attribute__((ext_vector_type(4))) float f32x4;

#define DEV __device__ __forceinline__

DEV float bf2f(u16 u) { return __uint_as_float(((unsigned)u) << 16); }
DEV void atomicMaxF(float* p, float v) { atomicMax((unsigned*)p, __float_as_uint(v)); }
DEV float waveMax(float v) {
#pragma unroll
  for (int o = 32; o; o >>= 1) v = fmaxf(v, __shfl_xor(v, o, 64));
  return v;
}
DEV float waveSum(float v) {
#pragma unroll
  for (int o = 32; o; o >>= 1) v += __shfl_xor(v, o, 64);
  return v;
}
DEV int waveSumI(int v) {
#pragma unroll
  for (int o = 32; o; o >>= 1) v += __shfl_xor(v, o, 64);
  return v;
}
DEV void blockStatMax(float v, float* __restrict__ slot64, float* sred4, int flatBlk) {
  v = waveMax(v);
  const int tid = threadIdx.x;
  if ((tid & 63) == 0) sred4[tid >> 6] = v;
  __syncthreads();
  if (tid == 0) {
    float m = fmaxf(fmaxf(sred4[0], sred4[1]), fmaxf(sred4[2], sred4[3]));
    atomicMaxF(&slot64[flatBlk & 63], m);
  }
}
DEV float slotMax64(const float* __restrict__ s) {
  float m = 0.f;
#pragma unroll
  for (int i = 0; i < 64; ++i) m = fmaxf(m, s[i]);
  return m;
}
DEV f32x4 ld4(const void* p, int i4, int isf32) {
  if (isf32) return ((const f32x4*)p)[i4];
  ushort4 u = ((const ushort4*)p)[i4];
  return (f32x4){bf2f(u.x), bf2f(u.y), bf2f(u.z), bf2f(u.w)};
}
DEV void gll16(const void* g, void* l) {
  __builtin_amdgcn_global_load_lds((__attribute__((address_space(1))) void*)(g),
                                   (__attribute__((address_space(3))) void*)(l),
                                   16, 0, 0);
}
DEV unsigned ldsaddr(const void* p) {
  return (unsigned)(size_t)(__attribute__((address_space(3))) const void*)p;
}
DEV unsigned quadsel(unsigned a, unsigned b, unsigned c, unsigned d, int idx) {
  unsigned lo = (idx & 1) ? b : a;
  unsigned hi = (idx & 1) ? d : c;
  return (idx & 2) ? hi : lo;
}

__global__ void detect_f32(const u16* __restrict__ x, int* __restrict__ flag) {
  const int tid = threadIdx.x;
  int cnt = 0;
#pragma unroll
  for (int i = 0; i < 16; ++i) {
    u16 u = x[tid * 16 + i];
    if ((u & 0x7f80u) >= 0x4380u) ++cnt;
  }
  cnt = waveSumI(cnt);
  if (tid == 0) flag[0] = (cnt > 16) ? 1 : 0;
}

struct AJobs { const void* p[13]; int n4[13]; int bstart[14]; };

__global__ __launch_bounds__(256) void absmax_multi(AJobs J, float* __restrict__ M,
                                                    const int* __restrict__ flagp) {
  __shared__ float sred[4];
  const int isf32 = flagp[0];
  const int blk = blockIdx.x, tid = threadIdx.x;
  int j = 0;
  while (j < 12 && blk >= J.bstart[j + 1]) ++j;
  const int lb = blk - J.bstart[j];
  const int nb = J.bstart[j + 1] - J.bstart[j];
  float mx = 0.f;
  const void* p = J.p[j];
  for (int i = lb * 256 + tid; i < J.n4[j]; i += nb * 256) {
    f32x4 v = ld4(p, i, isf32);
    mx = fmaxf(mx, fmaxf(fmaxf(fabsf(v.x), fabsf(v.y)),
                         fmaxf(fabsf(v.z), fabsf(v.w))));
  }
  blockStatMax(mx, M + j * 64, sred, lb);
}

__global__ __launch_bounds__(256) void quant_in_signed(
    const void* __restrict__ in, int8_t* __restrict__ out,
    const float* __restrict__ mp, const int* __restrict__ flagp, int n4) {
  const int isf32 = flagp[0];
  const float s = fmaxf(slotMax64(mp), 1e-8f) / 127.0f;
  char4* op = (char4*)out;
  for (int i = blockIdx.x * 256 + threadIdx.x; i < n4; i += gridDim.x * 256) {
    f32x4 v = ld4(in, i, isf32);
    char4 q;
    q.x = (signed char)fminf(fmaxf(rintf(v.x / s), -128.f), 127.f);
    q.y = (signed char)fminf(fmaxf(rintf(v.y / s), -128.f), 127.f);
    q.z = (signed char)fminf(fmaxf(rintf(v.z / s), -128.f), 127.f);
    q.w = (signed char)fminf(fmaxf(rintf(v.w / s), -128.f), 127.f);
    op[i] = q;
  }
}

struct WJobs { const void* in[5]; int8_t* out[5]; int mslot[5]; int n4[5]; int bstart[6]; };

__global__ __launch_bounds__(256) void quant_w_multi(WJobs J, const float* __restrict__ M,
                                                     const int* __restrict__ flagp) {
  const int isf32 = flagp[0];
  const int blk = blockIdx.x, tid = threadIdx.x;
  int j = 0;
  while (j < 4 && blk >= J.bstart[j + 1]) ++j;
  const int lb = blk - J.bstart[j];
  const int nb = J.bstart[j + 1] - J.bstart[j];
  const float s = fmaxf(slotMax64(M + J.mslot[j] * 64), 1e-8f) / 127.0f;
  const void* p = J.in[j];
  char4* o = (char4*)J.out[j];
  for (int i = lb * 256 + tid; i < J.n4[j]; i += nb * 256) {
    f32x4 v = ld4(p, i, isf32);
    char4 q;
    q.x = (signed char)fminf(fmaxf(rintf(v.x / s), -127.f), 127.f);
    q.y = (signed char)fminf(fmaxf(rintf(v.y / s), -127.f), 127.f);
    q.z = (signed char)fminf(fmaxf(rintf(v.z / s), -127.f), 127.f);
    q.w = (signed char)fminf(fmaxf(rintf(v.w / s), -127.f), 127.f);
    o[i] = q;
  }
}

__global__ __launch_bounds__(256) void quant_w2_rs(
    const void* __restrict__ w2, int8_t* __restrict__ out,
    const float* __restrict__ mp, const int* __restrict__ flagp,
    int* __restrict__ rowsum) {
  const int isf32 = flagp[0];
  const int row = blockIdx.x, tid = threadIdx.x;
  const float s = fmaxf(slotMax64(mp), 1e-8f) / 127.0f;
  char4* op = (char4*)(out + (size_t)row * 4096);
  int sum = 0;
  for (int i = tid; i < 1024; i += 256) {
    f32x4 v = ld4(w2, row * 1024 + i, isf32);
    char4 q;
    q.x = (signed char)fminf(fmaxf(rintf(v.x / s), -127.f), 127.f);
    q.y = (signed char)fminf(fmaxf(rintf(v.y / s), -127.f), 127.f);
    q.z = (signed char)fminf(fmaxf(rintf(v.z / s), -127.f), 127.f);
    q.w = (signed char)fminf(fmaxf(rintf(v.w / s), -127.f), 127.f);
    op[i] = q;
    sum += (int)q.x + (int)q.y + (int)q.z + (int)q.w;
  }
  sum = waveSumI(sum);
  __shared__ int rs4[4];
  if ((tid & 63) == 0) rs4[tid >> 6] = sum;
  __syncthreads();
  if (tid == 0) rowsum[row] = rs4[0] + rs4[1] + rs4[2] + rs4[3];
}

struct BJobs { const void* in[6]; float* out[6]; int mslot[6]; int n4[6]; };

__global__ __launch_bounds__(256) void fq_bias_multi(BJobs J, const float* __restrict__ M,
                                                     const int* __restrict__ flagp) {
  const int isf32 = flagp[0];
  const int j = blockIdx.x;
  const float s = fmaxf(slotMax64(M + J.mslot[j] * 64), 1e-8f) / 127.0f;
  float* o = J.out[j];
  for (int i = threadIdx.x; i < J.n4[j]; i += 256) {
    f32x4 v = ld4(J.in[j], i, isf32);
    f32x4 r;
    r.x = fminf(fmaxf(rintf(v.x / s), -128.f), 127.f) * s;
    r.y = fminf(fmaxf(rintf(v.y / s), -128.f), 127.f) * s;
    r.z = fminf(fmaxf(rintf(v.z / s), -128.f), 127.f) * s;
    r.w = fminf(fmaxf(rintf(v.w / s), -128.f), 127.f) * s;
    *(f32x4*)(o + i * 4) = r;
  }
}

__global__ __launch_bounds__(256) void quant_f32_signed(
    const float* __restrict__ in, int8_t* __restrict__ out,
    const float* __restrict__ mp, float pre, int n4) {
  const float s = fmaxf(slotMax64(mp) * pre, 1e-8f) / 127.0f;
  const f32x4* ip = (const f32x4*)in;
  char4* op = (char4*)out;
  for (int i = blockIdx.x * 256 + threadIdx.x; i < n4; i += gridDim.x * 256) {
    f32x4 v = ip[i];
    char4 q;
    q.x = (signed char)fminf(fmaxf(rintf(v.x * pre / s), -128.f), 127.f);
    q.y = (signed char)fminf(fmaxf(rintf(v.y * pre / s), -128.f), 127.f);
    q.z = (signed char)fminf(fmaxf(rintf(v.z * pre / s), -128.f), 127.f);
    q.w = (signed char)fminf(fmaxf(rintf(v.w * pre / s), -128.f), 127.f);
    op[i] = q;
  }
}

__global__ __launch_bounds__(256) void quant_v_t(
    const float* __restrict__ V, int8_t* __restrict__ Vt,
    const float* __restrict__ mp) {
  __shared__ float tile[64][65];
  const int bh = blockIdx.x, st = blockIdx.y;
  const int b = bh >> 4, h = bh & 15;
  const int tid = threadIdx.x;
  const float s = fmaxf(slotMax64(mp), 1e-8f) / 127.0f;
  const int r = tid >> 2, c = (tid & 3) * 16;
  const float* src = V + ((size_t)(b * 1024 + st * 64 + r)) * 1024 + h * 64 + c;
#pragma unroll
  for (int g = 0; g < 4; ++g) {
    f32x4 v = *(const f32x4*)(src + g * 4);
    tile[r][c + g * 4 + 0] = v.x;
    tile[r][c + g * 4 + 1] = v.y;
    tile[r][c + g * 4 + 2] = v.z;
    tile[r][c + g * 4 + 3] = v.w;
  }
  __syncthreads();
  unsigned wds[4];
#pragma unroll
  for (int g = 0; g < 4; ++g) {
    unsigned wd = 0;
#pragma unroll
    for (int k = 0; k < 4; ++k) {
      float v = tile[c + g * 4 + k][r];
      int q = (int)fminf(fmaxf(rintf(v / s), -128.f), 127.f);
      wd |= ((unsigned)(unsigned char)(signed char)q) << (8 * k);
    }
    wds[g] = wd;
  }
  i32x4 ov = {(int)wds[0], (int)wds[1], (int)wds[2], (int)wds[3]};
  *(i32x4*)(Vt + ((size_t)((b * 16 + h) * 64 + r)) * 1024 + st * 64 + c) = ov;
}

// ---------------- int8 GEMM (4-buffer, distance-3, asm ds_read) --------------
// mode 0: store f32 Cf, stat->mOut ; mode 1: stats only ; mode 2: requant u8-128
// Per iter: s_waitcnt vmcnt(8) (tiles i+1,i+2 stay in flight) -> s_barrier ->
// issue tile i+3 -> asm ds_read_b128 tile i -> lgkmcnt(0)+sched_barrier ->
// 16 MFMA. asm ds_reads are invisible to the compiler's DMA aliaser, so no
// hidden vmcnt(0) drain; volatile asm keeps mutual order.
__global__ __launch_bounds__(256) void gemm_i8(
    const int8_t* __restrict__ A, const int8_t* __restrict__ B,
    float* __restrict__ Cf, int8_t* __restrict__ Cq,
    const float* __restrict__ mA, float preA, float qmaxA,
    const float* __restrict__ mB,
    const float* __restrict__ bias, const int* __restrict__ extra,
    int relu, int mode, float* __restrict__ mOut, int K, int O) {
  __shared__ __align__(16) int8_t smem[4][16384];  // per buf: A[128][64] | B[128][64]
  __shared__ float sred[4];
  const int tid = threadIdx.x;
  const int nb = blockIdx.x, ob = blockIdx.y;
  const int w = tid >> 6, lane = tid & 63, l15 = lane & 15, quad = lane >> 4;
  const int wr = w >> 1, wc = w & 1;
  i32x4 acc[4][4];
#pragma unroll
  for (int i = 0; i < 4; ++i)
#pragma unroll
    for (int j = 0; j < 4; ++j) acc[i][j] = (i32x4){0, 0, 0, 0};
  const int r0 = tid >> 2, c0 = (tid & 3) * 16;
  const int8_t* Ab = A + (size_t)(nb * 128) * K;
  const int8_t* Bb = B + (size_t)(ob * 128) * K;
  const int nk = K >> 6;
  const int aoffl = (wr * 64 + l15) * 64 + quad * 16;
  const int boffl = 8192 + (wc * 64 + l15) * 64 + quad * 16;
  // prologue: stage tiles 0..2
  for (int t = 0; t < 3 && t < nk; ++t) {
    const size_t kt0 = (size_t)t << 6;
    int8_t* d = smem[t];
    gll16(Ab + (size_t)r0 * K + kt0 + c0, d + tid * 16);
    gll16(Ab + (size_t)(r0 + 64) * K + kt0 + c0, d + 4096 + tid * 16);
    gll16(Bb + (size_t)r0 * K + kt0 + c0, d + 8192 + tid * 16);
    gll16(Bb + (size_t)(r0 + 64) * K + kt0 + c0, d + 12288 + tid * 16);
  }
  for (int i = 0; i < nk; ++i) {
    const int infl = nk - 1 - i;  // tiles still prefetched beyond i
    if (infl >= 2)      asm volatile("s_waitcnt vmcnt(8)" ::: "memory");
    else if (infl == 1) asm volatile("s_waitcnt vmcnt(4)" ::: "memory");
    else                asm volatile("s_waitcnt vmcnt(0)" ::: "memory");
    asm volatile("s_barrier" ::: "memory");
    if (i + 3 < nk) {
      const size_t kt0 = (size_t)(i + 3) << 6;
      int8_t* d = smem[(i + 3) & 3];
      gll16(Ab + (size_t)r0 * K + kt0 + c0, d + tid * 16);
      gll16(Ab + (size_t)(r0 + 64) * K + kt0 + c0, d + 4096 + tid * 16);
      gll16(Bb + (size_t)r0 * K + kt0 + c0, d + 8192 + tid * 16);
      gll16(Bb + (size_t)(r0 + 64) * K + kt0 + c0, d + 12288 + tid * 16);
    }
    const unsigned a_addr = ldsaddr(smem[i & 3] + aoffl);
    const unsigned b_addr = ldsaddr(smem[i & 3] + boffl);
    i32x4 af[4], bf[4];
    asm volatile("ds_read_b128 %0, %1 offset:0"    : "=v"(af[0]) : "v"(a_addr));
    asm volatile("ds_read_b128 %0, %1 offset:1024" : "=v"(af[1]) : "v"(a_addr));
    asm volatile("ds_read_b128 %0, %1 offset:2048" : "=v"(af[2]) : "v"(a_addr));
    asm volatile("ds_read_b128 %0, %1 offset:3072" : "=v"(af[3]) : "v"(a_addr));
    asm volatile("ds_read_b128 %0, %1 offset:0"    : "=v"(bf[0]) : "v"(b_addr));
    asm volatile("ds_read_b128 %0, %1 offset:1024" : "=v"(bf[1]) : "v"(b_addr));
    asm volatile("ds_read_b128 %0, %1 offset:2048" : "=v"(bf[2]) : "v"(b_addr));
    asm volatile("ds_read_b128 %0, %1 offset:3072" : "=v"(bf[3]) : "v"(b_addr));
    asm volatile("s_waitcnt lgkmcnt(0)" ::: "memory");
    __builtin_amdgcn_sched_barrier(0);
#pragma unroll
    for (int mt = 0; mt < 4; ++mt)
#pragma unroll
      for (int nt = 0; nt < 4; ++nt)
        acc[mt][nt] = __builtin_amdgcn_mfma_i32_16x16x64_i8(af[mt], bf[nt], acc[mt][nt], 0, 0, 0);
  }
  const float sA = fmaxf(slotMax64(mA) * preA, 1e-8f) / qmaxA;
  const float sB = fmaxf(slotMax64(mB), 1e-8f) / 127.0f;
  const float sAB = sA * sB;
  const float sq = (mode == 2) ? (fmaxf(slotMax64(mOut), 1e-8f) / 255.0f) : 1.0f;
  float lmax = 0.f;
#pragma unroll
  for (int mt = 0; mt < 4; ++mt) {
    const int n = nb * 128 + wr * 64 + mt * 16 + quad * 4;
#pragma unroll
    for (int nt = 0; nt < 4; ++nt) {
      const int o = ob * 128 + wc * 64 + nt * 16 + l15;
      const int ext = extra ? 128 * extra[o] : 0;
      const float bv = bias[o];
#pragma unroll
      for (int r = 0; r < 4; ++r) {
        float v = sAB * (float)(acc[mt][nt][r] + ext) + bv;
        if (relu) v = fmaxf(v, 0.f);
        if (mode == 0) Cf[(size_t)(n + r) * O + o] = v;
        else if (mode == 2) {
          int q = (int)fminf(fmaxf(rintf(v / sq), 0.f), 255.f) - 128;
          Cq[(size_t)(n + r) * O + o] = (int8_t)q;
        }
        lmax = fmaxf(lmax, fabsf(v));
      }
    }
  }
  if (mode != 2)
    blockStatMax(lmax, mOut, sred, nb + ob * gridDim.x);
}

// --------------------------- fused causal attention --------------------------
// R9: grid 1024 = (b, h, pair p, rowhalf). Waves 0-1: hi tile (qt=15-p) rows
// rh*32+{0,16}; waves 2-3: lo tile (qt=p), same rows. Shared K/V staging over
// kt=0..15-p (lo range is a subset). Swapped QK^T -> lane-local softmax row,
// register quad-transpose of quantized P (no ptile LDS).
__global__ __launch_bounds__(256, 4) void attn_fused(
    const int8_t* __restrict__ Qq, const int8_t* __restrict__ Kq,
    const int8_t* __restrict__ Vt, float* __restrict__ ctx,
    const float* __restrict__ M, float* __restrict__ mOut) {
  __shared__ __align__(16) int8_t qtile[4096];
  __shared__ __align__(16) int8_t ktile[2][4096];
  __shared__ __align__(16) int8_t vtile[2][4096];
  __shared__ float sred[4];
  const int tid = threadIdx.x, bid = blockIdx.x;
  const int pidx = bid & 7, rh = (bid >> 3) & 1, h = (bid >> 4) & 15, b = bid >> 8;
  const int qthi = 15 - pidx, qtlo = pidx, ktmax = qthi;
  const int w = tid >> 6, lane = tid & 63, l15 = lane & 15, quad = lane >> 4;
  const int wqt = (w < 2) ? qthi : qtlo;
  const int wrow0 = rh * 32 + (w & 1) * 16;
  const float sqs = fmaxf(slotMax64(M + 13 * 64) * 0.125f, 1e-8f) / 127.0f;
  const float sk = fmaxf(slotMax64(M + 14 * 64), 1e-8f) / 127.0f;
  const float sv = fmaxf(slotMax64(M + 15 * 64), 1e-8f) / 127.0f;
  const float sqk = sqs * sk;
  const float s_attn = 1.0f / 127.0f;  // softmax global max == 1.0 exactly
  const int r0 = tid >> 2, c0 = (tid & 3) * 16;
  const int8_t* Kbase = Kq + (size_t)(b * 1024) * 1024 + h * 64 + c0;
  const int8_t* Vbase = Vt + (size_t)((b * 16 + h) * 64 + r0) * 1024 + c0;

  // stage Q: staging rows 0..31 -> hi tile rows rh*32+(0..31); 32..63 -> lo
  {
    const int qt_s = (r0 < 32) ? qthi : qtlo;
    const int qrow_g = qt_s * 64 + rh * 32 + (r0 & 31);
    gll16(Qq + ((size_t)(b * 1024 + qrow_g)) * 1024 + h * 64 + c0, qtile + tid * 16);
  }
  gll16(Kbase + (size_t)r0 * 1024, ktile[0] + tid * 16);
  __syncthreads();
  const i32x4 aq = *(const i32x4*)(qtile + (w * 16 + l15) * 64 + quad * 16);
  const int qrow = wqt * 64 + wrow0 + l15;  // this lane's q-row (0..1023)

  // ---- Phase A: swapped QK^T; per-lane online (m,l) over 16 kcols per kt ----
  float m_l = -1e30f, l_l = 0.f;
  for (int kt = 0; kt <= ktmax; ++kt) {
    if (kt) __syncthreads();
    if (kt < ktmax)
      gll16(Kbase + (size_t)((kt + 1) * 64 + r0) * 1024, ktile[(kt + 1) & 1] + tid * 16);
    if (kt <= wqt) {
      const int8_t* kc = ktile[kt & 1];
      const int kc0 = kt * 64 + quad * 4;
      float sc[4][4];
#pragma unroll
      for (int nt = 0; nt < 4; ++nt) {
        i32x4 z = {0, 0, 0, 0};
        i32x4 bk = *(const i32x4*)(kc + (nt * 16 + l15) * 64 + quad * 16);
        i32x4 d = __builtin_amdgcn_mfma_i32_16x16x64_i8(bk, aq, z, 0, 0, 0);
        if (kt == wqt) {
#pragma unroll
          for (int r = 0; r < 4; ++r)
            sc[nt][r] = (kc0 + nt * 16 + r <= qrow) ? sqk * (float)d[r] : -1e30f;
        } else {
#pragma unroll
          for (int r = 0; r < 4; ++r) sc[nt][r] = sqk * (float)d[r];
        }
      }
      float vm = sc[0][0];
#pragma unroll
      for (int nt = 0; nt < 4; ++nt)
#pragma unroll
        for (int r = 0; r < 4; ++r) vm = fmaxf(vm, sc[nt][r]);
      const float mn = fmaxf(m_l, vm);
      float sum = 0.f;
#pragma unroll
      for (int nt = 0; nt < 4; ++nt)
#pragma unroll
        for (int r = 0; r < 4; ++r) sum += __expf(sc[nt][r] - mn);
      l_l = l_l * __expf(m_l - mn) + sum;
      m_l = mn;
    }
  }
  // merge the 4 quads (lanes sharing l15 hold the same q-row)
#pragma unroll
  for (int off = 16; off <= 32; off <<= 1) {
    float om = __shfl_xor(m_l, off, 64);
    float ol = __shfl_xor(l_l, off, 64);
    float mn = fmaxf(m_l, om);
    l_l = l_l * __expf(m_l - mn) + ol * __expf(om - mn);
    m_l = mn;
  }
  const float rl127 = 127.0f / l_l;  // P*127 in [0,127] exactly -> no clamps

  // ---- Phase B: recompute, quantize P in-register, quad-transpose, PV ----
  __syncthreads();
  gll16(Kbase + (size_t)r0 * 1024, ktile[0] + tid * 16);
  gll16(Vbase, vtile[0] + tid * 16);
  i32x4 cacc[4] = {{0, 0, 0, 0}, {0, 0, 0, 0}, {0, 0, 0, 0}, {0, 0, 0, 0}};
  for (int kt = 0; kt <= ktmax; ++kt) {
    __syncthreads();
    if (kt < ktmax) {
      gll16(Kbase + (size_t)((kt + 1) * 64 + r0) * 1024, ktile[(kt + 1) & 1] + tid * 16);
      gll16(Vbase + (kt + 1) * 64, vtile[(kt + 1) & 1] + tid * 16);
    }
    if (kt <= wqt) {
      const int8_t* kc = ktile[kt & 1];
      const int kc0 = kt * 64 + quad * 4;
      unsigned Dw[4];
#pragma unroll
      for (int nt = 0; nt < 4; ++nt) {
        i32x4 z = {0, 0, 0, 0};
        i32x4 bk = *(const i32x4*)(kc + (nt * 16 + l15) * 64 + quad * 16);
        i32x4 d = __builtin_amdgcn_mfma_i32_16x16x64_i8(bk, aq, z, 0, 0, 0);
        unsigned wd = 0;
        if (kt == wqt) {
#pragma unroll
          for (int r = 0; r < 4; ++r) {
            float e = (kc0 + nt * 16 + r <= qrow)
                          ? __expf(sqk * (float)d[r] - m_l) * rl127 : 0.f;
            wd |= ((unsigned)(int)rintf(e)) << (8 * r);
          }
        } else {
#pragma unroll
          for (int r = 0; r < 4; ++r) {
            float e = __expf(sqk * (float)d[r] - m_l) * rl127;
            wd |= ((unsigned)(int)rintf(e)) << (8 * r);
          }
        }
        Dw[nt] = wd;
      }
      // 4x4 quad-transpose: pf[j] (k=quad*16+4j..) <- Dw[quad] @ lane quad'=j
      unsigned selfv = quadsel(Dw[0], Dw[1], Dw[2], Dw[3], quad);
      unsigned rv1 = (unsigned)__shfl_xor(
          (int)quadsel(Dw[0], Dw[1], Dw[2], Dw[3], quad ^ 1), 16, 64);
      unsigned rv2 = (unsigned)__shfl_xor(
          (int)quadsel(Dw[0], Dw[1], Dw[2], Dw[3], quad ^ 2), 32, 64);
      unsigned rv3 = (unsigned)__shfl_xor(
          (int)quadsel(Dw[0], Dw[1], Dw[2], Dw[3], quad ^ 3), 48, 64);
      i32x4 pf;
#pragma unroll
      for (int j = 0; j < 4; ++j) {
        const int t = j ^ quad;
        pf[j] = (int)((t == 0) ? selfv : (t == 1) ? rv1 : (t == 2) ? rv2 : rv3);
      }
      const int8_t* vc = vtile[kt & 1];
#pragma unroll
      for (int nt = 0; nt < 4; ++nt) {
        i32x4 bv = *(const i32x4*)(vc + (nt * 16 + l15) * 64 + quad * 16);
        cacc[nt] = __builtin_amdgcn_mfma_i32_16x16x64_i8(pf, bv, cacc[nt], 0, 0, 0);
      }
    }
  }
  const float sc2 = s_attn * sv;
  float lmax = 0.f;
  const int orow0 = wqt * 64 + wrow0 + quad * 4;
#pragma unroll
  for (int nt = 0; nt < 4; ++nt) {
    const int d = nt * 16 + l15;
#pragma unroll
    for (int r = 0; r < 4; ++r) {
      float v = sc2 * (float)cacc[nt][r];
      ctx[((size_t)(b * 1024 + orow0 + r)) * 1024 + h * 64 + d] = v;
      lmax = fmaxf(lmax, fabsf(v));
    }
  }
  blockStatMax(lmax, mOut, sred, bid);
}

// --------------------------- residual + layernorm ---------------------------
__global__ __launch_bounds__(256) void ln_res(
    const int8_t* __restrict__ xq, const float* __restrict__ mx,
    const float* __restrict__ ao, const float* __restrict__ ma,
    float* __restrict__ x1, float* __restrict__ mOut) {
  __shared__ float red[8];
  __shared__ float sred[4];
  const int row = blockIdx.x, tid = threadIdx.x;
  const float sx = fmaxf(slotMax64(mx), 1e-8f) / 127.0f;
  const float sa = fmaxf(slotMax64(ma), 1e-8f) / 127.0f;
  char4 xv = *(const char4*)(xq + (size_t)row * 1024 + tid * 4);
  f32x4 av = *(const f32x4*)(ao + (size_t)row * 1024 + tid * 4);
  float t[4];
  t[0] = (float)xv.x * sx + fminf(fmaxf(rintf(av.x / sa), -128.f), 127.f) * sa;
  t[1] = (float)xv.y * sx + fminf(fmaxf(rintf(av.y / sa), -128.f), 127.f) * sa;
  t[2] = (float)xv.z * sx + fminf(fmaxf(rintf(av.z / sa), -128.f), 127.f) * sa;
  t[3] = (float)xv.w * sx + fminf(fmaxf(rintf(av.w / sa), -128.f), 127.f) * sa;
  float s = waveSum(t[0] + t[1] + t[2] + t[3]);
  if ((tid & 63) == 0) red[tid >> 6] = s;
  __syncthreads();
  const float mean = (red[0] + red[1] + red[2] + red[3]) * (1.0f / 1024.0f);
  float vs = 0.f;
#pragma unroll
  for (int i = 0; i < 4; ++i) { float d = t[i] - mean; vs += d * d; }
  vs = waveSum(vs);
  if ((tid & 63) == 0) red[4 + (tid >> 6)] = vs;
  __syncthreads();
  const float var = (red[4] + red[5] + red[6] + red[7]) * (1.0f / 1024.0f);
  const float rs = sqrtf(var + 1e-5f);
  f32x4 o;
  o.x = (t[0] - mean) / rs;
  o.y = (t[1] - mean) / rs;
  o.z = (t[2] - mean) / rs;
  o.w = (t[3] - mean) / rs;
  *(f32x4*)(x1 + (size_t)row * 1024 + tid * 4) = o;
  float lmax = fmaxf(fmaxf(fabsf(o.x), fabsf(o.y)), fmaxf(fabsf(o.z), fabsf(o.w)));
  blockStatMax(lmax, mOut, sred, row);
}

__global__ __launch_bounds__(256) void ln_final(
    const int8_t* __restrict__ x1q, const float* __restrict__ mx1,
    const float* __restrict__ h2, const float* __restrict__ mh2,
    float* __restrict__ out) {
  __shared__ float red[8];
  const int row = blockIdx.x, tid = threadIdx.x;
  const float s1 = fmaxf(slotMax64(mx1), 1e-8f) / 127.0f;
  const float s2 = fmaxf(slotMax64(mh2), 1e-8f) / 127.0f;
  char4 xv = *(const char4*)(x1q + (size_t)row * 1024 + tid * 4);
  f32x4 hv = *(const f32x4*)(h2 + (size_t)row * 1024 + tid * 4);
  float t[4];
  t[0] = (float)xv.x * s1 + fminf(fmaxf(rintf(hv.x / s2), -128.f), 127.f) * s2;
  t[1] = (float)xv.y * s1 + fminf(fmaxf(rintf(hv.y / s2), -128.f), 127.f) * s2;
  t[2] = (float)xv.z * s1 + fminf(fmaxf(rintf(hv.z / s2), -128.f), 127.f) * s2;
  t[3] = (float)xv.w * s1 + fminf(fmaxf(rintf(hv.w / s2), -128.f), 127.f) * s2;
  float s = waveSum(t[0] + t[1] + t[2] + t[3]);
  if ((tid & 63) == 0) red[tid >> 6] = s;
  __syncthreads();
  const float mean = (red[0] + red[1] + red[2] + red[3]) * (1.0f / 1024.0f);
  float vs = 0.f;
#pragma unroll
  for (int i = 0; i < 4; ++i) { float d = t[i] - mean; vs += d * d; }
  vs = waveSum(vs);
  if ((tid & 63) == 0) red[4 + (tid >> 6)] = vs;
  __syncthreads();
  const float var = (red[4] + red[5] + red[6] + red[7]) * (1.0f / 1024.0f);
  const float rs = sqrtf(var + 1e-5f);
  f32x4 o;
  o.x = (t[0] - mean) / rs;
  o.y = (t[1] - mean) / rs;
  o.z = (t[2] - mean) / rs;
  o.w = (t[3] - mean) / rs;
  *(f32x4*)(out + (size_t)row * 1024 + tid * 4) = o;
}

// --------------------------- workspace layout (52.07 MB peak) ----------------
static constexpr size_t MB = 1u << 20;
static constexpr size_t OFF_M     = 0;          // 21 stats x 64 f32 slots
static constexpr size_t OFF_FLAG  = 6400;
static constexpr size_t OFF_BIASQ = 8192;
static constexpr size_t OFF_BIASK = OFF_BIASQ + 4096;
static constexpr size_t OFF_BIASV = OFF_BIASK + 4096;
static constexpr size_t OFF_BIASO = OFF_BIASV + 4096;
static constexpr size_t OFF_BIAS1 = OFF_BIASO + 4096;
static constexpr size_t OFF_BIAS2 = OFF_BIAS1 + 16384;
static constexpr size_t OFF_RS    = OFF_BIAS2 + 4096;
static constexpr size_t OFF_XQ    = 65536;
static constexpr size_t OFF_WQQ   = OFF_XQ  + 4 * MB;
static constexpr size_t OFF_WKQ   = OFF_WQQ + 1 * MB;
static constexpr size_t OFF_WVQ   = OFF_WKQ + 1 * MB;
static constexpr size_t OFF_WOQ   = OFF_WVQ + 1 * MB;
static constexpr size_t OFF_W1Q   = OFF_WOQ + 1 * MB;
static constexpr size_t OFF_W2Q   = OFF_W1Q + 4 * MB;
static constexpr size_t OFF_X1Q   = OFF_W2Q + 4 * MB;
static constexpr size_t OFF_A1    = OFF_X1Q + 4 * MB;     // arena1, 16 MB
static constexpr size_t OFF_A2    = OFF_A1 + 16 * MB;     // arena2 (f32), 16 MB

extern "C" void kernel_launch(void* const* d_in, const int* in_sizes, int n_in,
                              void* d_out, int out_size, void* d_ws, size_t ws_size,
                              hipStream_t stream) {
  (void)n_in; (void)out_size; (void)ws_size;
  char* ws = (char*)d_ws;
  float* M = (float*)(ws + OFF_M);
  int* FLAG = (int*)(ws + OFF_FLAG);
  float* BIASQ = (float*)(ws + OFF_BIASQ);
  float* BIASK = (float*)(ws + OFF_BIASK);
  float* BIASV = (float*)(ws + OFF_BIASV);
  float* BIASO = (float*)(ws + OFF_BIASO);
  float* BIAS1 = (float*)(ws + OFF_BIAS1);
  float* BIAS2 = (float*)(ws + OFF_BIAS2);
  int* RS = (int*)(ws + OFF_RS);
  int8_t* XQ  = (int8_t*)(ws + OFF_XQ);
  int8_t* WQQ = (int8_t*)(ws + OFF_WQQ);
  int8_t* WKQ = (int8_t*)(ws + OFF_WKQ);
  int8_t* WVQ = (int8_t*)(ws + OFF_WVQ);
  int8_t* WOQ = (int8_t*)(ws + OFF_WOQ);
  int8_t* W1Q = (int8_t*)(ws + OFF_W1Q);
  int8_t* W2Q = (int8_t*)(ws + OFF_W2Q);
  int8_t* X1Q = (int8_t*)(ws + OFF_X1Q);
  int8_t* QQ   = (int8_t*)(ws + OFF_A1);
  int8_t* KQQ  = (int8_t*)(ws + OFF_A1 + 4 * MB);
  int8_t* VT   = (int8_t*)(ws + OFF_A1 + 8 * MB);
  int8_t* CTXQ = (int8_t*)(ws + OFF_A1 + 12 * MB);
  float*  X1F  = (float*)(ws + OFF_A1);
  int8_t* HQ   = (int8_t*)(ws + OFF_A1);
  float* FBUF = (float*)(ws + OFF_A2);   // serial reuse: QF/KF/VF/ctx/ao/h2

  hipMemsetAsync(M, 0, 8192, stream);
  detect_f32<<<1, 64, 0, stream>>>((const u16*)d_in[0], FLAG);

  AJobs aj;
  const int ablk[13] = {512, 128, 1, 128, 1, 128, 1, 128, 1, 512, 2, 512, 1};
  int bs = 0;
  for (int i = 0; i < 13; ++i) {
    aj.p[i] = d_in[i];
    aj.n4[i] = in_sizes[i] / 4;
    aj.bstart[i] = bs;
    bs += ablk[i];
  }
  aj.bstart[13] = bs;
  absmax_multi<<<bs, 256, 0, stream>>>(aj, M, FLAG);

  quant_in_signed<<<1024, 256, 0, stream>>>(d_in[0], XQ, M + 0 * 64, FLAG, in_sizes[0] / 4);

  WJobs wj;
  const int widx[5] = {1, 3, 5, 7, 9};
  int8_t* wout[5] = {WQQ, WKQ, WVQ, WOQ, W1Q};
  const int wblk[5] = {128, 128, 128, 128, 512};
  int wb = 0;
  for (int j = 0; j < 5; ++j) {
    wj.in[j] = d_in[widx[j]];
    wj.out[j] = wout[j];
    wj.mslot[j] = widx[j];
    wj.n4[j] = in_sizes[widx[j]] / 4;
    wj.bstart[j] = wb;
    wb += wblk[j];
  }
  wj.bstart[5] = wb;
  quant_w_multi<<<wb, 256, 0, stream>>>(wj, M, FLAG);
  quant_w2_rs<<<1024, 256, 0, stream>>>(d_in[11], W2Q, M + 11 * 64, FLAG, RS);

  BJobs bj;
  const int bidx[6] = {2, 4, 6, 8, 10, 12};
  float* bout[6] = {BIASQ, BIASK, BIASV, BIASO, BIAS1, BIAS2};
  for (int j = 0; j < 6; ++j) {
    bj.in[j] = d_in[bidx[j]];
    bj.out[j] = bout[j];
    bj.mslot[j] = bidx[j];
    bj.n4[j] = in_sizes[bidx[j]] / 4;
  }
  fq_bias_multi<<<6, 256, 0, stream>>>(bj, M, FLAG);

  // Q/K/V projections through the 16MB f32 arena, strictly serial
  gemm_i8<<<dim3(32, 8), 256, 0, stream>>>(XQ, WQQ, FBUF, nullptr, M + 0 * 64, 1.f, 127.f, M + 1 * 64, BIASQ, nullptr, 0, 0, M + 13 * 64, 1024, 1024);
  quant_f32_signed<<<2048, 256, 0, stream>>>(FBUF, QQ, M + 13 * 64, 0.125f, 1024 * 1024);
  gemm_i8<<<dim3(32, 8), 256, 0, stream>>>(XQ, WKQ, FBUF, nullptr, M + 0 * 64, 1.f, 127.f, M + 3 * 64, BIASK, nullptr, 0, 0, M + 14 * 64, 1024, 1024);
  quant_f32_signed<<<2048, 256, 0, stream>>>(FBUF, KQQ, M + 14 * 64, 1.0f, 1024 * 1024);
  gemm_i8<<<dim3(32, 8), 256, 0, stream>>>(XQ, WVQ, FBUF, nullptr, M + 0 * 64, 1.f, 127.f, M + 5 * 64, BIASV, nullptr, 0, 0, M + 15 * 64, 1024, 1024);
  quant_v_t<<<dim3(64, 16), 256, 0, stream>>>(FBUF, VT, M + 15 * 64);

  attn_fused<<<1024, 256, 0, stream>>>(QQ, KQQ, VT, FBUF, M, M + 16 * 64);
  quant_f32_signed<<<2048, 256, 0, stream>>>(FBUF, CTXQ, M + 16 * 64, 1.0f, 1024 * 1024);

  gemm_i8<<<dim3(32, 8), 256, 0, stream>>>(CTXQ, WOQ, FBUF, nullptr, M + 16 * 64, 1.f, 127.f, M + 7 * 64, BIASO, nullptr, 0, 0, M + 17 * 64, 1024, 1024);

  ln_res<<<4096, 256, 0, stream>>>(XQ, M + 0 * 64, FBUF, M + 17 * 64, X1F, M + 18 * 64);
  quant_f32_signed<<<2048, 256, 0, stream>>>(X1F, X1Q, M + 18 * 64, 1.0f, 1024 * 1024);

  gemm_i8<<<dim3(32, 32), 256, 0, stream>>>(X1Q, W1Q, nullptr, nullptr, M + 18 * 64, 1.f, 127.f, M + 9 * 64, BIAS1, nullptr, 1, 1, M + 19 * 64, 1024, 4096);
  gemm_i8<<<dim3(32, 32), 256, 0, stream>>>(X1Q, W1Q, nullptr, HQ,      M + 18 * 64, 1.f, 127.f, M + 9 * 64, BIAS1, nullptr, 1, 2, M + 19 * 64, 1024, 4096);

  gemm_i8<<<dim3(32, 8), 256, 0, stream>>>(HQ, W2Q, FBUF, nullptr, M + 19 * 64, 1.f, 255.f, M + 11 * 64, BIAS2, RS, 0, 0, M + 20 * 64, 4096, 1024);

  ln_final<<<4096, 256, 0, stream>>>(X1Q, M + 18 * 64, FBUF, M + 20 * 64, (float*)d_out);
}

// Round 5
// 432.898 us; speedup vs baseline: 1.0783x; 1.0114x over previous
//
#include <hip/hip_runtime.h>
#include <stdint.h>
#include <stddef.h>

// ---------------------------------------------------------------------------
// Fully fake-quantized transformer block on MI355X (gfx950).
// i8 MFMA GEMMs (exact i32 acc), flash-style fused attention.
// R12: attn_fused gets the R11 pipeline (which fixed gemm_i8: 54.6->sub-45):
// 4-buffer K/V tiles, distance-3 prefetch, counted s_waitcnt vmcnt(N) + raw
// s_barrier per kt (never drain mid-loop), and ALL LDS reads as inline-asm
// ds_read_b128 + lgkmcnt(0) + sched_barrier(0) so the compiler's DMA-aliaser
// can't insert hidden vmcnt(0) drains (rule #18). Buffer-reuse safety: wave
// reaches iter-kt barrier only after its iter-(kt-1) lgkmcnt(0), so staging
// into buf (kt+3)&3 == (kt-1)&3 after the barrier is race-free (same argument
// validated by gemm R11). Math bit-identical.
// R11 (kept): gemm_i8 4-buffer distance-3 asm-ds_read pipeline.
// R9 (kept): attn block=(b,h,pair,rowhalf), swapped QK^T, reg P-transpose.
// ---------------------------------------------------------------------------

typedef unsigned short u16;
typedef __attribute__((ext_vector_type(4))) int   i32x4;
typedef __attribute__((ext_vector_type(4))) float f32x4;

#define DEV __device__ __forceinline__

DEV float bf2f(u16 u) { return __uint_as_float(((unsigned)u) << 16); }
DEV void atomicMaxF(float* p, float v) { atomicMax((unsigned*)p, __float_as_uint(v)); }
DEV float waveMax(float v) {
#pragma unroll
  for (int o = 32; o; o >>= 1) v = fmaxf(v, __shfl_xor(v, o, 64));
  return v;
}
DEV float waveSum(float v) {
#pragma unroll
  for (int o = 32; o; o >>= 1) v += __shfl_xor(v, o, 64);
  return v;
}
DEV int waveSumI(int v) {
#pragma unroll
  for (int o = 32; o; o >>= 1) v += __shfl_xor(v, o, 64);
  return v;
}
DEV void blockStatMax(float v, float* __restrict__ slot64, float* sred4, int flatBlk) {
  v = waveMax(v);
  const int tid = threadIdx.x;
  if ((tid & 63) == 0) sred4[tid >> 6] = v;
  __syncthreads();
  if (tid == 0) {
    float m = fmaxf(fmaxf(sred4[0], sred4[1]), fmaxf(sred4[2], sred4[3]));
    atomicMaxF(&slot64[flatBlk & 63], m);
  }
}
DEV float slotMax64(const float* __restrict__ s) {
  float m = 0.f;
#pragma unroll
  for (int i = 0; i < 64; ++i) m = fmaxf(m, s[i]);
  return m;
}
DEV f32x4 ld4(const void* p, int i4, int isf32) {
  if (isf32) return ((const f32x4*)p)[i4];
  ushort4 u = ((const ushort4*)p)[i4];
  return (f32x4){bf2f(u.x), bf2f(u.y), bf2f(u.z), bf2f(u.w)};
}
DEV void gll16(const void* g, void* l) {
  __builtin_amdgcn_global_load_lds((__attribute__((address_space(1))) void*)(g),
                                   (__attribute__((address_space(3))) void*)(l),
                                   16, 0, 0);
}
DEV unsigned ldsaddr(const void* p) {
  return (unsigned)(size_t)(__attribute__((address_space(3))) const void*)p;
}
DEV unsigned quadsel(unsigned a, unsigned b, unsigned c, unsigned d, int idx) {
  unsigned lo = (idx & 1) ? b : a;
  unsigned hi = (idx & 1) ? d : c;
  return (idx & 2) ? hi : lo;
}

__global__ void detect_f32(const u16* __restrict__ x, int* __restrict__ flag) {
  const int tid = threadIdx.x;
  int cnt = 0;
#pragma unroll
  for (int i = 0; i < 16; ++i) {
    u16 u = x[tid * 16 + i];
    if ((u & 0x7f80u) >= 0x4380u) ++cnt;
  }
  cnt = waveSumI(cnt);
  if (tid == 0) flag[0] = (cnt > 16) ? 1 : 0;
}

struct AJobs { const void* p[13]; int n4[13]; int bstart[14]; };

__global__ __launch_bounds__(256) void absmax_multi(AJobs J, float* __restrict__ M,
                                                    const int* __restrict__ flagp) {
  __shared__ float sred[4];
  const int isf32 = flagp[0];
  const int blk = blockIdx.x, tid = threadIdx.x;
  int j = 0;
  while (j < 12 && blk >= J.bstart[j + 1]) ++j;
  const int lb = blk - J.bstart[j];
  const int nb = J.bstart[j + 1] - J.bstart[j];
  float mx = 0.f;
  const void* p = J.p[j];
  for (int i = lb * 256 + tid; i < J.n4[j]; i += nb * 256) {
    f32x4 v = ld4(p, i, isf32);
    mx = fmaxf(mx, fmaxf(fmaxf(fabsf(v.x), fabsf(v.y)),
                         fmaxf(fabsf(v.z), fabsf(v.w))));
  }
  blockStatMax(mx, M + j * 64, sred, lb);
}

__global__ __launch_bounds__(256) void quant_in_signed(
    const void* __restrict__ in, int8_t* __restrict__ out,
    const float* __restrict__ mp, const int* __restrict__ flagp, int n4) {
  const int isf32 = flagp[0];
  const float s = fmaxf(slotMax64(mp), 1e-8f) / 127.0f;
  char4* op = (char4*)out;
  for (int i = blockIdx.x * 256 + threadIdx.x; i < n4; i += gridDim.x * 256) {
    f32x4 v = ld4(in, i, isf32);
    char4 q;
    q.x = (signed char)fminf(fmaxf(rintf(v.x / s), -128.f), 127.f);
    q.y = (signed char)fminf(fmaxf(rintf(v.y / s), -128.f), 127.f);
    q.z = (signed char)fminf(fmaxf(rintf(v.z / s), -128.f), 127.f);
    q.w = (signed char)fminf(fmaxf(rintf(v.w / s), -128.f), 127.f);
    op[i] = q;
  }
}

struct WJobs { const void* in[5]; int8_t* out[5]; int mslot[5]; int n4[5]; int bstart[6]; };

__global__ __launch_bounds__(256) void quant_w_multi(WJobs J, const float* __restrict__ M,
                                                     const int* __restrict__ flagp) {
  const int isf32 = flagp[0];
  const int blk = blockIdx.x, tid = threadIdx.x;
  int j = 0;
  while (j < 4 && blk >= J.bstart[j + 1]) ++j;
  const int lb = blk - J.bstart[j];
  const int nb = J.bstart[j + 1] - J.bstart[j];
  const float s = fmaxf(slotMax64(M + J.mslot[j] * 64), 1e-8f) / 127.0f;
  const void* p = J.in[j];
  char4* o = (char4*)J.out[j];
  for (int i = lb * 256 + tid; i < J.n4[j]; i += nb * 256) {
    f32x4 v = ld4(p, i, isf32);
    char4 q;
    q.x = (signed char)fminf(fmaxf(rintf(v.x / s), -127.f), 127.f);
    q.y = (signed char)fminf(fmaxf(rintf(v.y / s), -127.f), 127.f);
    q.z = (signed char)fminf(fmaxf(rintf(v.z / s), -127.f), 127.f);
    q.w = (signed char)fminf(fmaxf(rintf(v.w / s), -127.f), 127.f);
    o[i] = q;
  }
}

__global__ __launch_bounds__(256) void quant_w2_rs(
    const void* __restrict__ w2, int8_t* __restrict__ out,
    const float* __restrict__ mp, const int* __restrict__ flagp,
    int* __restrict__ rowsum) {
  const int isf32 = flagp[0];
  const int row = blockIdx.x, tid = threadIdx.x;
  const float s = fmaxf(slotMax64(mp), 1e-8f) / 127.0f;
  char4* op = (char4*)(out + (size_t)row * 4096);
  int sum = 0;
  for (int i = tid; i < 1024; i += 256) {
    f32x4 v = ld4(w2, row * 1024 + i, isf32);
    char4 q;
    q.x = (signed char)fminf(fmaxf(rintf(v.x / s), -127.f), 127.f);
    q.y = (signed char)fminf(fmaxf(rintf(v.y / s), -127.f), 127.f);
    q.z = (signed char)fminf(fmaxf(rintf(v.z / s), -127.f), 127.f);
    q.w = (signed char)fminf(fmaxf(rintf(v.w / s), -127.f), 127.f);
    op[i] = q;
    sum += (int)q.x + (int)q.y + (int)q.z + (int)q.w;
  }
  sum = waveSumI(sum);
  __shared__ int rs4[4];
  if ((tid & 63) == 0) rs4[tid >> 6] = sum;
  __syncthreads();
  if (tid == 0) rowsum[row] = rs4[0] + rs4[1] + rs4[2] + rs4[3];
}

struct BJobs { const void* in[6]; float* out[6]; int mslot[6]; int n4[6]; };

__global__ __launch_bounds__(256) void fq_bias_multi(BJobs J, const float* __restrict__ M,
                                                     const int* __restrict__ flagp) {
  const int isf32 = flagp[0];
  const int j = blockIdx.x;
  const float s = fmaxf(slotMax64(M + J.mslot[j] * 64), 1e-8f) / 127.0f;
  float* o = J.out[j];
  for (int i = threadIdx.x; i < J.n4[j]; i += 256) {
    f32x4 v = ld4(J.in[j], i, isf32);
    f32x4 r;
    r.x = fminf(fmaxf(rintf(v.x / s), -128.f), 127.f) * s;
    r.y = fminf(fmaxf(rintf(v.y / s), -128.f), 127.f) * s;
    r.z = fminf(fmaxf(rintf(v.z / s), -128.f), 127.f) * s;
    r.w = fminf(fmaxf(rintf(v.w / s), -128.f), 127.f) * s;
    *(f32x4*)(o + i * 4) = r;
  }
}

__global__ __launch_bounds__(256) void quant_f32_signed(
    const float* __restrict__ in, int8_t* __restrict__ out,
    const float* __restrict__ mp, float pre, int n4) {
  const float s = fmaxf(slotMax64(mp) * pre, 1e-8f) / 127.0f;
  const f32x4* ip = (const f32x4*)in;
  char4* op = (char4*)out;
  for (int i = blockIdx.x * 256 + threadIdx.x; i < n4; i += gridDim.x * 256) {
    f32x4 v = ip[i];
    char4 q;
    q.x = (signed char)fminf(fmaxf(rintf(v.x * pre / s), -128.f), 127.f);
    q.y = (signed char)fminf(fmaxf(rintf(v.y * pre / s), -128.f), 127.f);
    q.z = (signed char)fminf(fmaxf(rintf(v.z * pre / s), -128.f), 127.f);
    q.w = (signed char)fminf(fmaxf(rintf(v.w * pre / s), -128.f), 127.f);
    op[i] = q;
  }
}

__global__ __launch_bounds__(256) void quant_v_t(
    const float* __restrict__ V, int8_t* __restrict__ Vt,
    const float* __restrict__ mp) {
  __shared__ float tile[64][65];
  const int bh = blockIdx.x, st = blockIdx.y;
  const int b = bh >> 4, h = bh & 15;
  const int tid = threadIdx.x;
  const float s = fmaxf(slotMax64(mp), 1e-8f) / 127.0f;
  const int r = tid >> 2, c = (tid & 3) * 16;
  const float* src = V + ((size_t)(b * 1024 + st * 64 + r)) * 1024 + h * 64 + c;
#pragma unroll
  for (int g = 0; g < 4; ++g) {
    f32x4 v = *(const f32x4*)(src + g * 4);
    tile[r][c + g * 4 + 0] = v.x;
    tile[r][c + g * 4 + 1] = v.y;
    tile[r][c + g * 4 + 2] = v.z;
    tile[r][c + g * 4 + 3] = v.w;
  }
  __syncthreads();
  unsigned wds[4];
#pragma unroll
  for (int g = 0; g < 4; ++g) {
    unsigned wd = 0;
#pragma unroll
    for (int k = 0; k < 4; ++k) {
      float v = tile[c + g * 4 + k][r];
      int q = (int)fminf(fmaxf(rintf(v / s), -128.f), 127.f);
      wd |= ((unsigned)(unsigned char)(signed char)q) << (8 * k);
    }
    wds[g] = wd;
  }
  i32x4 ov = {(int)wds[0], (int)wds[1], (int)wds[2], (int)wds[3]};
  *(i32x4*)(Vt + ((size_t)((b * 16 + h) * 64 + r)) * 1024 + st * 64 + c) = ov;
}

// ---------------- int8 GEMM (4-buffer, distance-3, asm ds_read) --------------
// mode 0: store f32 Cf, stat->mOut ; mode 1: stats only ; mode 2: requant u8-128
__global__ __launch_bounds__(256) void gemm_i8(
    const int8_t* __restrict__ A, const int8_t* __restrict__ B,
    float* __restrict__ Cf, int8_t* __restrict__ Cq,
    const float* __restrict__ mA, float preA, float qmaxA,
    const float* __restrict__ mB,
    const float* __restrict__ bias, const int* __restrict__ extra,
    int relu, int mode, float* __restrict__ mOut, int K, int O) {
  __shared__ __align__(16) int8_t smem[4][16384];  // per buf: A[128][64] | B[128][64]
  __shared__ float sred[4];
  const int tid = threadIdx.x;
  const int nb = blockIdx.x, ob = blockIdx.y;
  const int w = tid >> 6, lane = tid & 63, l15 = lane & 15, quad = lane >> 4;
  const int wr = w >> 1, wc = w & 1;
  i32x4 acc[4][4];
#pragma unroll
  for (int i = 0; i < 4; ++i)
#pragma unroll
    for (int j = 0; j < 4; ++j) acc[i][j] = (i32x4){0, 0, 0, 0};
  const int r0 = tid >> 2, c0 = (tid & 3) * 16;
  const int8_t* Ab = A + (size_t)(nb * 128) * K;
  const int8_t* Bb = B + (size_t)(ob * 128) * K;
  const int nk = K >> 6;
  const int aoffl = (wr * 64 + l15) * 64 + quad * 16;
  const int boffl = 8192 + (wc * 64 + l15) * 64 + quad * 16;
  // prologue: stage tiles 0..2
  for (int t = 0; t < 3 && t < nk; ++t) {
    const size_t kt0 = (size_t)t << 6;
    int8_t* d = smem[t];
    gll16(Ab + (size_t)r0 * K + kt0 + c0, d + tid * 16);
    gll16(Ab + (size_t)(r0 + 64) * K + kt0 + c0, d + 4096 + tid * 16);
    gll16(Bb + (size_t)r0 * K + kt0 + c0, d + 8192 + tid * 16);
    gll16(Bb + (size_t)(r0 + 64) * K + kt0 + c0, d + 12288 + tid * 16);
  }
  for (int i = 0; i < nk; ++i) {
    const int infl = nk - 1 - i;  // tiles still prefetched beyond i
    if (infl >= 2)      asm volatile("s_waitcnt vmcnt(8)" ::: "memory");
    else if (infl == 1) asm volatile("s_waitcnt vmcnt(4)" ::: "memory");
    else                asm volatile("s_waitcnt vmcnt(0)" ::: "memory");
    asm volatile("s_barrier" ::: "memory");
    if (i + 3 < nk) {
      const size_t kt0 = (size_t)(i + 3) << 6;
      int8_t* d = smem[(i + 3) & 3];
      gll16(Ab + (size_t)r0 * K + kt0 + c0, d + tid * 16);
      gll16(Ab + (size_t)(r0 + 64) * K + kt0 + c0, d + 4096 + tid * 16);
      gll16(Bb + (size_t)r0 * K + kt0 + c0, d + 8192 + tid * 16);
      gll16(Bb + (size_t)(r0 + 64) * K + kt0 + c0, d + 12288 + tid * 16);
    }
    const unsigned a_addr = ldsaddr(smem[i & 3] + aoffl);
    const unsigned b_addr = ldsaddr(smem[i & 3] + boffl);
    i32x4 af[4], bf[4];
    asm volatile("ds_read_b128 %0, %1 offset:0"    : "=v"(af[0]) : "v"(a_addr));
    asm volatile("ds_read_b128 %0, %1 offset:1024" : "=v"(af[1]) : "v"(a_addr));
    asm volatile("ds_read_b128 %0, %1 offset:2048" : "=v"(af[2]) : "v"(a_addr));
    asm volatile("ds_read_b128 %0, %1 offset:3072" : "=v"(af[3]) : "v"(a_addr));
    asm volatile("ds_read_b128 %0, %1 offset:0"    : "=v"(bf[0]) : "v"(b_addr));
    asm volatile("ds_read_b128 %0, %1 offset:1024" : "=v"(bf[1]) : "v"(b_addr));
    asm volatile("ds_read_b128 %0, %1 offset:2048" : "=v"(bf[2]) : "v"(b_addr));
    asm volatile("ds_read_b128 %0, %1 offset:3072" : "=v"(bf[3]) : "v"(b_addr));
    asm volatile("s_waitcnt lgkmcnt(0)" ::: "memory");
    __builtin_amdgcn_sched_barrier(0);
#pragma unroll
    for (int mt = 0; mt < 4; ++mt)
#pragma unroll
      for (int nt = 0; nt < 4; ++nt)
        acc[mt][nt] = __builtin_amdgcn_mfma_i32_16x16x64_i8(af[mt], bf[nt], acc[mt][nt], 0, 0, 0);
  }
  const float sA = fmaxf(slotMax64(mA) * preA, 1e-8f) / qmaxA;
  const float sB = fmaxf(slotMax64(mB), 1e-8f) / 127.0f;
  const float sAB = sA * sB;
  const float sq = (mode == 2) ? (fmaxf(slotMax64(mOut), 1e-8f) / 255.0f) : 1.0f;
  float lmax = 0.f;
#pragma unroll
  for (int mt = 0; mt < 4; ++mt) {
    const int n = nb * 128 + wr * 64 + mt * 16 + quad * 4;
#pragma unroll
    for (int nt = 0; nt < 4; ++nt) {
      const int o = ob * 128 + wc * 64 + nt * 16 + l15;
      const int ext = extra ? 128 * extra[o] : 0;
      const float bv = bias[o];
#pragma unroll
      for (int r = 0; r < 4; ++r) {
        float v = sAB * (float)(acc[mt][nt][r] + ext) + bv;
        if (relu) v = fmaxf(v, 0.f);
        if (mode == 0) Cf[(size_t)(n + r) * O + o] = v;
        else if (mode == 2) {
          int q = (int)fminf(fmaxf(rintf(v / sq), 0.f), 255.f) - 128;
          Cq[(size_t)(n + r) * O + o] = (int8_t)q;
        }
        lmax = fmaxf(lmax, fabsf(v));
      }
    }
  }
  if (mode != 2)
    blockStatMax(lmax, mOut, sred, nb + ob * gridDim.x);
}

// --------------------------- fused causal attention --------------------------
// R12: R9 structure + R11-style pipeline. grid 1024 = (b,h,pair,rowhalf);
// waves 0-1: hi tile (qt=15-p), waves 2-3: lo tile (qt=p), shared K/V staging.
// 4-buffer K/V, distance-3 prefetch, counted vmcnt + raw barrier per kt,
// asm ds_read for Q/K/V fragments. ktmax = 15-pidx >= 8 so prologue depth 3
// is always valid.
__global__ __launch_bounds__(256, 4) void attn_fused(
    const int8_t* __restrict__ Qq, const int8_t* __restrict__ Kq,
    const int8_t* __restrict__ Vt, float* __restrict__ ctx,
    const float* __restrict__ M, float* __restrict__ mOut) {
  __shared__ __align__(16) int8_t qtile[4096];
  __shared__ __align__(16) int8_t ktile[4][4096];
  __shared__ __align__(16) int8_t vtile[4][4096];
  __shared__ float sred[4];
  const int tid = threadIdx.x, bid = blockIdx.x;
  const int pidx = bid & 7, rh = (bid >> 3) & 1, h = (bid >> 4) & 15, b = bid >> 8;
  const int qthi = 15 - pidx, qtlo = pidx, ktmax = qthi;
  const int w = tid >> 6, lane = tid & 63, l15 = lane & 15, quad = lane >> 4;
  const int wqt = (w < 2) ? qthi : qtlo;
  const int wrow0 = rh * 32 + (w & 1) * 16;
  const float sqs = fmaxf(slotMax64(M + 13 * 64) * 0.125f, 1e-8f) / 127.0f;
  const float sk = fmaxf(slotMax64(M + 14 * 64), 1e-8f) / 127.0f;
  const float sv = fmaxf(slotMax64(M + 15 * 64), 1e-8f) / 127.0f;
  const float sqk = sqs * sk;
  const float s_attn = 1.0f / 127.0f;  // softmax global max == 1.0 exactly
  const int r0 = tid >> 2, c0 = (tid & 3) * 16;
  const int8_t* Kbase = Kq + (size_t)(b * 1024) * 1024 + h * 64 + c0;
  const int8_t* Vbase = Vt + (size_t)((b * 16 + h) * 64 + r0) * 1024 + c0;
  const unsigned fragoff = (unsigned)(l15 * 64 + quad * 16);  // frag base in a tile buf

  // ---- Phase A prologue: stage Q (1 item) + K tiles 0..2 (3 items) ----
  {
    const int qt_s = (r0 < 32) ? qthi : qtlo;
    const int qrow_g = qt_s * 64 + rh * 32 + (r0 & 31);
    gll16(Qq + ((size_t)(b * 1024 + qrow_g)) * 1024 + h * 64 + c0, qtile + tid * 16);
  }
#pragma unroll
  for (int t = 0; t < 3; ++t)
    gll16(Kbase + (size_t)(t * 64 + r0) * 1024, ktile[t] + tid * 16);
  asm volatile("s_waitcnt vmcnt(3)" ::: "memory");  // my Q landed
  asm volatile("s_barrier" ::: "memory");           // all waves' Q landed
  i32x4 aq;
  {
    const unsigned qa = ldsaddr(qtile) + (unsigned)((w * 16 + l15) * 64 + quad * 16);
    asm volatile("ds_read_b128 %0, %1 offset:0" : "=v"(aq) : "v"(qa));
    asm volatile("s_waitcnt lgkmcnt(0)" ::: "memory");
  }
  const int qrow = wqt * 64 + wrow0 + l15;  // this lane's q-row (0..1023)

  // ---- Phase A: swapped QK^T; per-lane online (m,l); pipelined K staging ----
  float m_l = -1e30f, l_l = 0.f;
  for (int kt = 0; kt <= ktmax; ++kt) {
    if (kt + 2 <= ktmax)      asm volatile("s_waitcnt vmcnt(2)" ::: "memory");
    else if (kt + 1 <= ktmax) asm volatile("s_waitcnt vmcnt(1)" ::: "memory");
    else                      asm volatile("s_waitcnt vmcnt(0)" ::: "memory");
    asm volatile("s_barrier" ::: "memory");
    if (kt + 3 <= ktmax)
      gll16(Kbase + (size_t)((kt + 3) * 64 + r0) * 1024, ktile[(kt + 3) & 3] + tid * 16);
    if (kt <= wqt) {
      const unsigned ka = ldsaddr(ktile[kt & 3]) + fragoff;
      i32x4 bk[4];
      asm volatile("ds_read_b128 %0, %1 offset:0"    : "=v"(bk[0]) : "v"(ka));
      asm volatile("ds_read_b128 %0, %1 offset:1024" : "=v"(bk[1]) : "v"(ka));
      asm volatile("ds_read_b128 %0, %1 offset:2048" : "=v"(bk[2]) : "v"(ka));
      asm volatile("ds_read_b128 %0, %1 offset:3072" : "=v"(bk[3]) : "v"(ka));
      asm volatile("s_waitcnt lgkmcnt(0)" ::: "memory");
      __builtin_amdgcn_sched_barrier(0);
      const int kc0 = kt * 64 + quad * 4;
      float sc[4][4];
#pragma unroll
      for (int nt = 0; nt < 4; ++nt) {
        i32x4 z = {0, 0, 0, 0};
        i32x4 d = __builtin_amdgcn_mfma_i32_16x16x64_i8(bk[nt], aq, z, 0, 0, 0);
        if (kt == wqt) {
#pragma unroll
          for (int r = 0; r < 4; ++r)
            sc[nt][r] = (kc0 + nt * 16 + r <= qrow) ? sqk * (float)d[r] : -1e30f;
        } else {
#pragma unroll
          for (int r = 0; r < 4; ++r) sc[nt][r] = sqk * (float)d[r];
        }
      }
      float vm = sc[0][0];
#pragma unroll
      for (int nt = 0; nt < 4; ++nt)
#pragma unroll
        for (int r = 0; r < 4; ++r) vm = fmaxf(vm, sc[nt][r]);
      const float mn = fmaxf(m_l, vm);
      float sum = 0.f;
#pragma unroll
      for (int nt = 0; nt < 4; ++nt)
#pragma unroll
        for (int r = 0; r < 4; ++r) sum += __expf(sc[nt][r] - mn);
      l_l = l_l * __expf(m_l - mn) + sum;
      m_l = mn;
    }
  }
  // merge the 4 quads (lanes sharing l15 hold the same q-row)
#pragma unroll
  for (int off = 16; off <= 32; off <<= 1) {
    float om = __shfl_xor(m_l, off, 64);
    float ol = __shfl_xor(l_l, off, 64);
    float mn = fmaxf(m_l, om);
    l_l = l_l * __expf(m_l - mn) + ol * __expf(om - mn);
    m_l = mn;
  }
  const float rl127 = 127.0f / l_l;  // P*127 in [0,127] exactly -> no clamps

  // ---- Phase B: recompute, quantize P in-register, quad-transpose, PV ----
  __syncthreads();  // all waves done reading Phase-A buffers (vmcnt already 0)
#pragma unroll
  for (int t = 0; t < 3; ++t) {
    gll16(Kbase + (size_t)(t * 64 + r0) * 1024, ktile[t] + tid * 16);
    gll16(Vbase + t * 64, vtile[t] + tid * 16);
  }
  i32x4 cacc[4] = {{0, 0, 0, 0}, {0, 0, 0, 0}, {0, 0, 0, 0}, {0, 0, 0, 0}};
  for (int kt = 0; kt <= ktmax; ++kt) {
    if (kt + 2 <= ktmax)      asm volatile("s_waitcnt vmcnt(4)" ::: "memory");
    else if (kt + 1 <= ktmax) asm volatile("s_waitcnt vmcnt(2)" ::: "memory");
    else                      asm volatile("s_waitcnt vmcnt(0)" ::: "memory");
    asm volatile("s_barrier" ::: "memory");
    if (kt + 3 <= ktmax) {
      gll16(Kbase + (size_t)((kt + 3) * 64 + r0) * 1024, ktile[(kt + 3) & 3] + tid * 16);
      gll16(Vbase + (kt + 3) * 64, vtile[(kt + 3) & 3] + tid * 16);
    }
    if (kt <= wqt) {
      const unsigned ka = ldsaddr(ktile[kt & 3]) + fragoff;
      const unsigned va = ldsaddr(vtile[kt & 3]) + fragoff;
      i32x4 bk[4], bv[4];
      asm volatile("ds_read_b128 %0, %1 offset:0"    : "=v"(bk[0]) : "v"(ka));
      asm volatile("ds_read_b128 %0, %1 offset:1024" : "=v"(bk[1]) : "v"(ka));
      asm volatile("ds_read_b128 %0, %1 offset:2048" : "=v"(bk[2]) : "v"(ka));
      asm volatile("ds_read_b128 %0, %1 offset:3072" : "=v"(bk[3]) : "v"(ka));
      asm volatile("ds_read_b128 %0, %1 offset:0"    : "=v"(bv[0]) : "v"(va));
      asm volatile("ds_read_b128 %0, %1 offset:1024" : "=v"(bv[1]) : "v"(va));
      asm volatile("ds_read_b128 %0, %1 offset:2048" : "=v"(bv[2]) : "v"(va));
      asm volatile("ds_read_b128 %0, %1 offset:3072" : "=v"(bv[3]) : "v"(va));
      asm volatile("s_waitcnt lgkmcnt(0)" ::: "memory");
      __builtin_amdgcn_sched_barrier(0);
      const int kc0 = kt * 64 + quad * 4;
      unsigned Dw[4];
#pragma unroll
      for (int nt = 0; nt < 4; ++nt) {
        i32x4 z = {0, 0, 0, 0};
        i32x4 d = __builtin_amdgcn_mfma_i32_16x16x64_i8(bk[nt], aq, z, 0, 0, 0);
        unsigned wd = 0;
        if (kt == wqt) {
#pragma unroll
          for (int r = 0; r < 4; ++r) {
            float e = (kc0 + nt * 16 + r <= qrow)
                          ? __expf(sqk * (float)d[r] - m_l) * rl127 : 0.f;
            wd |= ((unsigned)(int)rintf(e)) << (8 * r);
          }
        } else {
#pragma unroll
          for (int r = 0; r < 4; ++r) {
            float e = __expf(sqk * (float)d[r] - m_l) * rl127;
            wd |= ((unsigned)(int)rintf(e)) << (8 * r);
          }
        }
        Dw[nt] = wd;
      }
      // 4x4 quad-transpose: pf[j] (k=quad*16+4j..) <- Dw[quad] @ lane quad'=j
      unsigned selfv = quadsel(Dw[0], Dw[1], Dw[2], Dw[3], quad);
      unsigned rv1 = (unsigned)__shfl_xor(
          (int)quadsel(Dw[0], Dw[1], Dw[2], Dw[3], quad ^ 1), 16, 64);
      unsigned rv2 = (unsigned)__shfl_xor(
          (int)quadsel(Dw[0], Dw[1], Dw[2], Dw[3], quad ^ 2), 32, 64);
      unsigned rv3 = (unsigned)__shfl_xor(
          (int)quadsel(Dw[0], Dw[1], Dw[2], Dw[3], quad ^ 3), 48, 64);
      i32x4 pf;
#pragma unroll
      for (int j = 0; j < 4; ++j) {
        const int t = j ^ quad;
        pf[j] = (int)((t == 0) ? selfv : (t == 1) ? rv1 : (t == 2) ? rv2 : rv3);
      }
#pragma unroll
      for (int nt = 0; nt < 4; ++nt)
        cacc[nt] = __builtin_amdgcn_mfma_i32_16x16x64_i8(pf, bv[nt], cacc[nt], 0, 0, 0);
    }
  }
  const float sc2 = s_attn * sv;
  float lmax = 0.f;
  const int orow0 = wqt * 64 + wrow0 + quad * 4;
#pragma unroll
  for (int nt = 0; nt < 4; ++nt) {
    const int d = nt * 16 + l15;
#pragma unroll
    for (int r = 0; r < 4; ++r) {
      float v = sc2 * (float)cacc[nt][r];
      ctx[((size_t)(b * 1024 + orow0 + r)) * 1024 + h * 64 + d] = v;
      lmax = fmaxf(lmax, fabsf(v));
    }
  }
  blockStatMax(lmax, mOut, sred, bid);
}

// --------------------------- residual + layernorm ---------------------------
__global__ __launch_bounds__(256) void ln_res(
    const int8_t* __restrict__ xq, const float* __restrict__ mx,
    const float* __restrict__ ao, const float* __restrict__ ma,
    float* __restrict__ x1, float* __restrict__ mOut) {
  __shared__ float red[8];
  __shared__ float sred[4];
  const int row = blockIdx.x, tid = threadIdx.x;
  const float sx = fmaxf(slotMax64(mx), 1e-8f) / 127.0f;
  const float sa = fmaxf(slotMax64(ma), 1e-8f) / 127.0f;
  char4 xv = *(const char4*)(xq + (size_t)row * 1024 + tid * 4);
  f32x4 av = *(const f32x4*)(ao + (size_t)row * 1024 + tid * 4);
  float t[4];
  t[0] = (float)xv.x * sx + fminf(fmaxf(rintf(av.x / sa), -128.f), 127.f) * sa;
  t[1] = (float)xv.y * sx + fminf(fmaxf(rintf(av.y / sa), -128.f), 127.f) * sa;
  t[2] = (float)xv.z * sx + fminf(fmaxf(rintf(av.z / sa), -128.f), 127.f) * sa;
  t[3] = (float)xv.w * sx + fminf(fmaxf(rintf(av.w / sa), -128.f), 127.f) * sa;
  float s = waveSum(t[0] + t[1] + t[2] + t[3]);
  if ((tid & 63) == 0) red[tid >> 6] = s;
  __syncthreads();
  const float mean = (red[0] + red[1] + red[2] + red[3]) * (1.0f / 1024.0f);
  float vs = 0.f;
#pragma unroll
  for (int i = 0; i < 4; ++i) { float d = t[i] - mean; vs += d * d; }
  vs = waveSum(vs);
  if ((tid & 63) == 0) red[4 + (tid >> 6)] = vs;
  __syncthreads();
  const float var = (red[4] + red[5] + red[6] + red[7]) * (1.0f / 1024.0f);
  const float rs = sqrtf(var + 1e-5f);
  f32x4 o;
  o.x = (t[0] - mean) / rs;
  o.y = (t[1] - mean) / rs;
  o.z = (t[2] - mean) / rs;
  o.w = (t[3] - mean) / rs;
  *(f32x4*)(x1 + (size_t)row * 1024 + tid * 4) = o;
  float lmax = fmaxf(fmaxf(fabsf(o.x), fabsf(o.y)), fmaxf(fabsf(o.z), fabsf(o.w)));
  blockStatMax(lmax, mOut, sred, row);
}

__global__ __launch_bounds__(256) void ln_final(
    const int8_t* __restrict__ x1q, const float* __restrict__ mx1,
    const float* __restrict__ h2, const float* __restrict__ mh2,
    float* __restrict__ out) {
  __shared__ float red[8];
  const int row = blockIdx.x, tid = threadIdx.x;
  const float s1 = fmaxf(slotMax64(mx1), 1e-8f) / 127.0f;
  const float s2 = fmaxf(slotMax64(mh2), 1e-8f) / 127.0f;
  char4 xv = *(const char4*)(x1q + (size_t)row * 1024 + tid * 4);
  f32x4 hv = *(const f32x4*)(h2 + (size_t)row * 1024 + tid * 4);
  float t[4];
  t[0] = (float)xv.x * s1 + fminf(fmaxf(rintf(hv.x / s2), -128.f), 127.f) * s2;
  t[1] = (float)xv.y * s1 + fminf(fmaxf(rintf(hv.y / s2), -128.f), 127.f) * s2;
  t[2] = (float)xv.z * s1 + fminf(fmaxf(rintf(hv.z / s2), -128.f), 127.f) * s2;
  t[3] = (float)xv.w * s1 + fminf(fmaxf(rintf(hv.w / s2), -128.f), 127.f) * s2;
  float s = waveSum(t[0] + t[1] + t[2] + t[3]);
  if ((tid & 63) == 0) red[tid >> 6] = s;
  __syncthreads();
  const float mean = (red[0] + red[1] + red[2] + red[3]) * (1.0f / 1024.0f);
  float vs = 0.f;
#pragma unroll
  for (int i = 0; i < 4; ++i) { float d = t[i] - mean; vs += d * d; }
  vs = waveSum(vs);
  if ((tid & 63) == 0) red[4 + (tid >> 6)] = vs;
  __syncthreads();
  const float var = (red[4] + red[5] + red[6] + red[7]) * (1.0f / 1024.0f);
  const float rs = sqrtf(var + 1e-5f);
  f32x4 o;
  o.x = (t[0] - mean) / rs;
  o.y = (t[1] - mean) / rs;
  o.z = (t[2] - mean) / rs;
  o.w = (t[3] - mean) / rs;
  *(f32x4*)(out + (size_t)row * 1024 + tid * 4) = o;
}

// --------------------------- workspace layout (52.07 MB peak) ----------------
static constexpr size_t MB = 1u << 20;
static constexpr size_t OFF_M     = 0;          // 21 stats x 64 f32 slots
static constexpr size_t OFF_FLAG  = 6400;
static constexpr size_t OFF_BIASQ = 8192;
static constexpr size_t OFF_BIASK = OFF_BIASQ + 4096;
static constexpr size_t OFF_BIASV = OFF_BIASK + 4096;
static constexpr size_t OFF_BIASO = OFF_BIASV + 4096;
static constexpr size_t OFF_BIAS1 = OFF_BIASO + 4096;
static constexpr size_t OFF_BIAS2 = OFF_BIAS1 + 16384;
static constexpr size_t OFF_RS    = OFF_BIAS2 + 4096;
static constexpr size_t OFF_XQ    = 65536;
static constexpr size_t OFF_WQQ   = OFF_XQ  + 4 * MB;
static constexpr size_t OFF_WKQ   = OFF_WQQ + 1 * MB;
static constexpr size_t OFF_WVQ   = OFF_WKQ + 1 * MB;
static constexpr size_t OFF_WOQ   = OFF_WVQ + 1 * MB;
static constexpr size_t OFF_W1Q   = OFF_WOQ + 1 * MB;
static constexpr size_t OFF_W2Q   = OFF_W1Q + 4 * MB;
static constexpr size_t OFF_X1Q   = OFF_W2Q + 4 * MB;
static constexpr size_t OFF_A1    = OFF_X1Q + 4 * MB;     // arena1, 16 MB
static constexpr size_t OFF_A2    = OFF_A1 + 16 * MB;     // arena2 (f32), 16 MB

extern "C" void kernel_launch(void* const* d_in, const int* in_sizes, int n_in,
                              void* d_out, int out_size, void* d_ws, size_t ws_size,
                              hipStream_t stream) {
  (void)n_in; (void)out_size; (void)ws_size;
  char* ws = (char*)d_ws;
  float* M = (float*)(ws + OFF_M);
  int* FLAG = (int*)(ws + OFF_FLAG);
  float* BIASQ = (float*)(ws + OFF_BIASQ);
  float* BIASK = (float*)(ws + OFF_BIASK);
  float* BIASV = (float*)(ws + OFF_BIASV);
  float* BIASO = (float*)(ws + OFF_BIASO);
  float* BIAS1 = (float*)(ws + OFF_BIAS1);
  float* BIAS2 = (float*)(ws + OFF_BIAS2);
  int* RS = (int*)(ws + OFF_RS);
  int8_t* XQ  = (int8_t*)(ws + OFF_XQ);
  int8_t* WQQ = (int8_t*)(ws + OFF_WQQ);
  int8_t* WKQ = (int8_t*)(ws + OFF_WKQ);
  int8_t* WVQ = (int8_t*)(ws + OFF_WVQ);
  int8_t* WOQ = (int8_t*)(ws + OFF_WOQ);
  int8_t* W1Q = (int8_t*)(ws + OFF_W1Q);
  int8_t* W2Q = (int8_t*)(ws + OFF_W2Q);
  int8_t* X1Q = (int8_t*)(ws + OFF_X1Q);
  int8_t* QQ   = (int8_t*)(ws + OFF_A1);
  int8_t* KQQ  = (int8_t*)(ws + OFF_A1 + 4 * MB);
  int8_t* VT   = (int8_t*)(ws + OFF_A1 + 8 * MB);
  int8_t* CTXQ = (int8_t*)(ws + OFF_A1 + 12 * MB);
  float*  X1F  = (float*)(ws + OFF_A1);
  int8_t* HQ   = (int8_t*)(ws + OFF_A1);
  float* FBUF = (float*)(ws + OFF_A2);   // serial reuse: QF/KF/VF/ctx/ao/h2

  hipMemsetAsync(M, 0, 8192, stream);
  detect_f32<<<1, 64, 0, stream>>>((const u16*)d_in[0], FLAG);

  AJobs aj;
  const int ablk[13] = {512, 128, 1, 128, 1, 128, 1, 128, 1, 512, 2, 512, 1};
  int bs = 0;
  for (int i = 0; i < 13; ++i) {
    aj.p[i] = d_in[i];
    aj.n4[i] = in_sizes[i] / 4;
    aj.bstart[i] = bs;
    bs += ablk[i];
  }
  aj.bstart[13] = bs;
  absmax_multi<<<bs, 256, 0, stream>>>(aj, M, FLAG);

  quant_in_signed<<<1024, 256, 0, stream>>>(d_in[0], XQ, M + 0 * 64, FLAG, in_sizes[0] / 4);

  WJobs wj;
  const int widx[5] = {1, 3, 5, 7, 9};
  int8_t* wout[5] = {WQQ, WKQ, WVQ, WOQ, W1Q};
  const int wblk[5] = {128, 128, 128, 128, 512};
  int wb = 0;
  for (int j = 0; j < 5; ++j) {
    wj.in[j] = d_in[widx[j]];
    wj.out[j] = wout[j];
    wj.mslot[j] = widx[j];
    wj.n4[j] = in_sizes[widx[j]] / 4;
    wj.bstart[j] = wb;
    wb += wblk[j];
  }
  wj.bstart[5] = wb;
  quant_w_multi<<<wb, 256, 0, stream>>>(wj, M, FLAG);
  quant_w2_rs<<<1024, 256, 0, stream>>>(d_in[11], W2Q, M + 11 * 64, FLAG, RS);

  BJobs bj;
  const int bidx[6] = {2, 4, 6, 8, 10, 12};
  float* bout[6] = {BIASQ, BIASK, BIASV, BIASO, BIAS1, BIAS2};
  for (int j = 0; j < 6; ++j) {
    bj.in[j] = d_in[bidx[j]];
    bj.out[j] = bout[j];
    bj.mslot[j] = bidx[j];
    bj.n4[j] = in_sizes[bidx[j]] / 4;
  }
  fq_bias_multi<<<6, 256, 0, stream>>>(bj, M, FLAG);

  // Q/K/V projections through the 16MB f32 arena, strictly serial
  gemm_i8<<<dim3(32, 8), 256, 0, stream>>>(XQ, WQQ, FBUF, nullptr, M + 0 * 64, 1.f, 127.f, M + 1 * 64, BIASQ, nullptr, 0, 0, M + 13 * 64, 1024, 1024);
  quant_f32_signed<<<2048, 256, 0, stream>>>(FBUF, QQ, M + 13 * 64, 0.125f, 1024 * 1024);
  gemm_i8<<<dim3(32, 8), 256, 0, stream>>>(XQ, WKQ, FBUF, nullptr, M + 0 * 64, 1.f, 127.f, M + 3 * 64, BIASK, nullptr, 0, 0, M + 14 * 64, 1024, 1024);
  quant_f32_signed<<<2048, 256, 0, stream>>>(FBUF, KQQ, M + 14 * 64, 1.0f, 1024 * 1024);
  gemm_i8<<<dim3(32, 8), 256, 0, stream>>>(XQ, WVQ, FBUF, nullptr, M + 0 * 64, 1.f, 127.f, M + 5 * 64, BIASV, nullptr, 0, 0, M + 15 * 64, 1024, 1024);
  quant_v_t<<<dim3(64, 16), 256, 0, stream>>>(FBUF, VT, M + 15 * 64);

  attn_fused<<<1024, 256, 0, stream>>>(QQ, KQQ, VT, FBUF, M, M + 16 * 64);
  quant_f32_signed<<<2048, 256, 0, stream>>>(FBUF, CTXQ, M + 16 * 64, 1.0f, 1024 * 1024);

  gemm_i8<<<dim3(32, 8), 256, 0, stream>>>(CTXQ, WOQ, FBUF, nullptr, M + 16 * 64, 1.f, 127.f, M + 7 * 64, BIASO, nullptr, 0, 0, M + 17 * 64, 1024, 1024);

  ln_res<<<4096, 256, 0, stream>>>(XQ, M + 0 * 64, FBUF, M + 17 * 64, X1F, M + 18 * 64);
  quant_f32_signed<<<2048, 256, 0, stream>>>(X1F, X1Q, M + 18 * 64, 1.0f, 1024 * 1024);

  gemm_i8<<<dim3(32, 32), 256, 0, stream>>>(X1Q, W1Q, nullptr, nullptr, M + 18 * 64, 1.f, 127.f, M + 9 * 64, BIAS1, nullptr, 1, 1, M + 19 * 64, 1024, 4096);
  gemm_i8<<<dim3(32, 32), 256, 0, stream>>>(X1Q, W1Q, nullptr, HQ,      M + 18 * 64, 1.f, 127.f, M + 9 * 64, BIAS1, nullptr, 1, 2, M + 19 * 64, 1024, 4096);

  gemm_i8<<<dim3(32, 8), 256, 0, stream>>>(HQ, W2Q, FBUF, nullptr, M + 19 * 64, 1.f, 255.f, M + 11 * 64, BIAS2, RS, 0, 0, M + 20 * 64, 4096, 1024);

  ln_final<<<4096, 256, 0, stream>>>(X1Q, M + 18 * 64, FBUF, M + 20 * 64, (float*)d_out);
}

// Round 6
// 428.732 us; speedup vs baseline: 1.0888x; 1.0097x over previous
//
#include <hip/hip_runtime.h>
#include <stdint.h>
#include <stddef.h>

// ---------------------------------------------------------------------------
// Fully fake-quantized transformer block on MI355X (gfx950).
// i8 MFMA GEMMs (exact i32 acc), flash-style fused attention.
// R13: gemm_i8 retile 128x128 -> 128x64. N=1024 GEMMs ran grid 256 = 1
// block/CU (12.5% occupancy cap) - latency-bound with nothing to overlap
// barriers/epilogue. Now grid doubles (512 / MLP1 2048), 2-3 blocks/CU with
// INDEPENDENT barriers; per-iter 8 MFMA, 3 loads/tile (vmcnt 6/3/0), LDS
// 4x12KB=48KB, acc 2x4 frags. Same verified 16x16 MFMA lane mapping; wave w
// owns rows [w*32,w*32+32) x 64 cols. Callers: grid.y doubles. Attn untouched.
// R12 (kept): attn 4-buffer dist-3 pipeline, counted vmcnt, asm ds_read.
// R11 (kept): gemm asm-ds_read + counted-vmcnt pipeline (drain fix).
// R9  (kept): attn block=(b,h,pair,rowhalf), swapped QK^T, reg P-transpose.
// ---------------------------------------------------------------------------

typedef unsigned short u16;
typedef __attribute__((ext_vector_type(4))) int   i32x4;
typedef __attribute__((ext_vector_type(4))) float f32x4;

#define DEV __device__ __forceinline__

DEV float bf2f(u16 u) { return __uint_as_float(((unsigned)u) << 16); }
DEV void atomicMaxF(float* p, float v) { atomicMax((unsigned*)p, __float_as_uint(v)); }
DEV float waveMax(float v) {
#pragma unroll
  for (int o = 32; o; o >>= 1) v = fmaxf(v, __shfl_xor(v, o, 64));
  return v;
}
DEV float waveSum(float v) {
#pragma unroll
  for (int o = 32; o; o >>= 1) v += __shfl_xor(v, o, 64);
  return v;
}
DEV int waveSumI(int v) {
#pragma unroll
  for (int o = 32; o; o >>= 1) v += __shfl_xor(v, o, 64);
  return v;
}
DEV void blockStatMax(float v, float* __restrict__ slot64, float* sred4, int flatBlk) {
  v = waveMax(v);
  const int tid = threadIdx.x;
  if ((tid & 63) == 0) sred4[tid >> 6] = v;
  __syncthreads();
  if (tid == 0) {
    float m = fmaxf(fmaxf(sred4[0], sred4[1]), fmaxf(sred4[2], sred4[3]));
    atomicMaxF(&slot64[flatBlk & 63], m);
  }
}
DEV float slotMax64(const float* __restrict__ s) {
  float m = 0.f;
#pragma unroll
  for (int i = 0; i < 64; ++i) m = fmaxf(m, s[i]);
  return m;
}
DEV f32x4 ld4(const void* p, int i4, int isf32) {
  if (isf32) return ((const f32x4*)p)[i4];
  ushort4 u = ((const ushort4*)p)[i4];
  return (f32x4){bf2f(u.x), bf2f(u.y), bf2f(u.z), bf2f(u.w)};
}
DEV void gll16(const void* g, void* l) {
  __builtin_amdgcn_global_load_lds((__attribute__((address_space(1))) void*)(g),
                                   (__attribute__((address_space(3))) void*)(l),
                                   16, 0, 0);
}
DEV unsigned ldsaddr(const void* p) {
  return (unsigned)(size_t)(__attribute__((address_space(3))) const void*)p;
}
DEV unsigned quadsel(unsigned a, unsigned b, unsigned c, unsigned d, int idx) {
  unsigned lo = (idx & 1) ? b : a;
  unsigned hi = (idx & 1) ? d : c;
  return (idx & 2) ? hi : lo;
}

__global__ void detect_f32(const u16* __restrict__ x, int* __restrict__ flag) {
  const int tid = threadIdx.x;
  int cnt = 0;
#pragma unroll
  for (int i = 0; i < 16; ++i) {
    u16 u = x[tid * 16 + i];
    if ((u & 0x7f80u) >= 0x4380u) ++cnt;
  }
  cnt = waveSumI(cnt);
  if (tid == 0) flag[0] = (cnt > 16) ? 1 : 0;
}

struct AJobs { const void* p[13]; int n4[13]; int bstart[14]; };

__global__ __launch_bounds__(256) void absmax_multi(AJobs J, float* __restrict__ M,
                                                    const int* __restrict__ flagp) {
  __shared__ float sred[4];
  const int isf32 = flagp[0];
  const int blk = blockIdx.x, tid = threadIdx.x;
  int j = 0;
  while (j < 12 && blk >= J.bstart[j + 1]) ++j;
  const int lb = blk - J.bstart[j];
  const int nb = J.bstart[j + 1] - J.bstart[j];
  float mx = 0.f;
  const void* p = J.p[j];
  for (int i = lb * 256 + tid; i < J.n4[j]; i += nb * 256) {
    f32x4 v = ld4(p, i, isf32);
    mx = fmaxf(mx, fmaxf(fmaxf(fabsf(v.x), fabsf(v.y)),
                         fmaxf(fabsf(v.z), fabsf(v.w))));
  }
  blockStatMax(mx, M + j * 64, sred, lb);
}

__global__ __launch_bounds__(256) void quant_in_signed(
    const void* __restrict__ in, int8_t* __restrict__ out,
    const float* __restrict__ mp, const int* __restrict__ flagp, int n4) {
  const int isf32 = flagp[0];
  const float s = fmaxf(slotMax64(mp), 1e-8f) / 127.0f;
  char4* op = (char4*)out;
  for (int i = blockIdx.x * 256 + threadIdx.x; i < n4; i += gridDim.x * 256) {
    f32x4 v = ld4(in, i, isf32);
    char4 q;
    q.x = (signed char)fminf(fmaxf(rintf(v.x / s), -128.f), 127.f);
    q.y = (signed char)fminf(fmaxf(rintf(v.y / s), -128.f), 127.f);
    q.z = (signed char)fminf(fmaxf(rintf(v.z / s), -128.f), 127.f);
    q.w = (signed char)fminf(fmaxf(rintf(v.w / s), -128.f), 127.f);
    op[i] = q;
  }
}

struct WJobs { const void* in[5]; int8_t* out[5]; int mslot[5]; int n4[5]; int bstart[6]; };

__global__ __launch_bounds__(256) void quant_w_multi(WJobs J, const float* __restrict__ M,
                                                     const int* __restrict__ flagp) {
  const int isf32 = flagp[0];
  const int blk = blockIdx.x, tid = threadIdx.x;
  int j = 0;
  while (j < 4 && blk >= J.bstart[j + 1]) ++j;
  const int lb = blk - J.bstart[j];
  const int nb = J.bstart[j + 1] - J.bstart[j];
  const float s = fmaxf(slotMax64(M + J.mslot[j] * 64), 1e-8f) / 127.0f;
  const void* p = J.in[j];
  char4* o = (char4*)J.out[j];
  for (int i = lb * 256 + tid; i < J.n4[j]; i += nb * 256) {
    f32x4 v = ld4(p, i, isf32);
    char4 q;
    q.x = (signed char)fminf(fmaxf(rintf(v.x / s), -127.f), 127.f);
    q.y = (signed char)fminf(fmaxf(rintf(v.y / s), -127.f), 127.f);
    q.z = (signed char)fminf(fmaxf(rintf(v.z / s), -127.f), 127.f);
    q.w = (signed char)fminf(fmaxf(rintf(v.w / s), -127.f), 127.f);
    o[i] = q;
  }
}

__global__ __launch_bounds__(256) void quant_w2_rs(
    const void* __restrict__ w2, int8_t* __restrict__ out,
    const float* __restrict__ mp, const int* __restrict__ flagp,
    int* __restrict__ rowsum) {
  const int isf32 = flagp[0];
  const int row = blockIdx.x, tid = threadIdx.x;
  const float s = fmaxf(slotMax64(mp), 1e-8f) / 127.0f;
  char4* op = (char4*)(out + (size_t)row * 4096);
  int sum = 0;
  for (int i = tid; i < 1024; i += 256) {
    f32x4 v = ld4(w2, row * 1024 + i, isf32);
    char4 q;
    q.x = (signed char)fminf(fmaxf(rintf(v.x / s), -127.f), 127.f);
    q.y = (signed char)fminf(fmaxf(rintf(v.y / s), -127.f), 127.f);
    q.z = (signed char)fminf(fmaxf(rintf(v.z / s), -127.f), 127.f);
    q.w = (signed char)fminf(fmaxf(rintf(v.w / s), -127.f), 127.f);
    op[i] = q;
    sum += (int)q.x + (int)q.y + (int)q.z + (int)q.w;
  }
  sum = waveSumI(sum);
  __shared__ int rs4[4];
  if ((tid & 63) == 0) rs4[tid >> 6] = sum;
  __syncthreads();
  if (tid == 0) rowsum[row] = rs4[0] + rs4[1] + rs4[2] + rs4[3];
}

struct BJobs { const void* in[6]; float* out[6]; int mslot[6]; int n4[6]; };

__global__ __launch_bounds__(256) void fq_bias_multi(BJobs J, const float* __restrict__ M,
                                                     const int* __restrict__ flagp) {
  const int isf32 = flagp[0];
  const int j = blockIdx.x;
  const float s = fmaxf(slotMax64(M + J.mslot[j] * 64), 1e-8f) / 127.0f;
  float* o = J.out[j];
  for (int i = threadIdx.x; i < J.n4[j]; i += 256) {
    f32x4 v = ld4(J.in[j], i, isf32);
    f32x4 r;
    r.x = fminf(fmaxf(rintf(v.x / s), -128.f), 127.f) * s;
    r.y = fminf(fmaxf(rintf(v.y / s), -128.f), 127.f) * s;
    r.z = fminf(fmaxf(rintf(v.z / s), -128.f), 127.f) * s;
    r.w = fminf(fmaxf(rintf(v.w / s), -128.f), 127.f) * s;
    *(f32x4*)(o + i * 4) = r;
  }
}

__global__ __launch_bounds__(256) void quant_f32_signed(
    const float* __restrict__ in, int8_t* __restrict__ out,
    const float* __restrict__ mp, float pre, int n4) {
  const float s = fmaxf(slotMax64(mp) * pre, 1e-8f) / 127.0f;
  const f32x4* ip = (const f32x4*)in;
  char4* op = (char4*)out;
  for (int i = blockIdx.x * 256 + threadIdx.x; i < n4; i += gridDim.x * 256) {
    f32x4 v = ip[i];
    char4 q;
    q.x = (signed char)fminf(fmaxf(rintf(v.x * pre / s), -128.f), 127.f);
    q.y = (signed char)fminf(fmaxf(rintf(v.y * pre / s), -128.f), 127.f);
    q.z = (signed char)fminf(fmaxf(rintf(v.z * pre / s), -128.f), 127.f);
    q.w = (signed char)fminf(fmaxf(rintf(v.w * pre / s), -128.f), 127.f);
    op[i] = q;
  }
}

__global__ __launch_bounds__(256) void quant_v_t(
    const float* __restrict__ V, int8_t* __restrict__ Vt,
    const float* __restrict__ mp) {
  __shared__ float tile[64][65];
  const int bh = blockIdx.x, st = blockIdx.y;
  const int b = bh >> 4, h = bh & 15;
  const int tid = threadIdx.x;
  const float s = fmaxf(slotMax64(mp), 1e-8f) / 127.0f;
  const int r = tid >> 2, c = (tid & 3) * 16;
  const float* src = V + ((size_t)(b * 1024 + st * 64 + r)) * 1024 + h * 64 + c;
#pragma unroll
  for (int g = 0; g < 4; ++g) {
    f32x4 v = *(const f32x4*)(src + g * 4);
    tile[r][c + g * 4 + 0] = v.x;
    tile[r][c + g * 4 + 1] = v.y;
    tile[r][c + g * 4 + 2] = v.z;
    tile[r][c + g * 4 + 3] = v.w;
  }
  __syncthreads();
  unsigned wds[4];
#pragma unroll
  for (int g = 0; g < 4; ++g) {
    unsigned wd = 0;
#pragma unroll
    for (int k = 0; k < 4; ++k) {
      float v = tile[c + g * 4 + k][r];
      int q = (int)fminf(fmaxf(rintf(v / s), -128.f), 127.f);
      wd |= ((unsigned)(unsigned char)(signed char)q) << (8 * k);
    }
    wds[g] = wd;
  }
  i32x4 ov = {(int)wds[0], (int)wds[1], (int)wds[2], (int)wds[3]};
  *(i32x4*)(Vt + ((size_t)((b * 16 + h) * 64 + r)) * 1024 + st * 64 + c) = ov;
}

// ------------- int8 GEMM (128x64 tile, 4-buffer, distance-3, asm ds_read) ----
// mode 0: store f32 Cf, stat->mOut ; mode 1: stats only ; mode 2: requant u8-128
// Per buffer: A[128][64] (8KB) | B[64][64] (4KB). 3 gll16/tile -> vmcnt 6/3/0.
// Wave w owns output rows [w*32, w*32+32) x all 64 cols (acc 2x4 frags).
__global__ __launch_bounds__(256) void gemm_i8(
    const int8_t* __restrict__ A, const int8_t* __restrict__ B,
    float* __restrict__ Cf, int8_t* __restrict__ Cq,
    const float* __restrict__ mA, float preA, float qmaxA,
    const float* __restrict__ mB,
    const float* __restrict__ bias, const int* __restrict__ extra,
    int relu, int mode, float* __restrict__ mOut, int K, int O) {
  __shared__ __align__(16) int8_t smem[4][12288];
  __shared__ float sred[4];
  const int tid = threadIdx.x;
  const int nb = blockIdx.x, ob = blockIdx.y;
  const int w = tid >> 6, lane = tid & 63, l15 = lane & 15, quad = lane >> 4;
  i32x4 acc[2][4];
#pragma unroll
  for (int i = 0; i < 2; ++i)
#pragma unroll
    for (int j = 0; j < 4; ++j) acc[i][j] = (i32x4){0, 0, 0, 0};
  const int r0 = tid >> 2, c0 = (tid & 3) * 16;
  const int8_t* Ab = A + (size_t)(nb * 128) * K;
  const int8_t* Bb = B + (size_t)(ob * 64) * K;
  const int nk = K >> 6;
  const int aoffl = (w * 32 + l15) * 64 + quad * 16;
  const int boffl = 8192 + l15 * 64 + quad * 16;
  // prologue: stage tiles 0..2 (3 loads each)
  for (int t = 0; t < 3 && t < nk; ++t) {
    const size_t kt0 = (size_t)t << 6;
    int8_t* d = smem[t];
    gll16(Ab + (size_t)r0 * K + kt0 + c0, d + tid * 16);
    gll16(Ab + (size_t)(r0 + 64) * K + kt0 + c0, d + 4096 + tid * 16);
    gll16(Bb + (size_t)r0 * K + kt0 + c0, d + 8192 + tid * 16);
  }
  for (int i = 0; i < nk; ++i) {
    const int infl = nk - 1 - i;  // prefetched tiles beyond i
    if (infl >= 2)      asm volatile("s_waitcnt vmcnt(6)" ::: "memory");
    else if (infl == 1) asm volatile("s_waitcnt vmcnt(3)" ::: "memory");
    else                asm volatile("s_waitcnt vmcnt(0)" ::: "memory");
    asm volatile("s_barrier" ::: "memory");
    if (i + 3 < nk) {
      const size_t kt0 = (size_t)(i + 3) << 6;
      int8_t* d = smem[(i + 3) & 3];
      gll16(Ab + (size_t)r0 * K + kt0 + c0, d + tid * 16);
      gll16(Ab + (size_t)(r0 + 64) * K + kt0 + c0, d + 4096 + tid * 16);
      gll16(Bb + (size_t)r0 * K + kt0 + c0, d + 8192 + tid * 16);
    }
    const unsigned a_addr = ldsaddr(smem[i & 3] + aoffl);
    const unsigned b_addr = ldsaddr(smem[i & 3] + boffl);
    i32x4 af[2], bf[4];
    asm volatile("ds_read_b128 %0, %1 offset:0"    : "=v"(af[0]) : "v"(a_addr));
    asm volatile("ds_read_b128 %0, %1 offset:1024" : "=v"(af[1]) : "v"(a_addr));
    asm volatile("ds_read_b128 %0, %1 offset:0"    : "=v"(bf[0]) : "v"(b_addr));
    asm volatile("ds_read_b128 %0, %1 offset:1024" : "=v"(bf[1]) : "v"(b_addr));
    asm volatile("ds_read_b128 %0, %1 offset:2048" : "=v"(bf[2]) : "v"(b_addr));
    asm volatile("ds_read_b128 %0, %1 offset:3072" : "=v"(bf[3]) : "v"(b_addr));
    asm volatile("s_waitcnt lgkmcnt(0)" ::: "memory");
    __builtin_amdgcn_sched_barrier(0);
#pragma unroll
    for (int mt = 0; mt < 2; ++mt)
#pragma unroll
      for (int nt = 0; nt < 4; ++nt)
        acc[mt][nt] = __builtin_amdgcn_mfma_i32_16x16x64_i8(af[mt], bf[nt], acc[mt][nt], 0, 0, 0);
  }
  const float sA = fmaxf(slotMax64(mA) * preA, 1e-8f) / qmaxA;
  const float sB = fmaxf(slotMax64(mB), 1e-8f) / 127.0f;
  const float sAB = sA * sB;
  const float sq = (mode == 2) ? (fmaxf(slotMax64(mOut), 1e-8f) / 255.0f) : 1.0f;
  float lmax = 0.f;
#pragma unroll
  for (int mt = 0; mt < 2; ++mt) {
    const int n = nb * 128 + w * 32 + mt * 16 + quad * 4;
#pragma unroll
    for (int nt = 0; nt < 4; ++nt) {
      const int o = ob * 64 + nt * 16 + l15;
      const int ext = extra ? 128 * extra[o] : 0;
      const float bv = bias[o];
#pragma unroll
      for (int r = 0; r < 4; ++r) {
        float v = sAB * (float)(acc[mt][nt][r] + ext) + bv;
        if (relu) v = fmaxf(v, 0.f);
        if (mode == 0) Cf[(size_t)(n + r) * O + o] = v;
        else if (mode == 2) {
          int q = (int)fminf(fmaxf(rintf(v / sq), 0.f), 255.f) - 128;
          Cq[(size_t)(n + r) * O + o] = (int8_t)q;
        }
        lmax = fmaxf(lmax, fabsf(v));
      }
    }
  }
  if (mode != 2)
    blockStatMax(lmax, mOut, sred, nb + ob * gridDim.x);
}

// --------------------------- fused causal attention --------------------------
// R12: R9 structure + R11-style pipeline. grid 1024 = (b,h,pair,rowhalf);
// waves 0-1: hi tile (qt=15-p), waves 2-3: lo tile (qt=p), shared K/V staging.
// 4-buffer K/V, distance-3 prefetch, counted vmcnt + raw barrier per kt,
// asm ds_read for Q/K/V fragments. ktmax = 15-pidx >= 8 so prologue depth 3
// is always valid.
__global__ __launch_bounds__(256, 4) void attn_fused(
    const int8_t* __restrict__ Qq, const int8_t* __restrict__ Kq,
    const int8_t* __restrict__ Vt, float* __restrict__ ctx,
    const float* __restrict__ M, float* __restrict__ mOut) {
  __shared__ __align__(16) int8_t qtile[4096];
  __shared__ __align__(16) int8_t ktile[4][4096];
  __shared__ __align__(16) int8_t vtile[4][4096];
  __shared__ float sred[4];
  const int tid = threadIdx.x, bid = blockIdx.x;
  const int pidx = bid & 7, rh = (bid >> 3) & 1, h = (bid >> 4) & 15, b = bid >> 8;
  const int qthi = 15 - pidx, qtlo = pidx, ktmax = qthi;
  const int w = tid >> 6, lane = tid & 63, l15 = lane & 15, quad = lane >> 4;
  const int wqt = (w < 2) ? qthi : qtlo;
  const int wrow0 = rh * 32 + (w & 1) * 16;
  const float sqs = fmaxf(slotMax64(M + 13 * 64) * 0.125f, 1e-8f) / 127.0f;
  const float sk = fmaxf(slotMax64(M + 14 * 64), 1e-8f) / 127.0f;
  const float sv = fmaxf(slotMax64(M + 15 * 64), 1e-8f) / 127.0f;
  const float sqk = sqs * sk;
  const float s_attn = 1.0f / 127.0f;  // softmax global max == 1.0 exactly
  const int r0 = tid >> 2, c0 = (tid & 3) * 16;
  const int8_t* Kbase = Kq + (size_t)(b * 1024) * 1024 + h * 64 + c0;
  const int8_t* Vbase = Vt + (size_t)((b * 16 + h) * 64 + r0) * 1024 + c0;
  const unsigned fragoff = (unsigned)(l15 * 64 + quad * 16);  // frag base in a tile buf

  // ---- Phase A prologue: stage Q (1 item) + K tiles 0..2 (3 items) ----
  {
    const int qt_s = (r0 < 32) ? qthi : qtlo;
    const int qrow_g = qt_s * 64 + rh * 32 + (r0 & 31);
    gll16(Qq + ((size_t)(b * 1024 + qrow_g)) * 1024 + h * 64 + c0, qtile + tid * 16);
  }
#pragma unroll
  for (int t = 0; t < 3; ++t)
    gll16(Kbase + (size_t)(t * 64 + r0) * 1024, ktile[t] + tid * 16);
  asm volatile("s_waitcnt vmcnt(3)" ::: "memory");  // my Q landed
  asm volatile("s_barrier" ::: "memory");           // all waves' Q landed
  i32x4 aq;
  {
    const unsigned qa = ldsaddr(qtile) + (unsigned)((w * 16 + l15) * 64 + quad * 16);
    asm volatile("ds_read_b128 %0, %1 offset:0" : "=v"(aq) : "v"(qa));
    asm volatile("s_waitcnt lgkmcnt(0)" ::: "memory");
  }
  const int qrow = wqt * 64 + wrow0 + l15;  // this lane's q-row (0..1023)

  // ---- Phase A: swapped QK^T; per-lane online (m,l); pipelined K staging ----
  float m_l = -1e30f, l_l = 0.f;
  for (int kt = 0; kt <= ktmax; ++kt) {
    if (kt + 2 <= ktmax)      asm volatile("s_waitcnt vmcnt(2)" ::: "memory");
    else if (kt + 1 <= ktmax) asm volatile("s_waitcnt vmcnt(1)" ::: "memory");
    else                      asm volatile("s_waitcnt vmcnt(0)" ::: "memory");
    asm volatile("s_barrier" ::: "memory");
    if (kt + 3 <= ktmax)
      gll16(Kbase + (size_t)((kt + 3) * 64 + r0) * 1024, ktile[(kt + 3) & 3] + tid * 16);
    if (kt <= wqt) {
      const unsigned ka = ldsaddr(ktile[kt & 3]) + fragoff;
      i32x4 bk[4];
      asm volatile("ds_read_b128 %0, %1 offset:0"    : "=v"(bk[0]) : "v"(ka));
      asm volatile("ds_read_b128 %0, %1 offset:1024" : "=v"(bk[1]) : "v"(ka));
      asm volatile("ds_read_b128 %0, %1 offset:2048" : "=v"(bk[2]) : "v"(ka));
      asm volatile("ds_read_b128 %0, %1 offset:3072" : "=v"(bk[3]) : "v"(ka));
      asm volatile("s_waitcnt lgkmcnt(0)" ::: "memory");
      __builtin_amdgcn_sched_barrier(0);
      const int kc0 = kt * 64 + quad * 4;
      float sc[4][4];
#pragma unroll
      for (int nt = 0; nt < 4; ++nt) {
        i32x4 z = {0, 0, 0, 0};
        i32x4 d = __builtin_amdgcn_mfma_i32_16x16x64_i8(bk[nt], aq, z, 0, 0, 0);
        if (kt == wqt) {
#pragma unroll
          for (int r = 0; r < 4; ++r)
            sc[nt][r] = (kc0 + nt * 16 + r <= qrow) ? sqk * (float)d[r] : -1e30f;
        } else {
#pragma unroll
          for (int r = 0; r < 4; ++r) sc[nt][r] = sqk * (float)d[r];
        }
      }
      float vm = sc[0][0];
#pragma unroll
      for (int nt = 0; nt < 4; ++nt)
#pragma unroll
        for (int r = 0; r < 4; ++r) vm = fmaxf(vm, sc[nt][r]);
      const float mn = fmaxf(m_l, vm);
      float sum = 0.f;
#pragma unroll
      for (int nt = 0; nt < 4; ++nt)
#pragma unroll
        for (int r = 0; r < 4; ++r) sum += __expf(sc[nt][r] - mn);
      l_l = l_l * __expf(m_l - mn) + sum;
      m_l = mn;
    }
  }
  // merge the 4 quads (lanes sharing l15 hold the same q-row)
#pragma unroll
  for (int off = 16; off <= 32; off <<= 1) {
    float om = __shfl_xor(m_l, off, 64);
    float ol = __shfl_xor(l_l, off, 64);
    float mn = fmaxf(m_l, om);
    l_l = l_l * __expf(m_l - mn) + ol * __expf(om - mn);
    m_l = mn;
  }
  const float rl127 = 127.0f / l_l;  // P*127 in [0,127] exactly -> no clamps

  // ---- Phase B: recompute, quantize P in-register, quad-transpose, PV ----
  __syncthreads();  // all waves done reading Phase-A buffers (vmcnt already 0)
#pragma unroll
  for (int t = 0; t < 3; ++t) {
    gll16(Kbase + (size_t)(t * 64 + r0) * 1024, ktile[t] + tid * 16);
    gll16(Vbase + t * 64, vtile[t] + tid * 16);
  }
  i32x4 cacc[4] = {{0, 0, 0, 0}, {0, 0, 0, 0}, {0, 0, 0, 0}, {0, 0, 0, 0}};
  for (int kt = 0; kt <= ktmax; ++kt) {
    if (kt + 2 <= ktmax)      asm volatile("s_waitcnt vmcnt(4)" ::: "memory");
    else if (kt + 1 <= ktmax) asm volatile("s_waitcnt vmcnt(2)" ::: "memory");
    else                      asm volatile("s_waitcnt vmcnt(0)" ::: "memory");
    asm volatile("s_barrier" ::: "memory");
    if (kt + 3 <= ktmax) {
      gll16(Kbase + (size_t)((kt + 3) * 64 + r0) * 1024, ktile[(kt + 3) & 3] + tid * 16);
      gll16(Vbase + (kt + 3) * 64, vtile[(kt + 3) & 3] + tid * 16);
    }
    if (kt <= wqt) {
      const unsigned ka = ldsaddr(ktile[kt & 3]) + fragoff;
      const unsigned va = ldsaddr(vtile[kt & 3]) + fragoff;
      i32x4 bk[4], bv[4];
      asm volatile("ds_read_b128 %0, %1 offset:0"    : "=v"(bk[0]) : "v"(ka));
      asm volatile("ds_read_b128 %0, %1 offset:1024" : "=v"(bk[1]) : "v"(ka));
      asm volatile("ds_read_b128 %0, %1 offset:2048" : "=v"(bk[2]) : "v"(ka));
      asm volatile("ds_read_b128 %0, %1 offset:3072" : "=v"(bk[3]) : "v"(ka));
      asm volatile("ds_read_b128 %0, %1 offset:0"    : "=v"(bv[0]) : "v"(va));
      asm volatile("ds_read_b128 %0, %1 offset:1024" : "=v"(bv[1]) : "v"(va));
      asm volatile("ds_read_b128 %0, %1 offset:2048" : "=v"(bv[2]) : "v"(va));
      asm volatile("ds_read_b128 %0, %1 offset:3072" : "=v"(bv[3]) : "v"(va));
      asm volatile("s_waitcnt lgkmcnt(0)" ::: "memory");
      __builtin_amdgcn_sched_barrier(0);
      const int kc0 = kt * 64 + quad * 4;
      unsigned Dw[4];
#pragma unroll
      for (int nt = 0; nt < 4; ++nt) {
        i32x4 z = {0, 0, 0, 0};
        i32x4 d = __builtin_amdgcn_mfma_i32_16x16x64_i8(bk[nt], aq, z, 0, 0, 0);
        unsigned wd = 0;
        if (kt == wqt) {
#pragma unroll
          for (int r = 0; r < 4; ++r) {
            float e = (kc0 + nt * 16 + r <= qrow)
                          ? __expf(sqk * (float)d[r] - m_l) * rl127 : 0.f;
            wd |= ((unsigned)(int)rintf(e)) << (8 * r);
          }
        } else {
#pragma unroll
          for (int r = 0; r < 4; ++r) {
            float e = __expf(sqk * (float)d[r] - m_l) * rl127;
            wd |= ((unsigned)(int)rintf(e)) << (8 * r);
          }
        }
        Dw[nt] = wd;
      }
      // 4x4 quad-transpose: pf[j] (k=quad*16+4j..) <- Dw[quad] @ lane quad'=j
      unsigned selfv = quadsel(Dw[0], Dw[1], Dw[2], Dw[3], quad);
      unsigned rv1 = (unsigned)__shfl_xor(
          (int)quadsel(Dw[0], Dw[1], Dw[2], Dw[3], quad ^ 1), 16, 64);
      unsigned rv2 = (unsigned)__shfl_xor(
          (int)quadsel(Dw[0], Dw[1], Dw[2], Dw[3], quad ^ 2), 32, 64);
      unsigned rv3 = (unsigned)__shfl_xor(
          (int)quadsel(Dw[0], Dw[1], Dw[2], Dw[3], quad ^ 3), 48, 64);
      i32x4 pf;
#pragma unroll
      for (int j = 0; j < 4; ++j) {
        const int t = j ^ quad;
        pf[j] = (int)((t == 0) ? selfv : (t == 1) ? rv1 : (t == 2) ? rv2 : rv3);
      }
#pragma unroll
      for (int nt = 0; nt < 4; ++nt)
        cacc[nt] = __builtin_amdgcn_mfma_i32_16x16x64_i8(pf, bv[nt], cacc[nt], 0, 0, 0);
    }
  }
  const float sc2 = s_attn * sv;
  float lmax = 0.f;
  const int orow0 = wqt * 64 + wrow0 + quad * 4;
#pragma unroll
  for (int nt = 0; nt < 4; ++nt) {
    const int d = nt * 16 + l15;
#pragma unroll
    for (int r = 0; r < 4; ++r) {
      float v = sc2 * (float)cacc[nt][r];
      ctx[((size_t)(b * 1024 + orow0 + r)) * 1024 + h * 64 + d] = v;
      lmax = fmaxf(lmax, fabsf(v));
    }
  }
  blockStatMax(lmax, mOut, sred, bid);
}

// --------------------------- residual + layernorm ---------------------------
__global__ __launch_bounds__(256) void ln_res(
    const int8_t* __restrict__ xq, const float* __restrict__ mx,
    const float* __restrict__ ao, const float* __restrict__ ma,
    float* __restrict__ x1, float* __restrict__ mOut) {
  __shared__ float red[8];
  __shared__ float sred[4];
  const int row = blockIdx.x, tid = threadIdx.x;
  const float sx = fmaxf(slotMax64(mx), 1e-8f) / 127.0f;
  const float sa = fmaxf(slotMax64(ma), 1e-8f) / 127.0f;
  char4 xv = *(const char4*)(xq + (size_t)row * 1024 + tid * 4);
  f32x4 av = *(const f32x4*)(ao + (size_t)row * 1024 + tid * 4);
  float t[4];
  t[0] = (float)xv.x * sx + fminf(fmaxf(rintf(av.x / sa), -128.f), 127.f) * sa;
  t[1] = (float)xv.y * sx + fminf(fmaxf(rintf(av.y / sa), -128.f), 127.f) * sa;
  t[2] = (float)xv.z * sx + fminf(fmaxf(rintf(av.z / sa), -128.f), 127.f) * sa;
  t[3] = (float)xv.w * sx + fminf(fmaxf(rintf(av.w / sa), -128.f), 127.f) * sa;
  float s = waveSum(t[0] + t[1] + t[2] + t[3]);
  if ((tid & 63) == 0) red[tid >> 6] = s;
  __syncthreads();
  const float mean = (red[0] + red[1] + red[2] + red[3]) * (1.0f / 1024.0f);
  float vs = 0.f;
#pragma unroll
  for (int i = 0; i < 4; ++i) { float d = t[i] - mean; vs += d * d; }
  vs = waveSum(vs);
  if ((tid & 63) == 0) red[4 + (tid >> 6)] = vs;
  __syncthreads();
  const float var = (red[4] + red[5] + red[6] + red[7]) * (1.0f / 1024.0f);
  const float rs = sqrtf(var + 1e-5f);
  f32x4 o;
  o.x = (t[0] - mean) / rs;
  o.y = (t[1] - mean) / rs;
  o.z = (t[2] - mean) / rs;
  o.w = (t[3] - mean) / rs;
  *(f32x4*)(x1 + (size_t)row * 1024 + tid * 4) = o;
  float lmax = fmaxf(fmaxf(fabsf(o.x), fabsf(o.y)), fmaxf(fabsf(o.z), fabsf(o.w)));
  blockStatMax(lmax, mOut, sred, row);
}

__global__ __launch_bounds__(256) void ln_final(
    const int8_t* __restrict__ x1q, const float* __restrict__ mx1,
    const float* __restrict__ h2, const float* __restrict__ mh2,
    float* __restrict__ out) {
  __shared__ float red[8];
  const int row = blockIdx.x, tid = threadIdx.x;
  const float s1 = fmaxf(slotMax64(mx1), 1e-8f) / 127.0f;
  const float s2 = fmaxf(slotMax64(mh2), 1e-8f) / 127.0f;
  char4 xv = *(const char4*)(x1q + (size_t)row * 1024 + tid * 4);
  f32x4 hv = *(const f32x4*)(h2 + (size_t)row * 1024 + tid * 4);
  float t[4];
  t[0] = (float)xv.x * s1 + fminf(fmaxf(rintf(hv.x / s2), -128.f), 127.f) * s2;
  t[1] = (float)xv.y * s1 + fminf(fmaxf(rintf(hv.y / s2), -128.f), 127.f) * s2;
  t[2] = (float)xv.z * s1 + fminf(fmaxf(rintf(hv.z / s2), -128.f), 127.f) * s2;
  t[3] = (float)xv.w * s1 + fminf(fmaxf(rintf(hv.w / s2), -128.f), 127.f) * s2;
  float s = waveSum(t[0] + t[1] + t[2] + t[3]);
  if ((tid & 63) == 0) red[tid >> 6] = s;
  __syncthreads();
  const float mean = (red[0] + red[1] + red[2] + red[3]) * (1.0f / 1024.0f);
  float vs = 0.f;
#pragma unroll
  for (int i = 0; i < 4; ++i) { float d = t[i] - mean; vs += d * d; }
  vs = waveSum(vs);
  if ((tid & 63) == 0) red[4 + (tid >> 6)] = vs;
  __syncthreads();
  const float var = (red[4] + red[5] + red[6] + red[7]) * (1.0f / 1024.0f);
  const float rs = sqrtf(var + 1e-5f);
  f32x4 o;
  o.x = (t[0] - mean) / rs;
  o.y = (t[1] - mean) / rs;
  o.z = (t[2] - mean) / rs;
  o.w = (t[3] - mean) / rs;
  *(f32x4*)(out + (size_t)row * 1024 + tid * 4) = o;
}

// --------------------------- workspace layout (52.07 MB peak) ----------------
static constexpr size_t MB = 1u << 20;
static constexpr size_t OFF_M     = 0;          // 21 stats x 64 f32 slots
static constexpr size_t OFF_FLAG  = 6400;
static constexpr size_t OFF_BIASQ = 8192;
static constexpr size_t OFF_BIASK = OFF_BIASQ + 4096;
static constexpr size_t OFF_BIASV = OFF_BIASK + 4096;
static constexpr size_t OFF_BIASO = OFF_BIASV + 4096;
static constexpr size_t OFF_BIAS1 = OFF_BIASO + 4096;
static constexpr size_t OFF_BIAS2 = OFF_BIAS1 + 16384;
static constexpr size_t OFF_RS    = OFF_BIAS2 + 4096;
static constexpr size_t OFF_XQ    = 65536;
static constexpr size_t OFF_WQQ   = OFF_XQ  + 4 * MB;
static constexpr size_t OFF_WKQ   = OFF_WQQ + 1 * MB;
static constexpr size_t OFF_WVQ   = OFF_WKQ + 1 * MB;
static constexpr size_t OFF_WOQ   = OFF_WVQ + 1 * MB;
static constexpr size_t OFF_W1Q   = OFF_WOQ + 1 * MB;
static constexpr size_t OFF_W2Q   = OFF_W1Q + 4 * MB;
static constexpr size_t OFF_X1Q   = OFF_W2Q + 4 * MB;
static constexpr size_t OFF_A1    = OFF_X1Q + 4 * MB;     // arena1, 16 MB
static constexpr size_t OFF_A2    = OFF_A1 + 16 * MB;     // arena2 (f32), 16 MB

extern "C" void kernel_launch(void* const* d_in, const int* in_sizes, int n_in,
                              void* d_out, int out_size, void* d_ws, size_t ws_size,
                              hipStream_t stream) {
  (void)n_in; (void)out_size; (void)ws_size;
  char* ws = (char*)d_ws;
  float* M = (float*)(ws + OFF_M);
  int* FLAG = (int*)(ws + OFF_FLAG);
  float* BIASQ = (float*)(ws + OFF_BIASQ);
  float* BIASK = (float*)(ws + OFF_BIASK);
  float* BIASV = (float*)(ws + OFF_BIASV);
  float* BIASO = (float*)(ws + OFF_BIASO);
  float* BIAS1 = (float*)(ws + OFF_BIAS1);
  float* BIAS2 = (float*)(ws + OFF_BIAS2);
  int* RS = (int*)(ws + OFF_RS);
  int8_t* XQ  = (int8_t*)(ws + OFF_XQ);
  int8_t* WQQ = (int8_t*)(ws + OFF_WQQ);
  int8_t* WKQ = (int8_t*)(ws + OFF_WKQ);
  int8_t* WVQ = (int8_t*)(ws + OFF_WVQ);
  int8_t* WOQ = (int8_t*)(ws + OFF_WOQ);
  int8_t* W1Q = (int8_t*)(ws + OFF_W1Q);
  int8_t* W2Q = (int8_t*)(ws + OFF_W2Q);
  int8_t* X1Q = (int8_t*)(ws + OFF_X1Q);
  int8_t* QQ   = (int8_t*)(ws + OFF_A1);
  int8_t* KQQ  = (int8_t*)(ws + OFF_A1 + 4 * MB);
  int8_t* VT   = (int8_t*)(ws + OFF_A1 + 8 * MB);
  int8_t* CTXQ = (int8_t*)(ws + OFF_A1 + 12 * MB);
  float*  X1F  = (float*)(ws + OFF_A1);
  int8_t* HQ   = (int8_t*)(ws + OFF_A1);
  float* FBUF = (float*)(ws + OFF_A2);   // serial reuse: QF/KF/VF/ctx/ao/h2

  hipMemsetAsync(M, 0, 8192, stream);
  detect_f32<<<1, 64, 0, stream>>>((const u16*)d_in[0], FLAG);

  AJobs aj;
  const int ablk[13] = {512, 128, 1, 128, 1, 128, 1, 128, 1, 512, 2, 512, 1};
  int bs = 0;
  for (int i = 0; i < 13; ++i) {
    aj.p[i] = d_in[i];
    aj.n4[i] = in_sizes[i] / 4;
    aj.bstart[i] = bs;
    bs += ablk[i];
  }
  aj.bstart[13] = bs;
  absmax_multi<<<bs, 256, 0, stream>>>(aj, M, FLAG);

  quant_in_signed<<<1024, 256, 0, stream>>>(d_in[0], XQ, M + 0 * 64, FLAG, in_sizes[0] / 4);

  WJobs wj;
  const int widx[5] = {1, 3, 5, 7, 9};
  int8_t* wout[5] = {WQQ, WKQ, WVQ, WOQ, W1Q};
  const int wblk[5] = {128, 128, 128, 128, 512};
  int wb = 0;
  for (int j = 0; j < 5; ++j) {
    wj.in[j] = d_in[widx[j]];
    wj.out[j] = wout[j];
    wj.mslot[j] = widx[j];
    wj.n4[j] = in_sizes[widx[j]] / 4;
    wj.bstart[j] = wb;
    wb += wblk[j];
  }
  wj.bstart[5] = wb;
  quant_w_multi<<<wb, 256, 0, stream>>>(wj, M, FLAG);
  quant_w2_rs<<<1024, 256, 0, stream>>>(d_in[11], W2Q, M + 11 * 64, FLAG, RS);

  BJobs bj;
  const int bidx[6] = {2, 4, 6, 8, 10, 12};
  float* bout[6] = {BIASQ, BIASK, BIASV, BIASO, BIAS1, BIAS2};
  for (int j = 0; j < 6; ++j) {
    bj.in[j] = d_in[bidx[j]];
    bj.out[j] = bout[j];
    bj.mslot[j] = bidx[j];
    bj.n4[j] = in_sizes[bidx[j]] / 4;
  }
  fq_bias_multi<<<6, 256, 0, stream>>>(bj, M, FLAG);

  // Q/K/V projections through the 16MB f32 arena, strictly serial
  gemm_i8<<<dim3(32, 16), 256, 0, stream>>>(XQ, WQQ, FBUF, nullptr, M + 0 * 64, 1.f, 127.f, M + 1 * 64, BIASQ, nullptr, 0, 0, M + 13 * 64, 1024, 1024);
  quant_f32_signed<<<2048, 256, 0, stream>>>(FBUF, QQ, M + 13 * 64, 0.125f, 1024 * 1024);
  gemm_i8<<<dim3(32, 16), 256, 0, stream>>>(XQ, WKQ, FBUF, nullptr, M + 0 * 64, 1.f, 127.f, M + 3 * 64, BIASK, nullptr, 0, 0, M + 14 * 64, 1024, 1024);
  quant_f32_signed<<<2048, 256, 0, stream>>>(FBUF, KQQ, M + 14 * 64, 1.0f, 1024 * 1024);
  gemm_i8<<<dim3(32, 16), 256, 0, stream>>>(XQ, WVQ, FBUF, nullptr, M + 0 * 64, 1.f, 127.f, M + 5 * 64, BIASV, nullptr, 0, 0, M + 15 * 64, 1024, 1024);
  quant_v_t<<<dim3(64, 16), 256, 0, stream>>>(FBUF, VT, M + 15 * 64);

  attn_fused<<<1024, 256, 0, stream>>>(QQ, KQQ, VT, FBUF, M, M + 16 * 64);
  quant_f32_signed<<<2048, 256, 0, stream>>>(FBUF, CTXQ, M + 16 * 64, 1.0f, 1024 * 1024);

  gemm_i8<<<dim3(32, 16), 256, 0, stream>>>(CTXQ, WOQ, FBUF, nullptr, M + 16 * 64, 1.f, 127.f, M + 7 * 64, BIASO, nullptr, 0, 0, M + 17 * 64, 1024, 1024);

  ln_res<<<4096, 256, 0, stream>>>(XQ, M + 0 * 64, FBUF, M + 17 * 64, X1F, M + 18 * 64);
  quant_f32_signed<<<2048, 256, 0, stream>>>(X1F, X1Q, M + 18 * 64, 1.0f, 1024 * 1024);

  gemm_i8<<<dim3(32, 64), 256, 0, stream>>>(X1Q, W1Q, nullptr, nullptr, M + 18 * 64, 1.f, 127.f, M + 9 * 64, BIAS1, nullptr, 1, 1, M + 19 * 64, 1024, 4096);
  gemm_i8<<<dim3(32, 64), 256, 0, stream>>>(X1Q, W1Q, nullptr, HQ,      M + 18 * 64, 1.f, 127.f, M + 9 * 64, BIAS1, nullptr, 1, 2, M + 19 * 64, 1024, 4096);

  gemm_i8<<<dim3(32, 16), 256, 0, stream>>>(HQ, W2Q, FBUF, nullptr, M + 19 * 64, 1.f, 255.f, M + 11 * 64, BIAS2, RS, 0, 0, M + 20 * 64, 4096, 1024);

  ln_final<<<4096, 256, 0, stream>>>(X1Q, M + 18 * 64, FBUF, M + 20 * 64, (float*)d_out);
}

// Round 7
// 409.826 us; speedup vs baseline: 1.1390x; 1.0461x over previous
//
#include <hip/hip_runtime.h>
#include <stdint.h>
#include <stddef.h>

// ---------------------------------------------------------------------------
// Fully fake-quantized transformer block on MI355X (gfx950).
// i8 MFMA GEMMs (exact i32 acc), flash-style fused attention.
// R14: (a) T2 XOR swizzle on all LDS tiles (gemm + attn): rows stride 64B ->
// l15-lanes aliased 2 bank-groups = 8-way conflict on every ds_read_b128
// (3.15M + 1.69M conflict cycles measured). Fix per rule #21 both-sides:
// stage global col c0s = ((tid&3)^((tid>>2)&3))*16 (LDS dest stays linear for
// global_load_lds), read slot quad^(l15&3). row&3==l15&3 for all frags so
// offset:1024*nt immediates stay valid; coalescing unchanged.
// (b) MLP1 ran its 34-GOP GEMM TWICE (mode1 stats + mode2 requant). If
// ws_size admits a 64MB f32 scratch (runtime-gated, fallback = old path),
// run once in mode 0 -> HF, then quant_f32_u8 applies the identical
// clip(rint(v/s),0,255)-128 grid. f32 roundtrip exact -> bit-identical.
// R13: gemm 128x64 tile; R12/R11: counted-vmcnt + asm ds_read pipelines;
// R9: attn block=(b,h,pair,rowhalf), swapped QK^T, reg P-transpose.
// ---------------------------------------------------------------------------

typedef unsigned short u16;
typedef __attribute__((ext_vector_type(4))) int   i32x4;
typedef __attribute__((ext_vector_type(4))) float f32x4;

#define DEV __device__ __forceinline__

DEV float bf2f(u16 u) { return __uint_as_float(((unsigned)u) << 16); }
DEV void atomicMaxF(float* p, float v) { atomicMax((unsigned*)p, __float_as_uint(v)); }
DEV float waveMax(float v) {
#pragma unroll
  for (int o = 32; o; o >>= 1) v = fmaxf(v, __shfl_xor(v, o, 64));
  return v;
}
DEV float waveSum(float v) {
#pragma unroll
  for (int o = 32; o; o >>= 1) v += __shfl_xor(v, o, 64);
  return v;
}
DEV int waveSumI(int v) {
#pragma unroll
  for (int o = 32; o; o >>= 1) v += __shfl_xor(v, o, 64);
  return v;
}
DEV void blockStatMax(float v, float* __restrict__ slot64, float* sred4, int flatBlk) {
  v = waveMax(v);
  const int tid = threadIdx.x;
  if ((tid & 63) == 0) sred4[tid >> 6] = v;
  __syncthreads();
  if (tid == 0) {
    float m = fmaxf(fmaxf(sred4[0], sred4[1]), fmaxf(sred4[2], sred4[3]));
    atomicMaxF(&slot64[flatBlk & 63], m);
  }
}
DEV float slotMax64(const float* __restrict__ s) {
  float m = 0.f;
#pragma unroll
  for (int i = 0; i < 64; ++i) m = fmaxf(m, s[i]);
  return m;
}
DEV f32x4 ld4(const void* p, int i4, int isf32) {
  if (isf32) return ((const f32x4*)p)[i4];
  ushort4 u = ((const ushort4*)p)[i4];
  return (f32x4){bf2f(u.x), bf2f(u.y), bf2f(u.z), bf2f(u.w)};
}
DEV void gll16(const void* g, void* l) {
  __builtin_amdgcn_global_load_lds((__attribute__((address_space(1))) void*)(g),
                                   (__attribute__((address_space(3))) void*)(l),
                                   16, 0, 0);
}
DEV unsigned ldsaddr(const void* p) {
  return (unsigned)(size_t)(__attribute__((address_space(3))) const void*)p;
}
DEV unsigned quadsel(unsigned a, unsigned b, unsigned c, unsigned d, int idx) {
  unsigned lo = (idx & 1) ? b : a;
  unsigned hi = (idx & 1) ? d : c;
  return (idx & 2) ? hi : lo;
}

__global__ void detect_f32(const u16* __restrict__ x, int* __restrict__ flag) {
  const int tid = threadIdx.x;
  int cnt = 0;
#pragma unroll
  for (int i = 0; i < 16; ++i) {
    u16 u = x[tid * 16 + i];
    if ((u & 0x7f80u) >= 0x4380u) ++cnt;
  }
  cnt = waveSumI(cnt);
  if (tid == 0) flag[0] = (cnt > 16) ? 1 : 0;
}

struct AJobs { const void* p[13]; int n4[13]; int bstart[14]; };

__global__ __launch_bounds__(256) void absmax_multi(AJobs J, float* __restrict__ M,
                                                    const int* __restrict__ flagp) {
  __shared__ float sred[4];
  const int isf32 = flagp[0];
  const int blk = blockIdx.x, tid = threadIdx.x;
  int j = 0;
  while (j < 12 && blk >= J.bstart[j + 1]) ++j;
  const int lb = blk - J.bstart[j];
  const int nb = J.bstart[j + 1] - J.bstart[j];
  float mx = 0.f;
  const void* p = J.p[j];
  for (int i = lb * 256 + tid; i < J.n4[j]; i += nb * 256) {
    f32x4 v = ld4(p, i, isf32);
    mx = fmaxf(mx, fmaxf(fmaxf(fabsf(v.x), fabsf(v.y)),
                         fmaxf(fabsf(v.z), fabsf(v.w))));
  }
  blockStatMax(mx, M + j * 64, sred, lb);
}

__global__ __launch_bounds__(256) void quant_in_signed(
    const void* __restrict__ in, int8_t* __restrict__ out,
    const float* __restrict__ mp, const int* __restrict__ flagp, int n4) {
  const int isf32 = flagp[0];
  const float s = fmaxf(slotMax64(mp), 1e-8f) / 127.0f;
  char4* op = (char4*)out;
  for (int i = blockIdx.x * 256 + threadIdx.x; i < n4; i += gridDim.x * 256) {
    f32x4 v = ld4(in, i, isf32);
    char4 q;
    q.x = (signed char)fminf(fmaxf(rintf(v.x / s), -128.f), 127.f);
    q.y = (signed char)fminf(fmaxf(rintf(v.y / s), -128.f), 127.f);
    q.z = (signed char)fminf(fmaxf(rintf(v.z / s), -128.f), 127.f);
    q.w = (signed char)fminf(fmaxf(rintf(v.w / s), -128.f), 127.f);
    op[i] = q;
  }
}

struct WJobs { const void* in[5]; int8_t* out[5]; int mslot[5]; int n4[5]; int bstart[6]; };

__global__ __launch_bounds__(256) void quant_w_multi(WJobs J, const float* __restrict__ M,
                                                     const int* __restrict__ flagp) {
  const int isf32 = flagp[0];
  const int blk = blockIdx.x, tid = threadIdx.x;
  int j = 0;
  while (j < 4 && blk >= J.bstart[j + 1]) ++j;
  const int lb = blk - J.bstart[j];
  const int nb = J.bstart[j + 1] - J.bstart[j];
  const float s = fmaxf(slotMax64(M + J.mslot[j] * 64), 1e-8f) / 127.0f;
  const void* p = J.in[j];
  char4* o = (char4*)J.out[j];
  for (int i = lb * 256 + tid; i < J.n4[j]; i += nb * 256) {
    f32x4 v = ld4(p, i, isf32);
    char4 q;
    q.x = (signed char)fminf(fmaxf(rintf(v.x / s), -127.f), 127.f);
    q.y = (signed char)fminf(fmaxf(rintf(v.y / s), -127.f), 127.f);
    q.z = (signed char)fminf(fmaxf(rintf(v.z / s), -127.f), 127.f);
    q.w = (signed char)fminf(fmaxf(rintf(v.w / s), -127.f), 127.f);
    o[i] = q;
  }
}

__global__ __launch_bounds__(256) void quant_w2_rs(
    const void* __restrict__ w2, int8_t* __restrict__ out,
    const float* __restrict__ mp, const int* __restrict__ flagp,
    int* __restrict__ rowsum) {
  const int isf32 = flagp[0];
  const int row = blockIdx.x, tid = threadIdx.x;
  const float s = fmaxf(slotMax64(mp), 1e-8f) / 127.0f;
  char4* op = (char4*)(out + (size_t)row * 4096);
  int sum = 0;
  for (int i = tid; i < 1024; i += 256) {
    f32x4 v = ld4(w2, row * 1024 + i, isf32);
    char4 q;
    q.x = (signed char)fminf(fmaxf(rintf(v.x / s), -127.f), 127.f);
    q.y = (signed char)fminf(fmaxf(rintf(v.y / s), -127.f), 127.f);
    q.z = (signed char)fminf(fmaxf(rintf(v.z / s), -127.f), 127.f);
    q.w = (signed char)fminf(fmaxf(rintf(v.w / s), -127.f), 127.f);
    op[i] = q;
    sum += (int)q.x + (int)q.y + (int)q.z + (int)q.w;
  }
  sum = waveSumI(sum);
  __shared__ int rs4[4];
  if ((tid & 63) == 0) rs4[tid >> 6] = sum;
  __syncthreads();
  if (tid == 0) rowsum[row] = rs4[0] + rs4[1] + rs4[2] + rs4[3];
}

struct BJobs { const void* in[6]; float* out[6]; int mslot[6]; int n4[6]; };

__global__ __launch_bounds__(256) void fq_bias_multi(BJobs J, const float* __restrict__ M,
                                                     const int* __restrict__ flagp) {
  const int isf32 = flagp[0];
  const int j = blockIdx.x;
  const float s = fmaxf(slotMax64(M + J.mslot[j] * 64), 1e-8f) / 127.0f;
  float* o = J.out[j];
  for (int i = threadIdx.x; i < J.n4[j]; i += 256) {
    f32x4 v = ld4(J.in[j], i, isf32);
    f32x4 r;
    r.x = fminf(fmaxf(rintf(v.x / s), -128.f), 127.f) * s;
    r.y = fminf(fmaxf(rintf(v.y / s), -128.f), 127.f) * s;
    r.z = fminf(fmaxf(rintf(v.z / s), -128.f), 127.f) * s;
    r.w = fminf(fmaxf(rintf(v.w / s), -128.f), 127.f) * s;
    *(f32x4*)(o + i * 4) = r;
  }
}

__global__ __launch_bounds__(256) void quant_f32_signed(
    const float* __restrict__ in, int8_t* __restrict__ out,
    const float* __restrict__ mp, float pre, int n4) {
  const float s = fmaxf(slotMax64(mp) * pre, 1e-8f) / 127.0f;
  const f32x4* ip = (const f32x4*)in;
  char4* op = (char4*)out;
  for (int i = blockIdx.x * 256 + threadIdx.x; i < n4; i += gridDim.x * 256) {
    f32x4 v = ip[i];
    char4 q;
    q.x = (signed char)fminf(fmaxf(rintf(v.x * pre / s), -128.f), 127.f);
    q.y = (signed char)fminf(fmaxf(rintf(v.y * pre / s), -128.f), 127.f);
    q.z = (signed char)fminf(fmaxf(rintf(v.z * pre / s), -128.f), 127.f);
    q.w = (signed char)fminf(fmaxf(rintf(v.w * pre / s), -128.f), 127.f);
    op[i] = q;
  }
}

// u8-128 requant matching gemm_i8 mode-2 epilogue exactly: s = max/255,
// q = clip(rint(v/s),0,255) - 128.
__global__ __launch_bounds__(256) void quant_f32_u8(
    const float* __restrict__ in, int8_t* __restrict__ out,
    const float* __restrict__ mp, int n4) {
  const float s = fmaxf(slotMax64(mp), 1e-8f) / 255.0f;
  const f32x4* ip = (const f32x4*)in;
  char4* op = (char4*)out;
  for (int i = blockIdx.x * 256 + threadIdx.x; i < n4; i += gridDim.x * 256) {
    f32x4 v = ip[i];
    char4 q;
    q.x = (signed char)((int)fminf(fmaxf(rintf(v.x / s), 0.f), 255.f) - 128);
    q.y = (signed char)((int)fminf(fmaxf(rintf(v.y / s), 0.f), 255.f) - 128);
    q.z = (signed char)((int)fminf(fmaxf(rintf(v.z / s), 0.f), 255.f) - 128);
    q.w = (signed char)((int)fminf(fmaxf(rintf(v.w / s), 0.f), 255.f) - 128);
    op[i] = q;
  }
}

__global__ __launch_bounds__(256) void quant_v_t(
    const float* __restrict__ V, int8_t* __restrict__ Vt,
    const float* __restrict__ mp) {
  __shared__ float tile[64][65];
  const int bh = blockIdx.x, st = blockIdx.y;
  const int b = bh >> 4, h = bh & 15;
  const int tid = threadIdx.x;
  const float s = fmaxf(slotMax64(mp), 1e-8f) / 127.0f;
  const int r = tid >> 2, c = (tid & 3) * 16;
  const float* src = V + ((size_t)(b * 1024 + st * 64 + r)) * 1024 + h * 64 + c;
#pragma unroll
  for (int g = 0; g < 4; ++g) {
    f32x4 v = *(const f32x4*)(src + g * 4);
    tile[r][c + g * 4 + 0] = v.x;
    tile[r][c + g * 4 + 1] = v.y;
    tile[r][c + g * 4 + 2] = v.z;
    tile[r][c + g * 4 + 3] = v.w;
  }
  __syncthreads();
  unsigned wds[4];
#pragma unroll
  for (int g = 0; g < 4; ++g) {
    unsigned wd = 0;
#pragma unroll
    for (int k = 0; k < 4; ++k) {
      float v = tile[c + g * 4 + k][r];
      int q = (int)fminf(fmaxf(rintf(v / s), -128.f), 127.f);
      wd |= ((unsigned)(unsigned char)(signed char)q) << (8 * k);
    }
    wds[g] = wd;
  }
  i32x4 ov = {(int)wds[0], (int)wds[1], (int)wds[2], (int)wds[3]};
  *(i32x4*)(Vt + ((size_t)((b * 16 + h) * 64 + r)) * 1024 + st * 64 + c) = ov;
}

// ------------- int8 GEMM (128x64 tile, 4-buffer, dist-3, T2 swizzle) ---------
// mode 0: store f32 Cf, stat->mOut ; mode 1: stats only ; mode 2: requant u8-128
// LDS swizzle: dest linear (gll16 req); source col c0s=((tid&3)^((tid>>2)&3))*16;
// read slot quad^(l15&3). row&3==l15&3 for all mt/nt -> offset:1024*k valid.
__global__ __launch_bounds__(256) void gemm_i8(
    const int8_t* __restrict__ A, const int8_t* __restrict__ B,
    float* __restrict__ Cf, int8_t* __restrict__ Cq,
    const float* __restrict__ mA, float preA, float qmaxA,
    const float* __restrict__ mB,
    const float* __restrict__ bias, const int* __restrict__ extra,
    int relu, int mode, float* __restrict__ mOut, int K, int O) {
  __shared__ __align__(16) int8_t smem[4][12288];
  __shared__ float sred[4];
  const int tid = threadIdx.x;
  const int nb = blockIdx.x, ob = blockIdx.y;
  const int w = tid >> 6, lane = tid & 63, l15 = lane & 15, quad = lane >> 4;
  i32x4 acc[2][4];
#pragma unroll
  for (int i = 0; i < 2; ++i)
#pragma unroll
    for (int j = 0; j < 4; ++j) acc[i][j] = (i32x4){0, 0, 0, 0};
  const int r0 = tid >> 2;
  const int c0 = (((tid & 3) ^ ((tid >> 2) & 3)) * 16);  // swizzled source col
  const int8_t* Ab = A + (size_t)(nb * 128) * K;
  const int8_t* Bb = B + (size_t)(ob * 64) * K;
  const int nk = K >> 6;
  const int slot = (quad ^ (l15 & 3)) * 16;              // swizzled read slot
  const int aoffl = (w * 32 + l15) * 64 + slot;
  const int boffl = 8192 + l15 * 64 + slot;
  // prologue: stage tiles 0..2 (3 loads each)
  for (int t = 0; t < 3 && t < nk; ++t) {
    const size_t kt0 = (size_t)t << 6;
    int8_t* d = smem[t];
    gll16(Ab + (size_t)r0 * K + kt0 + c0, d + tid * 16);
    gll16(Ab + (size_t)(r0 + 64) * K + kt0 + c0, d + 4096 + tid * 16);
    gll16(Bb + (size_t)r0 * K + kt0 + c0, d + 8192 + tid * 16);
  }
  for (int i = 0; i < nk; ++i) {
    const int infl = nk - 1 - i;  // prefetched tiles beyond i
    if (infl >= 2)      asm volatile("s_waitcnt vmcnt(6)" ::: "memory");
    else if (infl == 1) asm volatile("s_waitcnt vmcnt(3)" ::: "memory");
    else                asm volatile("s_waitcnt vmcnt(0)" ::: "memory");
    asm volatile("s_barrier" ::: "memory");
    if (i + 3 < nk) {
      const size_t kt0 = (size_t)(i + 3) << 6;
      int8_t* d = smem[(i + 3) & 3];
      gll16(Ab + (size_t)r0 * K + kt0 + c0, d + tid * 16);
      gll16(Ab + (size_t)(r0 + 64) * K + kt0 + c0, d + 4096 + tid * 16);
      gll16(Bb + (size_t)r0 * K + kt0 + c0, d + 8192 + tid * 16);
    }
    const unsigned a_addr = ldsaddr(smem[i & 3] + aoffl);
    const unsigned b_addr = ldsaddr(smem[i & 3] + boffl);
    i32x4 af[2], bf[4];
    asm volatile("ds_read_b128 %0, %1 offset:0"    : "=v"(af[0]) : "v"(a_addr));
    asm volatile("ds_read_b128 %0, %1 offset:1024" : "=v"(af[1]) : "v"(a_addr));
    asm volatile("ds_read_b128 %0, %1 offset:0"    : "=v"(bf[0]) : "v"(b_addr));
    asm volatile("ds_read_b128 %0, %1 offset:1024" : "=v"(bf[1]) : "v"(b_addr));
    asm volatile("ds_read_b128 %0, %1 offset:2048" : "=v"(bf[2]) : "v"(b_addr));
    asm volatile("ds_read_b128 %0, %1 offset:3072" : "=v"(bf[3]) : "v"(b_addr));
    asm volatile("s_waitcnt lgkmcnt(0)" ::: "memory");
    __builtin_amdgcn_sched_barrier(0);
#pragma unroll
    for (int mt = 0; mt < 2; ++mt)
#pragma unroll
      for (int nt = 0; nt < 4; ++nt)
        acc[mt][nt] = __builtin_amdgcn_mfma_i32_16x16x64_i8(af[mt], bf[nt], acc[mt][nt], 0, 0, 0);
  }
  const float sA = fmaxf(slotMax64(mA) * preA, 1e-8f) / qmaxA;
  const float sB = fmaxf(slotMax64(mB), 1e-8f) / 127.0f;
  const float sAB = sA * sB;
  const float sq = (mode == 2) ? (fmaxf(slotMax64(mOut), 1e-8f) / 255.0f) : 1.0f;
  float lmax = 0.f;
#pragma unroll
  for (int mt = 0; mt < 2; ++mt) {
    const int n = nb * 128 + w * 32 + mt * 16 + quad * 4;
#pragma unroll
    for (int nt = 0; nt < 4; ++nt) {
      const int o = ob * 64 + nt * 16 + l15;
      const int ext = extra ? 128 * extra[o] : 0;
      const float bv = bias[o];
#pragma unroll
      for (int r = 0; r < 4; ++r) {
        float v = sAB * (float)(acc[mt][nt][r] + ext) + bv;
        if (relu) v = fmaxf(v, 0.f);
        if (mode == 0) Cf[(size_t)(n + r) * O + o] = v;
        else if (mode == 2) {
          int q = (int)fminf(fmaxf(rintf(v / sq), 0.f), 255.f) - 128;
          Cq[(size_t)(n + r) * O + o] = (int8_t)q;
        }
        lmax = fmaxf(lmax, fabsf(v));
      }
    }
  }
  if (mode != 2)
    blockStatMax(lmax, mOut, sred, nb + ob * gridDim.x);
}

// --------------------------- fused causal attention --------------------------
// R12 structure + R14 T2 swizzle (same both-sides scheme as gemm).
__global__ __launch_bounds__(256, 4) void attn_fused(
    const int8_t* __restrict__ Qq, const int8_t* __restrict__ Kq,
    const int8_t* __restrict__ Vt, float* __restrict__ ctx,
    const float* __restrict__ M, float* __restrict__ mOut) {
  __shared__ __align__(16) int8_t qtile[4096];
  __shared__ __align__(16) int8_t ktile[4][4096];
  __shared__ __align__(16) int8_t vtile[4][4096];
  __shared__ float sred[4];
  const int tid = threadIdx.x, bid = blockIdx.x;
  const int pidx = bid & 7, rh = (bid >> 3) & 1, h = (bid >> 4) & 15, b = bid >> 8;
  const int qthi = 15 - pidx, qtlo = pidx, ktmax = qthi;
  const int w = tid >> 6, lane = tid & 63, l15 = lane & 15, quad = lane >> 4;
  const int wqt = (w < 2) ? qthi : qtlo;
  const int wrow0 = rh * 32 + (w & 1) * 16;
  const float sqs = fmaxf(slotMax64(M + 13 * 64) * 0.125f, 1e-8f) / 127.0f;
  const float sk = fmaxf(slotMax64(M + 14 * 64), 1e-8f) / 127.0f;
  const float sv = fmaxf(slotMax64(M + 15 * 64), 1e-8f) / 127.0f;
  const float sqk = sqs * sk;
  const float s_attn = 1.0f / 127.0f;  // softmax global max == 1.0 exactly
  const int r0 = tid >> 2;
  const int c0 = (((tid & 3) ^ ((tid >> 2) & 3)) * 16);  // swizzled source col
  const int8_t* Kbase = Kq + (size_t)(b * 1024) * 1024 + h * 64 + c0;
  const int8_t* Vbase = Vt + (size_t)((b * 16 + h) * 64 + r0) * 1024 + c0;
  const unsigned fragoff = (unsigned)(l15 * 64 + (quad ^ (l15 & 3)) * 16);

  // ---- Phase A prologue: stage Q (1 item) + K tiles 0..2 (3 items) ----
  {
    const int qt_s = (r0 < 32) ? qthi : qtlo;
    const int qrow_g = qt_s * 64 + rh * 32 + (r0 & 31);
    gll16(Qq + ((size_t)(b * 1024 + qrow_g)) * 1024 + h * 64 + c0, qtile + tid * 16);
  }
#pragma unroll
  for (int t = 0; t < 3; ++t)
    gll16(Kbase + (size_t)(t * 64 + r0) * 1024, ktile[t] + tid * 16);
  asm volatile("s_waitcnt vmcnt(3)" ::: "memory");  // my Q landed
  asm volatile("s_barrier" ::: "memory");           // all waves' Q landed
  i32x4 aq;
  {
    const unsigned qa = ldsaddr(qtile) +
        (unsigned)((w * 16 + l15) * 64 + (quad ^ (l15 & 3)) * 16);
    asm volatile("ds_read_b128 %0, %1 offset:0" : "=v"(aq) : "v"(qa));
    asm volatile("s_waitcnt lgkmcnt(0)" ::: "memory");
  }
  const int qrow = wqt * 64 + wrow0 + l15;  // this lane's q-row (0..1023)

  // ---- Phase A: swapped QK^T; per-lane online (m,l); pipelined K staging ----
  float m_l = -1e30f, l_l = 0.f;
  for (int kt = 0; kt <= ktmax; ++kt) {
    if (kt + 2 <= ktmax)      asm volatile("s_waitcnt vmcnt(2)" ::: "memory");
    else if (kt + 1 <= ktmax) asm volatile("s_waitcnt vmcnt(1)" ::: "memory");
    else                      asm volatile("s_waitcnt vmcnt(0)" ::: "memory");
    asm volatile("s_barrier" ::: "memory");
    if (kt + 3 <= ktmax)
      gll16(Kbase + (size_t)((kt + 3) * 64 + r0) * 1024, ktile[(kt + 3) & 3] + tid * 16);
    if (kt <= wqt) {
      const unsigned ka = ldsaddr(ktile[kt & 3]) + fragoff;
      i32x4 bk[4];
      asm volatile("ds_read_b128 %0, %1 offset:0"    : "=v"(bk[0]) : "v"(ka));
      asm volatile("ds_read_b128 %0, %1 offset:1024" : "=v"(bk[1]) : "v"(ka));
      asm volatile("ds_read_b128 %0, %1 offset:2048" : "=v"(bk[2]) : "v"(ka));
      asm volatile("ds_read_b128 %0, %1 offset:3072" : "=v"(bk[3]) : "v"(ka));
      asm volatile("s_waitcnt lgkmcnt(0)" ::: "memory");
      __builtin_amdgcn_sched_barrier(0);
      const int kc0 = kt * 64 + quad * 4;
      float sc[4][4];
#pragma unroll
      for (int nt = 0; nt < 4; ++nt) {
        i32x4 z = {0, 0, 0, 0};
        i32x4 d = __builtin_amdgcn_mfma_i32_16x16x64_i8(bk[nt], aq, z, 0, 0, 0);
        if (kt == wqt) {
#pragma unroll
          for (int r = 0; r < 4; ++r)
            sc[nt][r] = (kc0 + nt * 16 + r <= qrow) ? sqk * (float)d[r] : -1e30f;
        } else {
#pragma unroll
          for (int r = 0; r < 4; ++r) sc[nt][r] = sqk * (float)d[r];
        }
      }
      float vm = sc[0][0];
#pragma unroll
      for (int nt = 0; nt < 4; ++nt)
#pragma unroll
        for (int r = 0; r < 4; ++r) vm = fmaxf(vm, sc[nt][r]);
      const float mn = fmaxf(m_l, vm);
      float sum = 0.f;
#pragma unroll
      for (int nt = 0; nt < 4; ++nt)
#pragma unroll
        for (int r = 0; r < 4; ++r) sum += __expf(sc[nt][r] - mn);
      l_l = l_l * __expf(m_l - mn) + sum;
      m_l = mn;
    }
  }
  // merge the 4 quads (lanes sharing l15 hold the same q-row)
#pragma unroll
  for (int off = 16; off <= 32; off <<= 1) {
    float om = __shfl_xor(m_l, off, 64);
    float ol = __shfl_xor(l_l, off, 64);
    float mn = fmaxf(m_l, om);
    l_l = l_l * __expf(m_l - mn) + ol * __expf(om - mn);
    m_l = mn;
  }
  const float rl127 = 127.0f / l_l;  // P*127 in [0,127] exactly -> no clamps

  // ---- Phase B: recompute, quantize P in-register, quad-transpose, PV ----
  __syncthreads();  // all waves done reading Phase-A buffers (vmcnt already 0)
#pragma unroll
  for (int t = 0; t < 3; ++t) {
    gll16(Kbase + (size_t)(t * 64 + r0) * 1024, ktile[t] + tid * 16);
    gll16(Vbase + t * 64, vtile[t] + tid * 16);
  }
  i32x4 cacc[4] = {{0, 0, 0, 0}, {0, 0, 0, 0}, {0, 0, 0, 0}, {0, 0, 0, 0}};
  for (int kt = 0; kt <= ktmax; ++kt) {
    if (kt + 2 <= ktmax)      asm volatile("s_waitcnt vmcnt(4)" ::: "memory");
    else if (kt + 1 <= ktmax) asm volatile("s_waitcnt vmcnt(2)" ::: "memory");
    else                      asm volatile("s_waitcnt vmcnt(0)" ::: "memory");
    asm volatile("s_barrier" ::: "memory");
    if (kt + 3 <= ktmax) {
      gll16(Kbase + (size_t)((kt + 3) * 64 + r0) * 1024, ktile[(kt + 3) & 3] + tid * 16);
      gll16(Vbase + (kt + 3) * 64, vtile[(kt + 3) & 3] + tid * 16);
    }
    if (kt <= wqt) {
      const unsigned ka = ldsaddr(ktile[kt & 3]) + fragoff;
      const unsigned va = ldsaddr(vtile[kt & 3]) + fragoff;
      i32x4 bk[4], bv[4];
      asm volatile("ds_read_b128 %0, %1 offset:0"    : "=v"(bk[0]) : "v"(ka));
      asm volatile("ds_read_b128 %0, %1 offset:1024" : "=v"(bk[1]) : "v"(ka));
      asm volatile("ds_read_b128 %0, %1 offset:2048" : "=v"(bk[2]) : "v"(ka));
      asm volatile("ds_read_b128 %0, %1 offset:3072" : "=v"(bk[3]) : "v"(ka));
      asm volatile("ds_read_b128 %0, %1 offset:0"    : "=v"(bv[0]) : "v"(va));
      asm volatile("ds_read_b128 %0, %1 offset:1024" : "=v"(bv[1]) : "v"(va));
      asm volatile("ds_read_b128 %0, %1 offset:2048" : "=v"(bv[2]) : "v"(va));
      asm volatile("ds_read_b128 %0, %1 offset:3072" : "=v"(bv[3]) : "v"(va));
      asm volatile("s_waitcnt lgkmcnt(0)" ::: "memory");
      __builtin_amdgcn_sched_barrier(0);
      const int kc0 = kt * 64 + quad * 4;
      unsigned Dw[4];
#pragma unroll
      for (int nt = 0; nt < 4; ++nt) {
        i32x4 z = {0, 0, 0, 0};
        i32x4 d = __builtin_amdgcn_mfma_i32_16x16x64_i8(bk[nt], aq, z, 0, 0, 0);
        unsigned wd = 0;
        if (kt == wqt) {
#pragma unroll
          for (int r = 0; r < 4; ++r) {
            float e = (kc0 + nt * 16 + r <= qrow)
                          ? __expf(sqk * (float)d[r] - m_l) * rl127 : 0.f;
            wd |= ((unsigned)(int)rintf(e)) << (8 * r);
          }
        } else {
#pragma unroll
          for (int r = 0; r < 4; ++r) {
            float e = __expf(sqk * (float)d[r] - m_l) * rl127;
            wd |= ((unsigned)(int)rintf(e)) << (8 * r);
          }
        }
        Dw[nt] = wd;
      }
      // 4x4 quad-transpose: pf[j] (k=quad*16+4j..) <- Dw[quad] @ lane quad'=j
      unsigned selfv = quadsel(Dw[0], Dw[1], Dw[2], Dw[3], quad);
      unsigned rv1 = (unsigned)__shfl_xor(
          (int)quadsel(Dw[0], Dw[1], Dw[2], Dw[3], quad ^ 1), 16, 64);
      unsigned rv2 = (unsigned)__shfl_xor(
          (int)quadsel(Dw[0], Dw[1], Dw[2], Dw[3], quad ^ 2), 32, 64);
      unsigned rv3 = (unsigned)__shfl_xor(
          (int)quadsel(Dw[0], Dw[1], Dw[2], Dw[3], quad ^ 3), 48, 64);
      i32x4 pf;
#pragma unroll
      for (int j = 0; j < 4; ++j) {
        const int t = j ^ quad;
        pf[j] = (int)((t == 0) ? selfv : (t == 1) ? rv1 : (t == 2) ? rv2 : rv3);
      }
#pragma unroll
      for (int nt = 0; nt < 4; ++nt)
        cacc[nt] = __builtin_amdgcn_mfma_i32_16x16x64_i8(pf, bv[nt], cacc[nt], 0, 0, 0);
    }
  }
  const float sc2 = s_attn * sv;
  float lmax = 0.f;
  const int orow0 = wqt * 64 + wrow0 + quad * 4;
#pragma unroll
  for (int nt = 0; nt < 4; ++nt) {
    const int d = nt * 16 + l15;
#pragma unroll
    for (int r = 0; r < 4; ++r) {
      float v = sc2 * (float)cacc[nt][r];
      ctx[((size_t)(b * 1024 + orow0 + r)) * 1024 + h * 64 + d] = v;
      lmax = fmaxf(lmax, fabsf(v));
    }
  }
  blockStatMax(lmax, mOut, sred, bid);
}

// --------------------------- residual + layernorm ---------------------------
__global__ __launch_bounds__(256) void ln_res(
    const int8_t* __restrict__ xq, const float* __restrict__ mx,
    const float* __restrict__ ao, const float* __restrict__ ma,
    float* __restrict__ x1, float* __restrict__ mOut) {
  __shared__ float red[8];
  __shared__ float sred[4];
  const int row = blockIdx.x, tid = threadIdx.x;
  const float sx = fmaxf(slotMax64(mx), 1e-8f) / 127.0f;
  const float sa = fmaxf(slotMax64(ma), 1e-8f) / 127.0f;
  char4 xv = *(const char4*)(xq + (size_t)row * 1024 + tid * 4);
  f32x4 av = *(const f32x4*)(ao + (size_t)row * 1024 + tid * 4);
  float t[4];
  t[0] = (float)xv.x * sx + fminf(fmaxf(rintf(av.x / sa), -128.f), 127.f) * sa;
  t[1] = (float)xv.y * sx + fminf(fmaxf(rintf(av.y / sa), -128.f), 127.f) * sa;
  t[2] = (float)xv.z * sx + fminf(fmaxf(rintf(av.z / sa), -128.f), 127.f) * sa;
  t[3] = (float)xv.w * sx + fminf(fmaxf(rintf(av.w / sa), -128.f), 127.f) * sa;
  float s = waveSum(t[0] + t[1] + t[2] + t[3]);
  if ((tid & 63) == 0) red[tid >> 6] = s;
  __syncthreads();
  const float mean = (red[0] + red[1] + red[2] + red[3]) * (1.0f / 1024.0f);
  float vs = 0.f;
#pragma unroll
  for (int i = 0; i < 4; ++i) { float d = t[i] - mean; vs += d * d; }
  vs = waveSum(vs);
  if ((tid & 63) == 0) red[4 + (tid >> 6)] = vs;
  __syncthreads();
  const float var = (red[4] + red[5] + red[6] + red[7]) * (1.0f / 1024.0f);
  const float rs = sqrtf(var + 1e-5f);
  f32x4 o;
  o.x = (t[0] - mean) / rs;
  o.y = (t[1] - mean) / rs;
  o.z = (t[2] - mean) / rs;
  o.w = (t[3] - mean) / rs;
  *(f32x4*)(x1 + (size_t)row * 1024 + tid * 4) = o;
  float lmax = fmaxf(fmaxf(fabsf(o.x), fabsf(o.y)), fmaxf(fabsf(o.z), fabsf(o.w)));
  blockStatMax(lmax, mOut, sred, row);
}

__global__ __launch_bounds__(256) void ln_final(
    const int8_t* __restrict__ x1q, const float* __restrict__ mx1,
    const float* __restrict__ h2, const float* __restrict__ mh2,
    float* __restrict__ out) {
  __shared__ float red[8];
  const int row = blockIdx.x, tid = threadIdx.x;
  const float s1 = fmaxf(slotMax64(mx1), 1e-8f) / 127.0f;
  const float s2 = fmaxf(slotMax64(mh2), 1e-8f) / 127.0f;
  char4 xv = *(const char4*)(x1q + (size_t)row * 1024 + tid * 4);
  f32x4 hv = *(const f32x4*)(h2 + (size_t)row * 1024 + tid * 4);
  float t[4];
  t[0] = (float)xv.x * s1 + fminf(fmaxf(rintf(hv.x / s2), -128.f), 127.f) * s2;
  t[1] = (float)xv.y * s1 + fminf(fmaxf(rintf(hv.y / s2), -128.f), 127.f) * s2;
  t[2] = (float)xv.z * s1 + fminf(fmaxf(rintf(hv.z / s2), -128.f), 127.f) * s2;
  t[3] = (float)xv.w * s1 + fminf(fmaxf(rintf(hv.w / s2), -128.f), 127.f) * s2;
  float s = waveSum(t[0] + t[1] + t[2] + t[3]);
  if ((tid & 63) == 0) red[tid >> 6] = s;
  __syncthreads();
  const float mean = (red[0] + red[1] + red[2] + red[3]) * (1.0f / 1024.0f);
  float vs = 0.f;
#pragma unroll
  for (int i = 0; i < 4; ++i) { float d = t[i] - mean; vs += d * d; }
  vs = waveSum(vs);
  if ((tid & 63) == 0) red[4 + (tid >> 6)] = vs;
  __syncthreads();
  const float var = (red[4] + red[5] + red[6] + red[7]) * (1.0f / 1024.0f);
  const float rs = sqrtf(var + 1e-5f);
  f32x4 o;
  o.x = (t[0] - mean) / rs;
  o.y = (t[1] - mean) / rs;
  o.z = (t[2] - mean) / rs;
  o.w = (t[3] - mean) / rs;
  *(f32x4*)(out + (size_t)row * 1024 + tid * 4) = o;
}

// --------------------------- workspace layout --------------------------------
static constexpr size_t MB = 1u << 20;
static constexpr size_t OFF_M     = 0;          // 21 stats x 64 f32 slots
static constexpr size_t OFF_FLAG  = 6400;
static constexpr size_t OFF_BIASQ = 8192;
static constexpr size_t OFF_BIASK = OFF_BIASQ + 4096;
static constexpr size_t OFF_BIASV = OFF_BIASK + 4096;
static constexpr size_t OFF_BIASO = OFF_BIASV + 4096;
static constexpr size_t OFF_BIAS1 = OFF_BIASO + 4096;
static constexpr size_t OFF_BIAS2 = OFF_BIAS1 + 16384;
static constexpr size_t OFF_RS    = OFF_BIAS2 + 4096;
static constexpr size_t OFF_XQ    = 65536;
static constexpr size_t OFF_WQQ   = OFF_XQ  + 4 * MB;
static constexpr size_t OFF_WKQ   = OFF_WQQ + 1 * MB;
static constexpr size_t OFF_WVQ   = OFF_WKQ + 1 * MB;
static constexpr size_t OFF_WOQ   = OFF_WVQ + 1 * MB;
static constexpr size_t OFF_W1Q   = OFF_WOQ + 1 * MB;
static constexpr size_t OFF_W2Q   = OFF_W1Q + 4 * MB;
static constexpr size_t OFF_X1Q   = OFF_W2Q + 4 * MB;
static constexpr size_t OFF_A1    = OFF_X1Q + 4 * MB;     // arena1, 16 MB
static constexpr size_t OFF_A2    = OFF_A1 + 16 * MB;     // arena2 (f32), 16 MB
static constexpr size_t OFF_HF    = OFF_A2 + 16 * MB;     // optional 64 MB f32 h

extern "C" void kernel_launch(void* const* d_in, const int* in_sizes, int n_in,
                              void* d_out, int out_size, void* d_ws, size_t ws_size,
                              hipStream_t stream) {
  (void)n_in; (void)out_size;
  char* ws = (char*)d_ws;
  float* M = (float*)(ws + OFF_M);
  int* FLAG = (int*)(ws + OFF_FLAG);
  float* BIASQ = (float*)(ws + OFF_BIASQ);
  float* BIASK = (float*)(ws + OFF_BIASK);
  float* BIASV = (float*)(ws + OFF_BIASV);
  float* BIASO = (float*)(ws + OFF_BIASO);
  float* BIAS1 = (float*)(ws + OFF_BIAS1);
  float* BIAS2 = (float*)(ws + OFF_BIAS2);
  int* RS = (int*)(ws + OFF_RS);
  int8_t* XQ  = (int8_t*)(ws + OFF_XQ);
  int8_t* WQQ = (int8_t*)(ws + OFF_WQQ);
  int8_t* WKQ = (int8_t*)(ws + OFF_WKQ);
  int8_t* WVQ = (int8_t*)(ws + OFF_WVQ);
  int8_t* WOQ = (int8_t*)(ws + OFF_WOQ);
  int8_t* W1Q = (int8_t*)(ws + OFF_W1Q);
  int8_t* W2Q = (int8_t*)(ws + OFF_W2Q);
  int8_t* X1Q = (int8_t*)(ws + OFF_X1Q);
  int8_t* QQ   = (int8_t*)(ws + OFF_A1);
  int8_t* KQQ  = (int8_t*)(ws + OFF_A1 + 4 * MB);
  int8_t* VT   = (int8_t*)(ws + OFF_A1 + 8 * MB);
  int8_t* CTXQ = (int8_t*)(ws + OFF_A1 + 12 * MB);
  float*  X1F  = (float*)(ws + OFF_A1);
  int8_t* HQ   = (int8_t*)(ws + OFF_A1);
  float* FBUF = (float*)(ws + OFF_A2);   // serial reuse: QF/KF/VF/ctx/ao/h2
  const bool bigws = ws_size >= OFF_HF + 64 * MB;

  hipMemsetAsync(M, 0, 8192, stream);
  detect_f32<<<1, 64, 0, stream>>>((const u16*)d_in[0], FLAG);

  AJobs aj;
  const int ablk[13] = {512, 128, 1, 128, 1, 128, 1, 128, 1, 512, 2, 512, 1};
  int bs = 0;
  for (int i = 0; i < 13; ++i) {
    aj.p[i] = d_in[i];
    aj.n4[i] = in_sizes[i] / 4;
    aj.bstart[i] = bs;
    bs += ablk[i];
  }
  aj.bstart[13] = bs;
  absmax_multi<<<bs, 256, 0, stream>>>(aj, M, FLAG);

  quant_in_signed<<<1024, 256, 0, stream>>>(d_in[0], XQ, M + 0 * 64, FLAG, in_sizes[0] / 4);

  WJobs wj;
  const int widx[5] = {1, 3, 5, 7, 9};
  int8_t* wout[5] = {WQQ, WKQ, WVQ, WOQ, W1Q};
  const int wblk[5] = {128, 128, 128, 128, 512};
  int wb = 0;
  for (int j = 0; j < 5; ++j) {
    wj.in[j] = d_in[widx[j]];
    wj.out[j] = wout[j];
    wj.mslot[j] = widx[j];
    wj.n4[j] = in_sizes[widx[j]] / 4;
    wj.bstart[j] = wb;
    wb += wblk[j];
  }
  wj.bstart[5] = wb;
  quant_w_multi<<<wb, 256, 0, stream>>>(wj, M, FLAG);
  quant_w2_rs<<<1024, 256, 0, stream>>>(d_in[11], W2Q, M + 11 * 64, FLAG, RS);

  BJobs bj;
  const int bidx[6] = {2, 4, 6, 8, 10, 12};
  float* bout[6] = {BIASQ, BIASK, BIASV, BIASO, BIAS1, BIAS2};
  for (int j = 0; j < 6; ++j) {
    bj.in[j] = d_in[bidx[j]];
    bj.out[j] = bout[j];
    bj.mslot[j] = bidx[j];
    bj.n4[j] = in_sizes[bidx[j]] / 4;
  }
  fq_bias_multi<<<6, 256, 0, stream>>>(bj, M, FLAG);

  // Q/K/V projections through the 16MB f32 arena, strictly serial
  gemm_i8<<<dim3(32, 16), 256, 0, stream>>>(XQ, WQQ, FBUF, nullptr, M + 0 * 64, 1.f, 127.f, M + 1 * 64, BIASQ, nullptr, 0, 0, M + 13 * 64, 1024, 1024);
  quant_f32_signed<<<2048, 256, 0, stream>>>(FBUF, QQ, M + 13 * 64, 0.125f, 1024 * 1024);
  gemm_i8<<<dim3(32, 16), 256, 0, stream>>>(XQ, WKQ, FBUF, nullptr, M + 0 * 64, 1.f, 127.f, M + 3 * 64, BIASK, nullptr, 0, 0, M + 14 * 64, 1024, 1024);
  quant_f32_signed<<<2048, 256, 0, stream>>>(FBUF, KQQ, M + 14 * 64, 1.0f, 1024 * 1024);
  gemm_i8<<<dim3(32, 16), 256, 0, stream>>>(XQ, WVQ, FBUF, nullptr, M + 0 * 64, 1.f, 127.f, M + 5 * 64, BIASV, nullptr, 0, 0, M + 15 * 64, 1024, 1024);
  quant_v_t<<<dim3(64, 16), 256, 0, stream>>>(FBUF, VT, M + 15 * 64);

  attn_fused<<<1024, 256, 0, stream>>>(QQ, KQQ, VT, FBUF, M, M + 16 * 64);
  quant_f32_signed<<<2048, 256, 0, stream>>>(FBUF, CTXQ, M + 16 * 64, 1.0f, 1024 * 1024);

  gemm_i8<<<dim3(32, 16), 256, 0, stream>>>(CTXQ, WOQ, FBUF, nullptr, M + 16 * 64, 1.f, 127.f, M + 7 * 64, BIASO, nullptr, 0, 0, M + 17 * 64, 1024, 1024);

  ln_res<<<4096, 256, 0, stream>>>(XQ, M + 0 * 64, FBUF, M + 17 * 64, X1F, M + 18 * 64);
  quant_f32_signed<<<2048, 256, 0, stream>>>(X1F, X1Q, M + 18 * 64, 1.0f, 1024 * 1024);

  if (bigws) {
    // MLP1 once: mode 0 writes f32 h (64MB scratch) + stats; then exact
    // u8-128 requant (identical grid to mode-2 epilogue). Bit-identical.
    float* HF = (float*)(ws + OFF_HF);
    gemm_i8<<<dim3(32, 64), 256, 0, stream>>>(X1Q, W1Q, HF, nullptr, M + 18 * 64, 1.f, 127.f, M + 9 * 64, BIAS1, nullptr, 1, 0, M + 19 * 64, 1024, 4096);
    quant_f32_u8<<<2048, 256, 0, stream>>>(HF, HQ, M + 19 * 64, 4096 * 1024);
  } else {
    gemm_i8<<<dim3(32, 64), 256, 0, stream>>>(X1Q, W1Q, nullptr, nullptr, M + 18 * 64, 1.f, 127.f, M + 9 * 64, BIAS1, nullptr, 1, 1, M + 19 * 64, 1024, 4096);
    gemm_i8<<<dim3(32, 64), 256, 0, stream>>>(X1Q, W1Q, nullptr, HQ,      M + 18 * 64, 1.f, 127.f, M + 9 * 64, BIAS1, nullptr, 1, 2, M + 19 * 64, 1024, 4096);
  }

  gemm_i8<<<dim3(32, 16), 256, 0, stream>>>(HQ, W2Q, FBUF, nullptr, M + 19 * 64, 1.f, 255.f, M + 11 * 64, BIAS2, RS, 0, 0, M + 20 * 64, 4096, 1024);

  ln_final<<<4096, 256, 0, stream>>>(X1Q, M + 18 * 64, FBUF, M + 20 * 64, (float*)d_out);
}

// Round 9
// 386.647 us; speedup vs baseline: 1.2073x; 1.0599x over previous
//
#include <hip/hip_runtime.h>
#include <stdint.h>
#include <stddef.h>

// ---------------------------------------------------------------------------
// Fully fake-quantized transformer block on MI355X (gfx950).
// i8 MFMA GEMMs (exact i32 acc), flash-style fused attention.
// R16: FIX R15's fused-QKV output stride (repeat of R6's bug: each region's
// output is [4096,1024] f32 = 16MB = 4M floats, NOT 1M). Region stride is now
// <<22, and the 48MB fused output goes to the 64MB HF scratch (proven present
// in R14: WRITE_SIZE 65.7MB on mode-0 MLP1 => bigws active). Non-bigws falls
// back to R14's serial QKV into the 16MB FBUF. MLP1 reuses HF afterward
// (stream-ordered). 3-buffer dist-2 gemm pipeline kept (logic re-verified:
// tile t -> buf t%3; reads of tile i-1 retire before iter-i barrier).
// R14: swizzle (null but harmless) + MLP1 single-pass; R13: 128x64 tile;
// R12/R11: counted-vmcnt + asm ds_read; R9: attn pair/rowhalf structure.
// ---------------------------------------------------------------------------

typedef unsigned short u16;
typedef __attribute__((ext_vector_type(4))) int   i32x4;
typedef __attribute__((ext_vector_type(4))) float f32x4;

#define DEV __device__ __forceinline__

DEV float bf2f(u16 u) { return __uint_as_float(((unsigned)u) << 16); }
DEV void atomicMaxF(float* p, float v) { atomicMax((unsigned*)p, __float_as_uint(v)); }
DEV float waveMax(float v) {
#pragma unroll
  for (int o = 32; o; o >>= 1) v = fmaxf(v, __shfl_xor(v, o, 64));
  return v;
}
DEV float waveSum(float v) {
#pragma unroll
  for (int o = 32; o; o >>= 1) v += __shfl_xor(v, o, 64);
  return v;
}
DEV int waveSumI(int v) {
#pragma unroll
  for (int o = 32; o; o >>= 1) v += __shfl_xor(v, o, 64);
  return v;
}
DEV void blockStatMax(float v, float* __restrict__ slot64, float* sred4, int flatBlk) {
  v = waveMax(v);
  const int tid = threadIdx.x;
  if ((tid & 63) == 0) sred4[tid >> 6] = v;
  __syncthreads();
  if (tid == 0) {
    float m = fmaxf(fmaxf(sred4[0], sred4[1]), fmaxf(sred4[2], sred4[3]));
    atomicMaxF(&slot64[flatBlk & 63], m);
  }
}
DEV float slotMax64(const float* __restrict__ s) {
  float m = 0.f;
#pragma unroll
  for (int i = 0; i < 64; ++i) m = fmaxf(m, s[i]);
  return m;
}
DEV f32x4 ld4(const void* p, int i4, int isf32) {
  if (isf32) return ((const f32x4*)p)[i4];
  ushort4 u = ((const ushort4*)p)[i4];
  return (f32x4){bf2f(u.x), bf2f(u.y), bf2f(u.z), bf2f(u.w)};
}
DEV void gll16(const void* g, void* l) {
  __builtin_amdgcn_global_load_lds((__attribute__((address_space(1))) void*)(g),
                                   (__attribute__((address_space(3))) void*)(l),
                                   16, 0, 0);
}
DEV unsigned ldsaddr(const void* p) {
  return (unsigned)(size_t)(__attribute__((address_space(3))) const void*)p;
}
DEV unsigned quadsel(unsigned a, unsigned b, unsigned c, unsigned d, int idx) {
  unsigned lo = (idx & 1) ? b : a;
  unsigned hi = (idx & 1) ? d : c;
  return (idx & 2) ? hi : lo;
}

__global__ void detect_f32(const u16* __restrict__ x, int* __restrict__ flag) {
  const int tid = threadIdx.x;
  int cnt = 0;
#pragma unroll
  for (int i = 0; i < 16; ++i) {
    u16 u = x[tid * 16 + i];
    if ((u & 0x7f80u) >= 0x4380u) ++cnt;
  }
  cnt = waveSumI(cnt);
  if (tid == 0) flag[0] = (cnt > 16) ? 1 : 0;
}

struct AJobs { const void* p[13]; int n4[13]; int bstart[14]; };

__global__ __launch_bounds__(256) void absmax_multi(AJobs J, float* __restrict__ M,
                                                    const int* __restrict__ flagp) {
  __shared__ float sred[4];
  const int isf32 = flagp[0];
  const int blk = blockIdx.x, tid = threadIdx.x;
  int j = 0;
  while (j < 12 && blk >= J.bstart[j + 1]) ++j;
  const int lb = blk - J.bstart[j];
  const int nb = J.bstart[j + 1] - J.bstart[j];
  float mx = 0.f;
  const void* p = J.p[j];
  for (int i = lb * 256 + tid; i < J.n4[j]; i += nb * 256) {
    f32x4 v = ld4(p, i, isf32);
    mx = fmaxf(mx, fmaxf(fmaxf(fabsf(v.x), fabsf(v.y)),
                         fmaxf(fabsf(v.z), fabsf(v.w))));
  }
  blockStatMax(mx, M + j * 64, sred, lb);
}

__global__ __launch_bounds__(256) void quant_in_signed(
    const void* __restrict__ in, int8_t* __restrict__ out,
    const float* __restrict__ mp, const int* __restrict__ flagp, int n4) {
  const int isf32 = flagp[0];
  const float s = fmaxf(slotMax64(mp), 1e-8f) / 127.0f;
  char4* op = (char4*)out;
  for (int i = blockIdx.x * 256 + threadIdx.x; i < n4; i += gridDim.x * 256) {
    f32x4 v = ld4(in, i, isf32);
    char4 q;
    q.x = (signed char)fminf(fmaxf(rintf(v.x / s), -128.f), 127.f);
    q.y = (signed char)fminf(fmaxf(rintf(v.y / s), -128.f), 127.f);
    q.z = (signed char)fminf(fmaxf(rintf(v.z / s), -128.f), 127.f);
    q.w = (signed char)fminf(fmaxf(rintf(v.w / s), -128.f), 127.f);
    op[i] = q;
  }
}

struct WJobs { const void* in[5]; int8_t* out[5]; int mslot[5]; int n4[5]; int bstart[6]; };

__global__ __launch_bounds__(256) void quant_w_multi(WJobs J, const float* __restrict__ M,
                                                     const int* __restrict__ flagp) {
  const int isf32 = flagp[0];
  const int blk = blockIdx.x, tid = threadIdx.x;
  int j = 0;
  while (j < 4 && blk >= J.bstart[j + 1]) ++j;
  const int lb = blk - J.bstart[j];
  const int nb = J.bstart[j + 1] - J.bstart[j];
  const float s = fmaxf(slotMax64(M + J.mslot[j] * 64), 1e-8f) / 127.0f;
  const void* p = J.in[j];
  char4* o = (char4*)J.out[j];
  for (int i = lb * 256 + tid; i < J.n4[j]; i += nb * 256) {
    f32x4 v = ld4(p, i, isf32);
    char4 q;
    q.x = (signed char)fminf(fmaxf(rintf(v.x / s), -127.f), 127.f);
    q.y = (signed char)fminf(fmaxf(rintf(v.y / s), -127.f), 127.f);
    q.z = (signed char)fminf(fmaxf(rintf(v.z / s), -127.f), 127.f);
    q.w = (signed char)fminf(fmaxf(rintf(v.w / s), -127.f), 127.f);
    o[i] = q;
  }
}

__global__ __launch_bounds__(256) void quant_w2_rs(
    const void* __restrict__ w2, int8_t* __restrict__ out,
    const float* __restrict__ mp, const int* __restrict__ flagp,
    int* __restrict__ rowsum) {
  const int isf32 = flagp[0];
  const int row = blockIdx.x, tid = threadIdx.x;
  const float s = fmaxf(slotMax64(mp), 1e-8f) / 127.0f;
  char4* op = (char4*)(out + (size_t)row * 4096);
  int sum = 0;
  for (int i = tid; i < 1024; i += 256) {
    f32x4 v = ld4(w2, row * 1024 + i, isf32);
    char4 q;
    q.x = (signed char)fminf(fmaxf(rintf(v.x / s), -127.f), 127.f);
    q.y = (signed char)fminf(fmaxf(rintf(v.y / s), -127.f), 127.f);
    q.z = (signed char)fminf(fmaxf(rintf(v.z / s), -127.f), 127.f);
    q.w = (signed char)fminf(fmaxf(rintf(v.w / s), -127.f), 127.f);
    op[i] = q;
    sum += (int)q.x + (int)q.y + (int)q.z + (int)q.w;
  }
  sum = waveSumI(sum);
  __shared__ int rs4[4];
  if ((tid & 63) == 0) rs4[tid >> 6] = sum;
  __syncthreads();
  if (tid == 0) rowsum[row] = rs4[0] + rs4[1] + rs4[2] + rs4[3];
}

struct BJobs { const void* in[6]; float* out[6]; int mslot[6]; int n4[6]; };

__global__ __launch_bounds__(256) void fq_bias_multi(BJobs J, const float* __restrict__ M,
                                                     const int* __restrict__ flagp) {
  const int isf32 = flagp[0];
  const int j = blockIdx.x;
  const float s = fmaxf(slotMax64(M + J.mslot[j] * 64), 1e-8f) / 127.0f;
  float* o = J.out[j];
  for (int i = threadIdx.x; i < J.n4[j]; i += 256) {
    f32x4 v = ld4(J.in[j], i, isf32);
    f32x4 r;
    r.x = fminf(fmaxf(rintf(v.x / s), -128.f), 127.f) * s;
    r.y = fminf(fmaxf(rintf(v.y / s), -128.f), 127.f) * s;
    r.z = fminf(fmaxf(rintf(v.z / s), -128.f), 127.f) * s;
    r.w = fminf(fmaxf(rintf(v.w / s), -128.f), 127.f) * s;
    *(f32x4*)(o + i * 4) = r;
  }
}

__global__ __launch_bounds__(256) void quant_f32_signed(
    const float* __restrict__ in, int8_t* __restrict__ out,
    const float* __restrict__ mp, float pre, int n4) {
  const float s = fmaxf(slotMax64(mp) * pre, 1e-8f) / 127.0f;
  const f32x4* ip = (const f32x4*)in;
  char4* op = (char4*)out;
  for (int i = blockIdx.x * 256 + threadIdx.x; i < n4; i += gridDim.x * 256) {
    f32x4 v = ip[i];
    char4 q;
    q.x = (signed char)fminf(fmaxf(rintf(v.x * pre / s), -128.f), 127.f);
    q.y = (signed char)fminf(fmaxf(rintf(v.y * pre / s), -128.f), 127.f);
    q.z = (signed char)fminf(fmaxf(rintf(v.z * pre / s), -128.f), 127.f);
    q.w = (signed char)fminf(fmaxf(rintf(v.w * pre / s), -128.f), 127.f);
    op[i] = q;
  }
}

// u8-128 requant matching gemm_i8 mode-2 epilogue exactly: s = max/255,
// q = clip(rint(v/s),0,255) - 128.
__global__ __launch_bounds__(256) void quant_f32_u8(
    const float* __restrict__ in, int8_t* __restrict__ out,
    const float* __restrict__ mp, int n4) {
  const float s = fmaxf(slotMax64(mp), 1e-8f) / 255.0f;
  const f32x4* ip = (const f32x4*)in;
  char4* op = (char4*)out;
  for (int i = blockIdx.x * 256 + threadIdx.x; i < n4; i += gridDim.x * 256) {
    f32x4 v = ip[i];
    char4 q;
    q.x = (signed char)((int)fminf(fmaxf(rintf(v.x / s), 0.f), 255.f) - 128);
    q.y = (signed char)((int)fminf(fmaxf(rintf(v.y / s), 0.f), 255.f) - 128);
    q.z = (signed char)((int)fminf(fmaxf(rintf(v.z / s), 0.f), 255.f) - 128);
    q.w = (signed char)((int)fminf(fmaxf(rintf(v.w / s), 0.f), 255.f) - 128);
    op[i] = q;
  }
}

__global__ __launch_bounds__(256) void quant_v_t(
    const float* __restrict__ V, int8_t* __restrict__ Vt,
    const float* __restrict__ mp) {
  __shared__ float tile[64][65];
  const int bh = blockIdx.x, st = blockIdx.y;
  const int b = bh >> 4, h = bh & 15;
  const int tid = threadIdx.x;
  const float s = fmaxf(slotMax64(mp), 1e-8f) / 127.0f;
  const int r = tid >> 2, c = (tid & 3) * 16;
  const float* src = V + ((size_t)(b * 1024 + st * 64 + r)) * 1024 + h * 64 + c;
#pragma unroll
  for (int g = 0; g < 4; ++g) {
    f32x4 v = *(const f32x4*)(src + g * 4);
    tile[r][c + g * 4 + 0] = v.x;
    tile[r][c + g * 4 + 1] = v.y;
    tile[r][c + g * 4 + 2] = v.z;
    tile[r][c + g * 4 + 3] = v.w;
  }
  __syncthreads();
  unsigned wds[4];
#pragma unroll
  for (int g = 0; g < 4; ++g) {
    unsigned wd = 0;
#pragma unroll
    for (int k = 0; k < 4; ++k) {
      float v = tile[c + g * 4 + k][r];
      int q = (int)fminf(fmaxf(rintf(v / s), -128.f), 127.f);
      wd |= ((unsigned)(unsigned char)(signed char)q) << (8 * k);
    }
    wds[g] = wd;
  }
  i32x4 ov = {(int)wds[0], (int)wds[1], (int)wds[2], (int)wds[3]};
  *(i32x4*)(Vt + ((size_t)((b * 16 + h) * 64 + r)) * 1024 + st * 64 + c) = ov;
}

// ------- int8 GEMM (128x64 tile, 3-buffer, dist-2, optional QKV fuse) --------
// mode 0: store f32 Cf, stat->mOut ; mode 1: stats only ; mode 2: requant u8-128
// qkv=1: region = ob>>4 in [0,3); Cf += region*4M floats (16MB per region!);
// mB += region*128 (slots 1/3/5); mOut += region*64 (13/14/15); bias global;
// output col = o & 1023.
__global__ __launch_bounds__(256) void gemm_i8(
    const int8_t* __restrict__ A, const int8_t* __restrict__ B,
    float* __restrict__ Cf, int8_t* __restrict__ Cq,
    const float* __restrict__ mA, float preA, float qmaxA,
    const float* __restrict__ mB,
    const float* __restrict__ bias, const int* __restrict__ extra,
    int relu, int mode, int qkv, float* __restrict__ mOut, int K, int O) {
  __shared__ __align__(16) int8_t smem[3][12288];
  __shared__ float sred[4];
  const int tid = threadIdx.x;
  const int nb = blockIdx.x, ob = blockIdx.y;
  const int w = tid >> 6, lane = tid & 63, l15 = lane & 15, quad = lane >> 4;
  i32x4 acc[2][4];
#pragma unroll
  for (int i = 0; i < 2; ++i)
#pragma unroll
    for (int j = 0; j < 4; ++j) acc[i][j] = (i32x4){0, 0, 0, 0};
  const int r0 = tid >> 2;
  const int c0 = (((tid & 3) ^ ((tid >> 2) & 3)) * 16);  // swizzled source col
  const int8_t* Ab = A + (size_t)(nb * 128) * K;
  const int8_t* Bb = B + (size_t)(ob * 64) * K;
  const int nk = K >> 6;
  const int slot = (quad ^ (l15 & 3)) * 16;              // swizzled read slot
  const int aoffl = (w * 32 + l15) * 64 + slot;
  const int boffl = 8192 + l15 * 64 + slot;
  // prologue: stage tiles 0..1 (3 loads each)
  for (int t = 0; t < 2 && t < nk; ++t) {
    const size_t kt0 = (size_t)t << 6;
    int8_t* d = smem[t];
    gll16(Ab + (size_t)r0 * K + kt0 + c0, d + tid * 16);
    gll16(Ab + (size_t)(r0 + 64) * K + kt0 + c0, d + 4096 + tid * 16);
    gll16(Bb + (size_t)r0 * K + kt0 + c0, d + 8192 + tid * 16);
  }
  int cb = 0, ib = 2;
  for (int i = 0; i < nk; ++i) {
    if (i + 1 < nk) asm volatile("s_waitcnt vmcnt(3)" ::: "memory");
    else            asm volatile("s_waitcnt vmcnt(0)" ::: "memory");
    asm volatile("s_barrier" ::: "memory");
    if (i + 2 < nk) {
      const size_t kt0 = (size_t)(i + 2) << 6;
      int8_t* d = smem[ib];
      gll16(Ab + (size_t)r0 * K + kt0 + c0, d + tid * 16);
      gll16(Ab + (size_t)(r0 + 64) * K + kt0 + c0, d + 4096 + tid * 16);
      gll16(Bb + (size_t)r0 * K + kt0 + c0, d + 8192 + tid * 16);
      ib = (ib == 2) ? 0 : ib + 1;
    }
    const unsigned a_addr = ldsaddr(smem[cb] + aoffl);
    const unsigned b_addr = ldsaddr(smem[cb] + boffl);
    cb = (cb == 2) ? 0 : cb + 1;
    i32x4 af[2], bf[4];
    asm volatile("ds_read_b128 %0, %1 offset:0"    : "=v"(af[0]) : "v"(a_addr));
    asm volatile("ds_read_b128 %0, %1 offset:1024" : "=v"(af[1]) : "v"(a_addr));
    asm volatile("ds_read_b128 %0, %1 offset:0"    : "=v"(bf[0]) : "v"(b_addr));
    asm volatile("ds_read_b128 %0, %1 offset:1024" : "=v"(bf[1]) : "v"(b_addr));
    asm volatile("ds_read_b128 %0, %1 offset:2048" : "=v"(bf[2]) : "v"(b_addr));
    asm volatile("ds_read_b128 %0, %1 offset:3072" : "=v"(bf[3]) : "v"(b_addr));
    asm volatile("s_waitcnt lgkmcnt(0)" ::: "memory");
    __builtin_amdgcn_sched_barrier(0);
#pragma unroll
    for (int mt = 0; mt < 2; ++mt)
#pragma unroll
      for (int nt = 0; nt < 4; ++nt)
        acc[mt][nt] = __builtin_amdgcn_mfma_i32_16x16x64_i8(af[mt], bf[nt], acc[mt][nt], 0, 0, 0);
  }
  const int region = qkv ? (ob >> 4) : 0;
  if (qkv) {
    Cf += (size_t)region << 22;   // region * 4M floats = 16MB (B*S x 1024 f32)
    mB += region * 128;           // weight-scale slots 1/3/5
    mOut += region * 64;          // out-stat slots 13/14/15
  }
  const float sA = fmaxf(slotMax64(mA) * preA, 1e-8f) / qmaxA;
  const float sB = fmaxf(slotMax64(mB), 1e-8f) / 127.0f;
  const float sAB = sA * sB;
  const float sq = (mode == 2) ? (fmaxf(slotMax64(mOut), 1e-8f) / 255.0f) : 1.0f;
  float lmax = 0.f;
#pragma unroll
  for (int mt = 0; mt < 2; ++mt) {
    const int n = nb * 128 + w * 32 + mt * 16 + quad * 4;
#pragma unroll
    for (int nt = 0; nt < 4; ++nt) {
      const int o = ob * 64 + nt * 16 + l15;      // global col (0..3071 if qkv)
      const int oc = qkv ? (o & 1023) : o;        // col within region
      const int ext = extra ? 128 * extra[o] : 0;
      const float bv = bias[o];
#pragma unroll
      for (int r = 0; r < 4; ++r) {
        float v = sAB * (float)(acc[mt][nt][r] + ext) + bv;
        if (relu) v = fmaxf(v, 0.f);
        if (mode == 0) Cf[(size_t)(n + r) * O + oc] = v;
        else if (mode == 2) {
          int q = (int)fminf(fmaxf(rintf(v / sq), 0.f), 255.f) - 128;
          Cq[(size_t)(n + r) * O + oc] = (int8_t)q;
        }
        lmax = fmaxf(lmax, fabsf(v));
      }
    }
  }
  if (mode != 2)
    blockStatMax(lmax, mOut, sred, nb + (qkv ? (ob & 15) : ob) * gridDim.x);
}

// --------------------------- fused causal attention --------------------------
// R12 structure + R14 swizzle. grid 1024 = (b,h,pair,rowhalf); waves 0-1: hi
// tile (qt=15-p), waves 2-3: lo tile (qt=p), shared K/V staging; 4-buffer
// dist-3 counted-vmcnt pipeline; asm ds_read; reg P-transpose.
__global__ __launch_bounds__(256, 4) void attn_fused(
    const int8_t* __restrict__ Qq, const int8_t* __restrict__ Kq,
    const int8_t* __restrict__ Vt, float* __restrict__ ctx,
    const float* __restrict__ M, float* __restrict__ mOut) {
  __shared__ __align__(16) int8_t qtile[4096];
  __shared__ __align__(16) int8_t ktile[4][4096];
  __shared__ __align__(16) int8_t vtile[4][4096];
  __shared__ float sred[4];
  const int tid = threadIdx.x, bid = blockIdx.x;
  const int pidx = bid & 7, rh = (bid >> 3) & 1, h = (bid >> 4) & 15, b = bid >> 8;
  const int qthi = 15 - pidx, qtlo = pidx, ktmax = qthi;
  const int w = tid >> 6, lane = tid & 63, l15 = lane & 15, quad = lane >> 4;
  const int wqt = (w < 2) ? qthi : qtlo;
  const int wrow0 = rh * 32 + (w & 1) * 16;
  const float sqs = fmaxf(slotMax64(M + 13 * 64) * 0.125f, 1e-8f) / 127.0f;
  const float sk = fmaxf(slotMax64(M + 14 * 64), 1e-8f) / 127.0f;
  const float sv = fmaxf(slotMax64(M + 15 * 64), 1e-8f) / 127.0f;
  const float sqk = sqs * sk;
  const float s_attn = 1.0f / 127.0f;  // softmax global max == 1.0 exactly
  const int r0 = tid >> 2;
  const int c0 = (((tid & 3) ^ ((tid >> 2) & 3)) * 16);  // swizzled source col
  const int8_t* Kbase = Kq + (size_t)(b * 1024) * 1024 + h * 64 + c0;
  const int8_t* Vbase = Vt + (size_t)((b * 16 + h) * 64 + r0) * 1024 + c0;
  const unsigned fragoff = (unsigned)(l15 * 64 + (quad ^ (l15 & 3)) * 16);

  // ---- Phase A prologue: stage Q (1 item) + K tiles 0..2 (3 items) ----
  {
    const int qt_s = (r0 < 32) ? qthi : qtlo;
    const int qrow_g = qt_s * 64 + rh * 32 + (r0 & 31);
    gll16(Qq + ((size_t)(b * 1024 + qrow_g)) * 1024 + h * 64 + c0, qtile + tid * 16);
  }
#pragma unroll
  for (int t = 0; t < 3; ++t)
    gll16(Kbase + (size_t)(t * 64 + r0) * 1024, ktile[t] + tid * 16);
  asm volatile("s_waitcnt vmcnt(3)" ::: "memory");  // my Q landed
  asm volatile("s_barrier" ::: "memory");           // all waves' Q landed
  i32x4 aq;
  {
    const unsigned qa = ldsaddr(qtile) +
        (unsigned)((w * 16 + l15) * 64 + (quad ^ (l15 & 3)) * 16);
    asm volatile("ds_read_b128 %0, %1 offset:0" : "=v"(aq) : "v"(qa));
    asm volatile("s_waitcnt lgkmcnt(0)" ::: "memory");
  }
  const int qrow = wqt * 64 + wrow0 + l15;  // this lane's q-row (0..1023)

  // ---- Phase A: swapped QK^T; per-lane online (m,l); pipelined K staging ----
  float m_l = -1e30f, l_l = 0.f;
  for (int kt = 0; kt <= ktmax; ++kt) {
    if (kt + 2 <= ktmax)      asm volatile("s_waitcnt vmcnt(2)" ::: "memory");
    else if (kt + 1 <= ktmax) asm volatile("s_waitcnt vmcnt(1)" ::: "memory");
    else                      asm volatile("s_waitcnt vmcnt(0)" ::: "memory");
    asm volatile("s_barrier" ::: "memory");
    if (kt + 3 <= ktmax)
      gll16(Kbase + (size_t)((kt + 3) * 64 + r0) * 1024, ktile[(kt + 3) & 3] + tid * 16);
    if (kt <= wqt) {
      const unsigned ka = ldsaddr(ktile[kt & 3]) + fragoff;
      i32x4 bk[4];
      asm volatile("ds_read_b128 %0, %1 offset:0"    : "=v"(bk[0]) : "v"(ka));
      asm volatile("ds_read_b128 %0, %1 offset:1024" : "=v"(bk[1]) : "v"(ka));
      asm volatile("ds_read_b128 %0, %1 offset:2048" : "=v"(bk[2]) : "v"(ka));
      asm volatile("ds_read_b128 %0, %1 offset:3072" : "=v"(bk[3]) : "v"(ka));
      asm volatile("s_waitcnt lgkmcnt(0)" ::: "memory");
      __builtin_amdgcn_sched_barrier(0);
      const int kc0 = kt * 64 + quad * 4;
      float sc[4][4];
#pragma unroll
      for (int nt = 0; nt < 4; ++nt) {
        i32x4 z = {0, 0, 0, 0};
        i32x4 d = __builtin_amdgcn_mfma_i32_16x16x64_i8(bk[nt], aq, z, 0, 0, 0);
        if (kt == wqt) {
#pragma unroll
          for (int r = 0; r < 4; ++r)
            sc[nt][r] = (kc0 + nt * 16 + r <= qrow) ? sqk * (float)d[r] : -1e30f;
        } else {
#pragma unroll
          for (int r = 0; r < 4; ++r) sc[nt][r] = sqk * (float)d[r];
        }
      }
      float vm = sc[0][0];
#pragma unroll
      for (int nt = 0; nt < 4; ++nt)
#pragma unroll
        for (int r = 0; r < 4; ++r) vm = fmaxf(vm, sc[nt][r]);
      const float mn = fmaxf(m_l, vm);
      float sum = 0.f;
#pragma unroll
      for (int nt = 0; nt < 4; ++nt)
#pragma unroll
        for (int r = 0; r < 4; ++r) sum += __expf(sc[nt][r] - mn);
      l_l = l_l * __expf(m_l - mn) + sum;
      m_l = mn;
    }
  }
  // merge the 4 quads (lanes sharing l15 hold the same q-row)
#pragma unroll
  for (int off = 16; off <= 32; off <<= 1) {
    float om = __shfl_xor(m_l, off, 64);
    float ol = __shfl_xor(l_l, off, 64);
    float mn = fmaxf(m_l, om);
    l_l = l_l * __expf(m_l - mn) + ol * __expf(om - mn);
    m_l = mn;
  }
  const float rl127 = 127.0f / l_l;  // P*127 in [0,127] exactly -> no clamps

  // ---- Phase B: recompute, quantize P in-register, quad-transpose, PV ----
  __syncthreads();  // all waves done reading Phase-A buffers (vmcnt already 0)
#pragma unroll
  for (int t = 0; t < 3; ++t) {
    gll16(Kbase + (size_t)(t * 64 + r0) * 1024, ktile[t] + tid * 16);
    gll16(Vbase + t * 64, vtile[t] + tid * 16);
  }
  i32x4 cacc[4] = {{0, 0, 0, 0}, {0, 0, 0, 0}, {0, 0, 0, 0}, {0, 0, 0, 0}};
  for (int kt = 0; kt <= ktmax; ++kt) {
    if (kt + 2 <= ktmax)      asm volatile("s_waitcnt vmcnt(4)" ::: "memory");
    else if (kt + 1 <= ktmax) asm volatile("s_waitcnt vmcnt(2)" ::: "memory");
    else                      asm volatile("s_waitcnt vmcnt(0)" ::: "memory");
    asm volatile("s_barrier" ::: "memory");
    if (kt + 3 <= ktmax) {
      gll16(Kbase + (size_t)((kt + 3) * 64 + r0) * 1024, ktile[(kt + 3) & 3] + tid * 16);
      gll16(Vbase + (kt + 3) * 64, vtile[(kt + 3) & 3] + tid * 16);
    }
    if (kt <= wqt) {
      const unsigned ka = ldsaddr(ktile[kt & 3]) + fragoff;
      const unsigned va = ldsaddr(vtile[kt & 3]) + fragoff;
      i32x4 bk[4], bv[4];
      asm volatile("ds_read_b128 %0, %1 offset:0"    : "=v"(bk[0]) : "v"(ka));
      asm volatile("ds_read_b128 %0, %1 offset:1024" : "=v"(bk[1]) : "v"(ka));
      asm volatile("ds_read_b128 %0, %1 offset:2048" : "=v"(bk[2]) : "v"(ka));
      asm volatile("ds_read_b128 %0, %1 offset:3072" : "=v"(bk[3]) : "v"(ka));
      asm volatile("ds_read_b128 %0, %1 offset:0"    : "=v"(bv[0]) : "v"(va));
      asm volatile("ds_read_b128 %0, %1 offset:1024" : "=v"(bv[1]) : "v"(va));
      asm volatile("ds_read_b128 %0, %1 offset:2048" : "=v"(bv[2]) : "v"(va));
      asm volatile("ds_read_b128 %0, %1 offset:3072" : "=v"(bv[3]) : "v"(va));
      asm volatile("s_waitcnt lgkmcnt(0)" ::: "memory");
      __builtin_amdgcn_sched_barrier(0);
      const int kc0 = kt * 64 + quad * 4;
      unsigned Dw[4];
#pragma unroll
      for (int nt = 0; nt < 4; ++nt) {
        i32x4 z = {0, 0, 0, 0};
        i32x4 d = __builtin_amdgcn_mfma_i32_16x16x64_i8(bk[nt], aq, z, 0, 0, 0);
        unsigned wd = 0;
        if (kt == wqt) {
#pragma unroll
          for (int r = 0; r < 4; ++r) {
            float e = (kc0 + nt * 16 + r <= qrow)
                          ? __expf(sqk * (float)d[r] - m_l) * rl127 : 0.f;
            wd |= ((unsigned)(int)rintf(e)) << (8 * r);
          }
        } else {
#pragma unroll
          for (int r = 0; r < 4; ++r) {
            float e = __expf(sqk * (float)d[r] - m_l) * rl127;
            wd |= ((unsigned)(int)rintf(e)) << (8 * r);
          }
        }
        Dw[nt] = wd;
      }
      // 4x4 quad-transpose: pf[j] (k=quad*16+4j..) <- Dw[quad] @ lane quad'=j
      unsigned selfv = quadsel(Dw[0], Dw[1], Dw[2], Dw[3], quad);
      unsigned rv1 = (unsigned)__shfl_xor(
          (int)quadsel(Dw[0], Dw[1], Dw[2], Dw[3], quad ^ 1), 16, 64);
      unsigned rv2 = (unsigned)__shfl_xor(
          (int)quadsel(Dw[0], Dw[1], Dw[2], Dw[3], quad ^ 2), 32, 64);
      unsigned rv3 = (unsigned)__shfl_xor(
          (int)quadsel(Dw[0], Dw[1], Dw[2], Dw[3], quad ^ 3), 48, 64);
      i32x4 pf;
#pragma unroll
      for (int j = 0; j < 4; ++j) {
        const int t = j ^ quad;
        pf[j] = (int)((t == 0) ? selfv : (t == 1) ? rv1 : (t == 2) ? rv2 : rv3);
      }
#pragma unroll
      for (int nt = 0; nt < 4; ++nt)
        cacc[nt] = __builtin_amdgcn_mfma_i32_16x16x64_i8(pf, bv[nt], cacc[nt], 0, 0, 0);
    }
  }
  const float sc2 = s_attn * sv;
  float lmax = 0.f;
  const int orow0 = wqt * 64 + wrow0 + quad * 4;
#pragma unroll
  for (int nt = 0; nt < 4; ++nt) {
    const int d = nt * 16 + l15;
#pragma unroll
    for (int r = 0; r < 4; ++r) {
      float v = sc2 * (float)cacc[nt][r];
      ctx[((size_t)(b * 1024 + orow0 + r)) * 1024 + h * 64 + d] = v;
      lmax = fmaxf(lmax, fabsf(v));
    }
  }
  blockStatMax(lmax, mOut, sred, bid);
}

// --------------------------- residual + layernorm ---------------------------
__global__ __launch_bounds__(256) void ln_res(
    const int8_t* __restrict__ xq, const float* __restrict__ mx,
    const float* __restrict__ ao, const float* __restrict__ ma,
    float* __restrict__ x1, float* __restrict__ mOut) {
  __shared__ float red[8];
  __shared__ float sred[4];
  const int row = blockIdx.x, tid = threadIdx.x;
  const float sx = fmaxf(slotMax64(mx), 1e-8f) / 127.0f;
  const float sa = fmaxf(slotMax64(ma), 1e-8f) / 127.0f;
  char4 xv = *(const char4*)(xq + (size_t)row * 1024 + tid * 4);
  f32x4 av = *(const f32x4*)(ao + (size_t)row * 1024 + tid * 4);
  float t[4];
  t[0] = (float)xv.x * sx + fminf(fmaxf(rintf(av.x / sa), -128.f), 127.f) * sa;
  t[1] = (float)xv.y * sx + fminf(fmaxf(rintf(av.y / sa), -128.f), 127.f) * sa;
  t[2] = (float)xv.z * sx + fminf(fmaxf(rintf(av.z / sa), -128.f), 127.f) * sa;
  t[3] = (float)xv.w * sx + fminf(fmaxf(rintf(av.w / sa), -128.f), 127.f) * sa;
  float s = waveSum(t[0] + t[1] + t[2] + t[3]);
  if ((tid & 63) == 0) red[tid >> 6] = s;
  __syncthreads();
  const float mean = (red[0] + red[1] + red[2] + red[3]) * (1.0f / 1024.0f);
  float vs = 0.f;
#pragma unroll
  for (int i = 0; i < 4; ++i) { float d = t[i] - mean; vs += d * d; }
  vs = waveSum(vs);
  if ((tid & 63) == 0) red[4 + (tid >> 6)] = vs;
  __syncthreads();
  const float var = (red[4] + red[5] + red[6] + red[7]) * (1.0f / 1024.0f);
  const float rs = sqrtf(var + 1e-5f);
  f32x4 o;
  o.x = (t[0] - mean) / rs;
  o.y = (t[1] - mean) / rs;
  o.z = (t[2] - mean) / rs;
  o.w = (t[3] - mean) / rs;
  *(f32x4*)(x1 + (size_t)row * 1024 + tid * 4) = o;
  float lmax = fmaxf(fmaxf(fabsf(o.x), fabsf(o.y)), fmaxf(fabsf(o.z), fabsf(o.w)));
  blockStatMax(lmax, mOut, sred, row);
}

__global__ __launch_bounds__(256) void ln_final(
    const int8_t* __restrict__ x1q, const float* __restrict__ mx1,
    const float* __restrict__ h2, const float* __restrict__ mh2,
    float* __restrict__ out) {
  __shared__ float red[8];
  const int row = blockIdx.x, tid = threadIdx.x;
  const float s1 = fmaxf(slotMax64(mx1), 1e-8f) / 127.0f;
  const float s2 = fmaxf(slotMax64(mh2), 1e-8f) / 127.0f;
  char4 xv = *(const char4*)(x1q + (size_t)row * 1024 + tid * 4);
  f32x4 hv = *(const f32x4*)(h2 + (size_t)row * 1024 + tid * 4);
  float t[4];
  t[0] = (float)xv.x * s1 + fminf(fmaxf(rintf(hv.x / s2), -128.f), 127.f) * s2;
  t[1] = (float)xv.y * s1 + fminf(fmaxf(rintf(hv.y / s2), -128.f), 127.f) * s2;
  t[2] = (float)xv.z * s1 + fminf(fmaxf(rintf(hv.z / s2), -128.f), 127.f) * s2;
  t[3] = (float)xv.w * s1 + fminf(fmaxf(rintf(hv.w / s2), -128.f), 127.f) * s2;
  float s = waveSum(t[0] + t[1] + t[2] + t[3]);
  if ((tid & 63) == 0) red[tid >> 6] = s;
  __syncthreads();
  const float mean = (red[0] + red[1] + red[2] + red[3]) * (1.0f / 1024.0f);
  float vs = 0.f;
#pragma unroll
  for (int i = 0; i < 4; ++i) { float d = t[i] - mean; vs += d * d; }
  vs = waveSum(vs);
  if ((tid & 63) == 0) red[4 + (tid >> 6)] = vs;
  __syncthreads();
  const float var = (red[4] + red[5] + red[6] + red[7]) * (1.0f / 1024.0f);
  const float rs = sqrtf(var + 1e-5f);
  f32x4 o;
  o.x = (t[0] - mean) / rs;
  o.y = (t[1] - mean) / rs;
  o.z = (t[2] - mean) / rs;
  o.w = (t[3] - mean) / rs;
  *(f32x4*)(out + (size_t)row * 1024 + tid * 4) = o;
}

// --------------------------- workspace layout --------------------------------
static constexpr size_t MB = 1u << 20;
static constexpr size_t OFF_M     = 0;          // 21 stats x 64 f32 slots
static constexpr size_t OFF_FLAG  = 6400;
static constexpr size_t OFF_BIASQ = 8192;
static constexpr size_t OFF_BIASK = OFF_BIASQ + 4096;
static constexpr size_t OFF_BIASV = OFF_BIASK + 4096;
static constexpr size_t OFF_BIASO = OFF_BIASV + 4096;
static constexpr size_t OFF_BIAS1 = OFF_BIASO + 4096;
static constexpr size_t OFF_BIAS2 = OFF_BIAS1 + 16384;
static constexpr size_t OFF_RS    = OFF_BIAS2 + 4096;
static constexpr size_t OFF_XQ    = 65536;
static constexpr size_t OFF_WQQ   = OFF_XQ  + 4 * MB;
static constexpr size_t OFF_WKQ   = OFF_WQQ + 1 * MB;
static constexpr size_t OFF_WVQ   = OFF_WKQ + 1 * MB;
static constexpr size_t OFF_WOQ   = OFF_WVQ + 1 * MB;
static constexpr size_t OFF_W1Q   = OFF_WOQ + 1 * MB;
static constexpr size_t OFF_W2Q   = OFF_W1Q + 4 * MB;
static constexpr size_t OFF_X1Q   = OFF_W2Q + 4 * MB;
static constexpr size_t OFF_A1    = OFF_X1Q + 4 * MB;     // arena1, 16 MB
static constexpr size_t OFF_A2    = OFF_A1 + 16 * MB;     // arena2 (f32), 16 MB
static constexpr size_t OFF_HF    = OFF_A2 + 16 * MB;     // optional 64 MB f32

extern "C" void kernel_launch(void* const* d_in, const int* in_sizes, int n_in,
                              void* d_out, int out_size, void* d_ws, size_t ws_size,
                              hipStream_t stream) {
  (void)n_in; (void)out_size;
  char* ws = (char*)d_ws;
  float* M = (float*)(ws + OFF_M);
  int* FLAG = (int*)(ws + OFF_FLAG);
  float* BIASQ = (float*)(ws + OFF_BIASQ);
  float* BIASK = (float*)(ws + OFF_BIASK);
  float* BIASV = (float*)(ws + OFF_BIASV);
  float* BIASO = (float*)(ws + OFF_BIASO);
  float* BIAS1 = (float*)(ws + OFF_BIAS1);
  float* BIAS2 = (float*)(ws + OFF_BIAS2);
  int* RS = (int*)(ws + OFF_RS);
  int8_t* XQ  = (int8_t*)(ws + OFF_XQ);
  int8_t* WQQ = (int8_t*)(ws + OFF_WQQ);
  int8_t* WKQ = (int8_t*)(ws + OFF_WKQ);
  int8_t* WVQ = (int8_t*)(ws + OFF_WVQ);
  int8_t* WOQ = (int8_t*)(ws + OFF_WOQ);
  int8_t* W1Q = (int8_t*)(ws + OFF_W1Q);
  int8_t* W2Q = (int8_t*)(ws + OFF_W2Q);
  int8_t* X1Q = (int8_t*)(ws + OFF_X1Q);
  int8_t* QQ   = (int8_t*)(ws + OFF_A1);
  int8_t* KQQ  = (int8_t*)(ws + OFF_A1 + 4 * MB);
  int8_t* VT   = (int8_t*)(ws + OFF_A1 + 8 * MB);
  int8_t* CTXQ = (int8_t*)(ws + OFF_A1 + 12 * MB);
  float*  X1F  = (float*)(ws + OFF_A1);
  int8_t* HQ   = (int8_t*)(ws + OFF_A1);
  float* FBUF = (float*)(ws + OFF_A2);   // serial reuse: QF/KF/VF/ctx/ao/h2
  const bool bigws = ws_size >= OFF_HF + 64 * MB;

  hipMemsetAsync(M, 0, 8192, stream);
  detect_f32<<<1, 64, 0, stream>>>((const u16*)d_in[0], FLAG);

  AJobs aj;
  const int ablk[13] = {512, 128, 1, 128, 1, 128, 1, 128, 1, 512, 2, 512, 1};
  int bs = 0;
  for (int i = 0; i < 13; ++i) {
    aj.p[i] = d_in[i];
    aj.n4[i] = in_sizes[i] / 4;
    aj.bstart[i] = bs;
    bs += ablk[i];
  }
  aj.bstart[13] = bs;
  absmax_multi<<<bs, 256, 0, stream>>>(aj, M, FLAG);

  quant_in_signed<<<1024, 256, 0, stream>>>(d_in[0], XQ, M + 0 * 64, FLAG, in_sizes[0] / 4);

  WJobs wj;
  const int widx[5] = {1, 3, 5, 7, 9};
  int8_t* wout[5] = {WQQ, WKQ, WVQ, WOQ, W1Q};
  const int wblk[5] = {128, 128, 128, 128, 512};
  int wb = 0;
  for (int j = 0; j < 5; ++j) {
    wj.in[j] = d_in[widx[j]];
    wj.out[j] = wout[j];
    wj.mslot[j] = widx[j];
    wj.n4[j] = in_sizes[widx[j]] / 4;
    wj.bstart[j] = wb;
    wb += wblk[j];
  }
  wj.bstart[5] = wb;
  quant_w_multi<<<wb, 256, 0, stream>>>(wj, M, FLAG);
  quant_w2_rs<<<1024, 256, 0, stream>>>(d_in[11], W2Q, M + 11 * 64, FLAG, RS);

  BJobs bj;
  const int bidx[6] = {2, 4, 6, 8, 10, 12};
  float* bout[6] = {BIASQ, BIASK, BIASV, BIASO, BIAS1, BIAS2};
  for (int j = 0; j < 6; ++j) {
    bj.in[j] = d_in[bidx[j]];
    bj.out[j] = bout[j];
    bj.mslot[j] = bidx[j];
    bj.n4[j] = in_sizes[bidx[j]] / 4;
  }
  fq_bias_multi<<<6, 256, 0, stream>>>(bj, M, FLAG);

  if (bigws) {
    // Fused Q/K/V projection: one dispatch, B = [WQ;WK;WV] (contiguous rows),
    // outputs to HF + region*16MB (48MB of the 64MB scratch).
    float* HF = (float*)(ws + OFF_HF);
    gemm_i8<<<dim3(32, 48), 256, 0, stream>>>(XQ, WQQ, HF, nullptr, M + 0 * 64, 1.f, 127.f, M + 1 * 64, BIASQ, nullptr, 0, 0, 1, M + 13 * 64, 1024, 1024);
    quant_f32_signed<<<2048, 256, 0, stream>>>(HF, QQ, M + 13 * 64, 0.125f, 1024 * 1024);
    quant_f32_signed<<<2048, 256, 0, stream>>>(HF + (1u << 22), KQQ, M + 14 * 64, 1.0f, 1024 * 1024);
    quant_v_t<<<dim3(64, 16), 256, 0, stream>>>(HF + (2u << 22), VT, M + 15 * 64);
  } else {
    gemm_i8<<<dim3(32, 16), 256, 0, stream>>>(XQ, WQQ, FBUF, nullptr, M + 0 * 64, 1.f, 127.f, M + 1 * 64, BIASQ, nullptr, 0, 0, 0, M + 13 * 64, 1024, 1024);
    quant_f32_signed<<<2048, 256, 0, stream>>>(FBUF, QQ, M + 13 * 64, 0.125f, 1024 * 1024);
    gemm_i8<<<dim3(32, 16), 256, 0, stream>>>(XQ, WKQ, FBUF, nullptr, M + 0 * 64, 1.f, 127.f, M + 3 * 64, BIASK, nullptr, 0, 0, 0, M + 14 * 64, 1024, 1024);
    quant_f32_signed<<<2048, 256, 0, stream>>>(FBUF, KQQ, M + 14 * 64, 1.0f, 1024 * 1024);
    gemm_i8<<<dim3(32, 16), 256, 0, stream>>>(XQ, WVQ, FBUF, nullptr, M + 0 * 64, 1.f, 127.f, M + 5 * 64, BIASV, nullptr, 0, 0, 0, M + 15 * 64, 1024, 1024);
    quant_v_t<<<dim3(64, 16), 256, 0, stream>>>(FBUF, VT, M + 15 * 64);
  }

  attn_fused<<<1024, 256, 0, stream>>>(QQ, KQQ, VT, FBUF, M, M + 16 * 64);
  quant_f32_signed<<<2048, 256, 0, stream>>>(FBUF, CTXQ, M + 16 * 64, 1.0f, 1024 * 1024);

  gemm_i8<<<dim3(32, 16), 256, 0, stream>>>(CTXQ, WOQ, FBUF, nullptr, M + 16 * 64, 1.f, 127.f, M + 7 * 64, BIASO, nullptr, 0, 0, 0, M + 17 * 64, 1024, 1024);

  ln_res<<<4096, 256, 0, stream>>>(XQ, M + 0 * 64, FBUF, M + 17 * 64, X1F, M + 18 * 64);
  quant_f32_signed<<<2048, 256, 0, stream>>>(X1F, X1Q, M + 18 * 64, 1.0f, 1024 * 1024);

  if (bigws) {
    // MLP1 once: mode 0 writes f32 h (64MB scratch) + stats; then exact
    // u8-128 requant (identical grid to mode-2 epilogue). Bit-identical.
    float* HF = (float*)(ws + OFF_HF);
    gemm_i8<<<dim3(32, 64), 256, 0, stream>>>(X1Q, W1Q, HF, nullptr, M + 18 * 64, 1.f, 127.f, M + 9 * 64, BIAS1, nullptr, 1, 0, 0, M + 19 * 64, 1024, 4096);
    quant_f32_u8<<<2048, 256, 0, stream>>>(HF, HQ, M + 19 * 64, 4096 * 1024);
  } else {
    gemm_i8<<<dim3(32, 64), 256, 0, stream>>>(X1Q, W1Q, nullptr, nullptr, M + 18 * 64, 1.f, 127.f, M + 9 * 64, BIAS1, nullptr, 1, 1, 0, M + 19 * 64, 1024, 4096);
    gemm_i8<<<dim3(32, 64), 256, 0, stream>>>(X1Q, W1Q, nullptr, HQ,      M + 18 * 64, 1.f, 127.f, M + 9 * 64, BIAS1, nullptr, 1, 2, 0, M + 19 * 64, 1024, 4096);
  }

  gemm_i8<<<dim3(32, 16), 256, 0, stream>>>(HQ, W2Q, FBUF, nullptr, M + 19 * 64, 1.f, 255.f, M + 11 * 64, BIAS2, RS, 0, 0, 0, M + 20 * 64, 4096, 1024);

  ln_final<<<4096, 256, 0, stream>>>(X1Q, M + 18 * 64, FBUF, M + 20 * 64, (float*)d_out);
}

// Round 10
// 371.257 us; speedup vs baseline: 1.2573x; 1.0415x over previous
//
#include <hip/hip_runtime.h>
#include <stdint.h>
#include <stddef.h>

// ---------------------------------------------------------------------------
// Fully fake-quantized transformer block on MI355X (gfx950).
// i8 MFMA GEMMs (exact i32 acc), flash-style fused attention.
// R17: MLP1 GEMM identified as L2->LDS staging-BW bound: staged traffic =
// grid*(BM+BN)*K = 2048*192*4096 = 1.57GB @ ~34.5TB/s = 45.6us ~= measured
// 43.0us. Fix: gemm_i8_128 (BN=128): traffic factor (1/BM+1/BN) drops 33%
// (1.05GB -> ~30us floor), 16 MFMA/iter (better latency coverage), LDS
// 3x16KB=48KB (3 blocks/CU). Used for MLP1 (grid 32x32) and fused QKV
// (grid 32x24, region=ob>>3, col=o&1023; 128-col tiles never cross a 1024
// boundary). W2/WO keep 128x64 (N=1024 at BN=128 -> 1 block/CU, worse).
// R16: fused QKV via HF scratch + stride fix; MLP1 single-pass.
// R13-R11: counted-vmcnt + asm ds_read pipelines; R9: attn structure.
// ---------------------------------------------------------------------------

typedef unsigned short u16;
typedef __attribute__((ext_vector_type(4))) int   i32x4;
typedef __attribute__((ext_vector_type(4))) float f32x4;

#define DEV __device__ __forceinline__

DEV float bf2f(u16 u) { return __uint_as_float(((unsigned)u) << 16); }
DEV void atomicMaxF(float* p, float v) { atomicMax((unsigned*)p, __float_as_uint(v)); }
DEV float waveMax(float v) {
#pragma unroll
  for (int o = 32; o; o >>= 1) v = fmaxf(v, __shfl_xor(v, o, 64));
  return v;
}
DEV float waveSum(float v) {
#pragma unroll
  for (int o = 32; o; o >>= 1) v += __shfl_xor(v, o, 64);
  return v;
}
DEV int waveSumI(int v) {
#pragma unroll
  for (int o = 32; o; o >>= 1) v += __shfl_xor(v, o, 64);
  return v;
}
DEV void blockStatMax(float v, float* __restrict__ slot64, float* sred4, int flatBlk) {
  v = waveMax(v);
  const int tid = threadIdx.x;
  if ((tid & 63) == 0) sred4[tid >> 6] = v;
  __syncthreads();
  if (tid == 0) {
    float m = fmaxf(fmaxf(sred4[0], sred4[1]), fmaxf(sred4[2], sred4[3]));
    atomicMaxF(&slot64[flatBlk & 63], m);
  }
}
DEV float slotMax64(const float* __restrict__ s) {
  float m = 0.f;
#pragma unroll
  for (int i = 0; i < 64; ++i) m = fmaxf(m, s[i]);
  return m;
}
DEV f32x4 ld4(const void* p, int i4, int isf32) {
  if (isf32) return ((const f32x4*)p)[i4];
  ushort4 u = ((const ushort4*)p)[i4];
  return (f32x4){bf2f(u.x), bf2f(u.y), bf2f(u.z), bf2f(u.w)};
}
DEV void gll16(const void* g, void* l) {
  __builtin_amdgcn_global_load_lds((__attribute__((address_space(1))) void*)(g),
                                   (__attribute__((address_space(3))) void*)(l),
                                   16, 0, 0);
}
DEV unsigned ldsaddr(const void* p) {
  return (unsigned)(size_t)(__attribute__((address_space(3))) const void*)p;
}
DEV unsigned quadsel(unsigned a, unsigned b, unsigned c, unsigned d, int idx) {
  unsigned lo = (idx & 1) ? b : a;
  unsigned hi = (idx & 1) ? d : c;
  return (idx & 2) ? hi : lo;
}

__global__ void detect_f32(const u16* __restrict__ x, int* __restrict__ flag) {
  const int tid = threadIdx.x;
  int cnt = 0;
#pragma unroll
  for (int i = 0; i < 16; ++i) {
    u16 u = x[tid * 16 + i];
    if ((u & 0x7f80u) >= 0x4380u) ++cnt;
  }
  cnt = waveSumI(cnt);
  if (tid == 0) flag[0] = (cnt > 16) ? 1 : 0;
}

struct AJobs { const void* p[13]; int n4[13]; int bstart[14]; };

__global__ __launch_bounds__(256) void absmax_multi(AJobs J, float* __restrict__ M,
                                                    const int* __restrict__ flagp) {
  __shared__ float sred[4];
  const int isf32 = flagp[0];
  const int blk = blockIdx.x, tid = threadIdx.x;
  int j = 0;
  while (j < 12 && blk >= J.bstart[j + 1]) ++j;
  const int lb = blk - J.bstart[j];
  const int nb = J.bstart[j + 1] - J.bstart[j];
  float mx = 0.f;
  const void* p = J.p[j];
  for (int i = lb * 256 + tid; i < J.n4[j]; i += nb * 256) {
    f32x4 v = ld4(p, i, isf32);
    mx = fmaxf(mx, fmaxf(fmaxf(fabsf(v.x), fabsf(v.y)),
                         fmaxf(fabsf(v.z), fabsf(v.w))));
  }
  blockStatMax(mx, M + j * 64, sred, lb);
}

__global__ __launch_bounds__(256) void quant_in_signed(
    const void* __restrict__ in, int8_t* __restrict__ out,
    const float* __restrict__ mp, const int* __restrict__ flagp, int n4) {
  const int isf32 = flagp[0];
  const float s = fmaxf(slotMax64(mp), 1e-8f) / 127.0f;
  char4* op = (char4*)out;
  for (int i = blockIdx.x * 256 + threadIdx.x; i < n4; i += gridDim.x * 256) {
    f32x4 v = ld4(in, i, isf32);
    char4 q;
    q.x = (signed char)fminf(fmaxf(rintf(v.x / s), -128.f), 127.f);
    q.y = (signed char)fminf(fmaxf(rintf(v.y / s), -128.f), 127.f);
    q.z = (signed char)fminf(fmaxf(rintf(v.z / s), -128.f), 127.f);
    q.w = (signed char)fminf(fmaxf(rintf(v.w / s), -128.f), 127.f);
    op[i] = q;
  }
}

struct WJobs { const void* in[5]; int8_t* out[5]; int mslot[5]; int n4[5]; int bstart[6]; };

__global__ __launch_bounds__(256) void quant_w_multi(WJobs J, const float* __restrict__ M,
                                                     const int* __restrict__ flagp) {
  const int isf32 = flagp[0];
  const int blk = blockIdx.x, tid = threadIdx.x;
  int j = 0;
  while (j < 4 && blk >= J.bstart[j + 1]) ++j;
  const int lb = blk - J.bstart[j];
  const int nb = J.bstart[j + 1] - J.bstart[j];
  const float s = fmaxf(slotMax64(M + J.mslot[j] * 64), 1e-8f) / 127.0f;
  const void* p = J.in[j];
  char4* o = (char4*)J.out[j];
  for (int i = lb * 256 + tid; i < J.n4[j]; i += nb * 256) {
    f32x4 v = ld4(p, i, isf32);
    char4 q;
    q.x = (signed char)fminf(fmaxf(rintf(v.x / s), -127.f), 127.f);
    q.y = (signed char)fminf(fmaxf(rintf(v.y / s), -127.f), 127.f);
    q.z = (signed char)fminf(fmaxf(rintf(v.z / s), -127.f), 127.f);
    q.w = (signed char)fminf(fmaxf(rintf(v.w / s), -127.f), 127.f);
    o[i] = q;
  }
}

__global__ __launch_bounds__(256) void quant_w2_rs(
    const void* __restrict__ w2, int8_t* __restrict__ out,
    const float* __restrict__ mp, const int* __restrict__ flagp,
    int* __restrict__ rowsum) {
  const int isf32 = flagp[0];
  const int row = blockIdx.x, tid = threadIdx.x;
  const float s = fmaxf(slotMax64(mp), 1e-8f) / 127.0f;
  char4* op = (char4*)(out + (size_t)row * 4096);
  int sum = 0;
  for (int i = tid; i < 1024; i += 256) {
    f32x4 v = ld4(w2, row * 1024 + i, isf32);
    char4 q;
    q.x = (signed char)fminf(fmaxf(rintf(v.x / s), -127.f), 127.f);
    q.y = (signed char)fminf(fmaxf(rintf(v.y / s), -127.f), 127.f);
    q.z = (signed char)fminf(fmaxf(rintf(v.z / s), -127.f), 127.f);
    q.w = (signed char)fminf(fmaxf(rintf(v.w / s), -127.f), 127.f);
    op[i] = q;
    sum += (int)q.x + (int)q.y + (int)q.z + (int)q.w;
  }
  sum = waveSumI(sum);
  __shared__ int rs4[4];
  if ((tid & 63) == 0) rs4[tid >> 6] = sum;
  __syncthreads();
  if (tid == 0) rowsum[row] = rs4[0] + rs4[1] + rs4[2] + rs4[3];
}

struct BJobs { const void* in[6]; float* out[6]; int mslot[6]; int n4[6]; };

__global__ __launch_bounds__(256) void fq_bias_multi(BJobs J, const float* __restrict__ M,
                                                     const int* __restrict__ flagp) {
  const int isf32 = flagp[0];
  const int j = blockIdx.x;
  const float s = fmaxf(slotMax64(M + J.mslot[j] * 64), 1e-8f) / 127.0f;
  float* o = J.out[j];
  for (int i = threadIdx.x; i < J.n4[j]; i += 256) {
    f32x4 v = ld4(J.in[j], i, isf32);
    f32x4 r;
    r.x = fminf(fmaxf(rintf(v.x / s), -128.f), 127.f) * s;
    r.y = fminf(fmaxf(rintf(v.y / s), -128.f), 127.f) * s;
    r.z = fminf(fmaxf(rintf(v.z / s), -128.f), 127.f) * s;
    r.w = fminf(fmaxf(rintf(v.w / s), -128.f), 127.f) * s;
    *(f32x4*)(o + i * 4) = r;
  }
}

__global__ __launch_bounds__(256) void quant_f32_signed(
    const float* __restrict__ in, int8_t* __restrict__ out,
    const float* __restrict__ mp, float pre, int n4) {
  const float s = fmaxf(slotMax64(mp) * pre, 1e-8f) / 127.0f;
  const f32x4* ip = (const f32x4*)in;
  char4* op = (char4*)out;
  for (int i = blockIdx.x * 256 + threadIdx.x; i < n4; i += gridDim.x * 256) {
    f32x4 v = ip[i];
    char4 q;
    q.x = (signed char)fminf(fmaxf(rintf(v.x * pre / s), -128.f), 127.f);
    q.y = (signed char)fminf(fmaxf(rintf(v.y * pre / s), -128.f), 127.f);
    q.z = (signed char)fminf(fmaxf(rintf(v.z * pre / s), -128.f), 127.f);
    q.w = (signed char)fminf(fmaxf(rintf(v.w * pre / s), -128.f), 127.f);
    op[i] = q;
  }
}

// u8-128 requant matching gemm mode-2 epilogue exactly: s = max/255,
// q = clip(rint(v/s),0,255) - 128.
__global__ __launch_bounds__(256) void quant_f32_u8(
    const float* __restrict__ in, int8_t* __restrict__ out,
    const float* __restrict__ mp, int n4) {
  const float s = fmaxf(slotMax64(mp), 1e-8f) / 255.0f;
  const f32x4* ip = (const f32x4*)in;
  char4* op = (char4*)out;
  for (int i = blockIdx.x * 256 + threadIdx.x; i < n4; i += gridDim.x * 256) {
    f32x4 v = ip[i];
    char4 q;
    q.x = (signed char)((int)fminf(fmaxf(rintf(v.x / s), 0.f), 255.f) - 128);
    q.y = (signed char)((int)fminf(fmaxf(rintf(v.y / s), 0.f), 255.f) - 128);
    q.z = (signed char)((int)fminf(fmaxf(rintf(v.z / s), 0.f), 255.f) - 128);
    q.w = (signed char)((int)fminf(fmaxf(rintf(v.w / s), 0.f), 255.f) - 128);
    op[i] = q;
  }
}

__global__ __launch_bounds__(256) void quant_v_t(
    const float* __restrict__ V, int8_t* __restrict__ Vt,
    const float* __restrict__ mp) {
  __shared__ float tile[64][65];
  const int bh = blockIdx.x, st = blockIdx.y;
  const int b = bh >> 4, h = bh & 15;
  const int tid = threadIdx.x;
  const float s = fmaxf(slotMax64(mp), 1e-8f) / 127.0f;
  const int r = tid >> 2, c = (tid & 3) * 16;
  const float* src = V + ((size_t)(b * 1024 + st * 64 + r)) * 1024 + h * 64 + c;
#pragma unroll
  for (int g = 0; g < 4; ++g) {
    f32x4 v = *(const f32x4*)(src + g * 4);
    tile[r][c + g * 4 + 0] = v.x;
    tile[r][c + g * 4 + 1] = v.y;
    tile[r][c + g * 4 + 2] = v.z;
    tile[r][c + g * 4 + 3] = v.w;
  }
  __syncthreads();
  unsigned wds[4];
#pragma unroll
  for (int g = 0; g < 4; ++g) {
    unsigned wd = 0;
#pragma unroll
    for (int k = 0; k < 4; ++k) {
      float v = tile[c + g * 4 + k][r];
      int q = (int)fminf(fmaxf(rintf(v / s), -128.f), 127.f);
      wd |= ((unsigned)(unsigned char)(signed char)q) << (8 * k);
    }
    wds[g] = wd;
  }
  i32x4 ov = {(int)wds[0], (int)wds[1], (int)wds[2], (int)wds[3]};
  *(i32x4*)(Vt + ((size_t)((b * 16 + h) * 64 + r)) * 1024 + st * 64 + c) = ov;
}

// ------- int8 GEMM (128x64 tile, 3-buffer, dist-2) — used for WO / W2 --------
// mode 0: store f32 Cf, stat->mOut ; mode 1: stats only ; mode 2: requant u8-128
__global__ __launch_bounds__(256) void gemm_i8(
    const int8_t* __restrict__ A, const int8_t* __restrict__ B,
    float* __restrict__ Cf, int8_t* __restrict__ Cq,
    const float* __restrict__ mA, float preA, float qmaxA,
    const float* __restrict__ mB,
    const float* __restrict__ bias, const int* __restrict__ extra,
    int relu, int mode, float* __restrict__ mOut, int K, int O) {
  __shared__ __align__(16) int8_t smem[3][12288];
  __shared__ float sred[4];
  const int tid = threadIdx.x;
  const int nb = blockIdx.x, ob = blockIdx.y;
  const int w = tid >> 6, lane = tid & 63, l15 = lane & 15, quad = lane >> 4;
  i32x4 acc[2][4];
#pragma unroll
  for (int i = 0; i < 2; ++i)
#pragma unroll
    for (int j = 0; j < 4; ++j) acc[i][j] = (i32x4){0, 0, 0, 0};
  const int r0 = tid >> 2;
  const int c0 = (((tid & 3) ^ ((tid >> 2) & 3)) * 16);  // swizzled source col
  const int8_t* Ab = A + (size_t)(nb * 128) * K;
  const int8_t* Bb = B + (size_t)(ob * 64) * K;
  const int nk = K >> 6;
  const int slot = (quad ^ (l15 & 3)) * 16;              // swizzled read slot
  const int aoffl = (w * 32 + l15) * 64 + slot;
  const int boffl = 8192 + l15 * 64 + slot;
  for (int t = 0; t < 2 && t < nk; ++t) {
    const size_t kt0 = (size_t)t << 6;
    int8_t* d = smem[t];
    gll16(Ab + (size_t)r0 * K + kt0 + c0, d + tid * 16);
    gll16(Ab + (size_t)(r0 + 64) * K + kt0 + c0, d + 4096 + tid * 16);
    gll16(Bb + (size_t)r0 * K + kt0 + c0, d + 8192 + tid * 16);
  }
  int cb = 0, ib = 2;
  for (int i = 0; i < nk; ++i) {
    if (i + 1 < nk) asm volatile("s_waitcnt vmcnt(3)" ::: "memory");
    else            asm volatile("s_waitcnt vmcnt(0)" ::: "memory");
    asm volatile("s_barrier" ::: "memory");
    if (i + 2 < nk) {
      const size_t kt0 = (size_t)(i + 2) << 6;
      int8_t* d = smem[ib];
      gll16(Ab + (size_t)r0 * K + kt0 + c0, d + tid * 16);
      gll16(Ab + (size_t)(r0 + 64) * K + kt0 + c0, d + 4096 + tid * 16);
      gll16(Bb + (size_t)r0 * K + kt0 + c0, d + 8192 + tid * 16);
      ib = (ib == 2) ? 0 : ib + 1;
    }
    const unsigned a_addr = ldsaddr(smem[cb] + aoffl);
    const unsigned b_addr = ldsaddr(smem[cb] + boffl);
    cb = (cb == 2) ? 0 : cb + 1;
    i32x4 af[2], bf[4];
    asm volatile("ds_read_b128 %0, %1 offset:0"    : "=v"(af[0]) : "v"(a_addr));
    asm volatile("ds_read_b128 %0, %1 offset:1024" : "=v"(af[1]) : "v"(a_addr));
    asm volatile("ds_read_b128 %0, %1 offset:0"    : "=v"(bf[0]) : "v"(b_addr));
    asm volatile("ds_read_b128 %0, %1 offset:1024" : "=v"(bf[1]) : "v"(b_addr));
    asm volatile("ds_read_b128 %0, %1 offset:2048" : "=v"(bf[2]) : "v"(b_addr));
    asm volatile("ds_read_b128 %0, %1 offset:3072" : "=v"(bf[3]) : "v"(b_addr));
    asm volatile("s_waitcnt lgkmcnt(0)" ::: "memory");
    __builtin_amdgcn_sched_barrier(0);
#pragma unroll
    for (int mt = 0; mt < 2; ++mt)
#pragma unroll
      for (int nt = 0; nt < 4; ++nt)
        acc[mt][nt] = __builtin_amdgcn_mfma_i32_16x16x64_i8(af[mt], bf[nt], acc[mt][nt], 0, 0, 0);
  }
  const float sA = fmaxf(slotMax64(mA) * preA, 1e-8f) / qmaxA;
  const float sB = fmaxf(slotMax64(mB), 1e-8f) / 127.0f;
  const float sAB = sA * sB;
  const float sq = (mode == 2) ? (fmaxf(slotMax64(mOut), 1e-8f) / 255.0f) : 1.0f;
  float lmax = 0.f;
#pragma unroll
  for (int mt = 0; mt < 2; ++mt) {
    const int n = nb * 128 + w * 32 + mt * 16 + quad * 4;
#pragma unroll
    for (int nt = 0; nt < 4; ++nt) {
      const int o = ob * 64 + nt * 16 + l15;
      const int ext = extra ? 128 * extra[o] : 0;
      const float bv = bias[o];
#pragma unroll
      for (int r = 0; r < 4; ++r) {
        float v = sAB * (float)(acc[mt][nt][r] + ext) + bv;
        if (relu) v = fmaxf(v, 0.f);
        if (mode == 0) Cf[(size_t)(n + r) * O + o] = v;
        else if (mode == 2) {
          int q = (int)fminf(fmaxf(rintf(v / sq), 0.f), 255.f) - 128;
          Cq[(size_t)(n + r) * O + o] = (int8_t)q;
        }
        lmax = fmaxf(lmax, fabsf(v));
      }
    }
  }
  if (mode != 2)
    blockStatMax(lmax, mOut, sred, nb + ob * gridDim.x);
}

// ---- int8 GEMM (128x128 tile, 3-buffer, dist-2) — MLP1 + fused QKV ----------
// mode 0 only (store f32 Cf + stats). qkv=1: region = ob>>3 (BN=128 => 8
// ob-blocks per 1024-col region); Cf += region*4M floats; mB += region*128;
// mOut += region*64; bias global; col = o & 1023.
__global__ __launch_bounds__(256) void gemm_i8_128(
    const int8_t* __restrict__ A, const int8_t* __restrict__ B,
    float* __restrict__ Cf,
    const float* __restrict__ mA, float preA, float qmaxA,
    const float* __restrict__ mB,
    const float* __restrict__ bias,
    int relu, int qkv, float* __restrict__ mOut, int K, int O) {
  __shared__ __align__(16) int8_t smem[3][16384];  // A[128][64] | B[128][64]
  __shared__ float sred[4];
  const int tid = threadIdx.x;
  const int nb = blockIdx.x, ob = blockIdx.y;
  const int w = tid >> 6, lane = tid & 63, l15 = lane & 15, quad = lane >> 4;
  i32x4 acc[2][8];
#pragma unroll
  for (int i = 0; i < 2; ++i)
#pragma unroll
    for (int j = 0; j < 8; ++j) acc[i][j] = (i32x4){0, 0, 0, 0};
  const int r0 = tid >> 2;
  const int c0 = (((tid & 3) ^ ((tid >> 2) & 3)) * 16);  // swizzled source col
  const int8_t* Ab = A + (size_t)(nb * 128) * K;
  const int8_t* Bb = B + (size_t)(ob * 128) * K;
  const int nk = K >> 6;
  const int slot = (quad ^ (l15 & 3)) * 16;              // swizzled read slot
  const int aoffl = (w * 32 + l15) * 64 + slot;
  const int boffl = 8192 + l15 * 64 + slot;
  for (int t = 0; t < 2 && t < nk; ++t) {
    const size_t kt0 = (size_t)t << 6;
    int8_t* d = smem[t];
    gll16(Ab + (size_t)r0 * K + kt0 + c0, d + tid * 16);
    gll16(Ab + (size_t)(r0 + 64) * K + kt0 + c0, d + 4096 + tid * 16);
    gll16(Bb + (size_t)r0 * K + kt0 + c0, d + 8192 + tid * 16);
    gll16(Bb + (size_t)(r0 + 64) * K + kt0 + c0, d + 12288 + tid * 16);
  }
  int cb = 0, ib = 2;
  for (int i = 0; i < nk; ++i) {
    if (i + 1 < nk) asm volatile("s_waitcnt vmcnt(4)" ::: "memory");
    else            asm volatile("s_waitcnt vmcnt(0)" ::: "memory");
    asm volatile("s_barrier" ::: "memory");
    if (i + 2 < nk) {
      const size_t kt0 = (size_t)(i + 2) << 6;
      int8_t* d = smem[ib];
      gll16(Ab + (size_t)r0 * K + kt0 + c0, d + tid * 16);
      gll16(Ab + (size_t)(r0 + 64) * K + kt0 + c0, d + 4096 + tid * 16);
      gll16(Bb + (size_t)r0 * K + kt0 + c0, d + 8192 + tid * 16);
      gll16(Bb + (size_t)(r0 + 64) * K + kt0 + c0, d + 12288 + tid * 16);
      ib = (ib == 2) ? 0 : ib + 1;
    }
    const unsigned a_addr = ldsaddr(smem[cb] + aoffl);
    const unsigned b_addr = ldsaddr(smem[cb] + boffl);
    cb = (cb == 2) ? 0 : cb + 1;
    i32x4 af[2], bf[8];
    asm volatile("ds_read_b128 %0, %1 offset:0"    : "=v"(af[0]) : "v"(a_addr));
    asm volatile("ds_read_b128 %0, %1 offset:1024" : "=v"(af[1]) : "v"(a_addr));
    asm volatile("ds_read_b128 %0, %1 offset:0"    : "=v"(bf[0]) : "v"(b_addr));
    asm volatile("ds_read_b128 %0, %1 offset:1024" : "=v"(bf[1]) : "v"(b_addr));
    asm volatile("ds_read_b128 %0, %1 offset:2048" : "=v"(bf[2]) : "v"(b_addr));
    asm volatile("ds_read_b128 %0, %1 offset:3072" : "=v"(bf[3]) : "v"(b_addr));
    asm volatile("ds_read_b128 %0, %1 offset:4096" : "=v"(bf[4]) : "v"(b_addr));
    asm volatile("ds_read_b128 %0, %1 offset:5120" : "=v"(bf[5]) : "v"(b_addr));
    asm volatile("ds_read_b128 %0, %1 offset:6144" : "=v"(bf[6]) : "v"(b_addr));
    asm volatile("ds_read_b128 %0, %1 offset:7168" : "=v"(bf[7]) : "v"(b_addr));
    asm volatile("s_waitcnt lgkmcnt(0)" ::: "memory");
    __builtin_amdgcn_sched_barrier(0);
#pragma unroll
    for (int mt = 0; mt < 2; ++mt)
#pragma unroll
      for (int nt = 0; nt < 8; ++nt)
        acc[mt][nt] = __builtin_amdgcn_mfma_i32_16x16x64_i8(af[mt], bf[nt], acc[mt][nt], 0, 0, 0);
  }
  const int region = qkv ? (ob >> 3) : 0;
  if (qkv) {
    Cf += (size_t)region << 22;   // region * 4M floats = 16MB
    mB += region * 128;           // weight-scale slots 1/3/5
    mOut += region * 64;          // out-stat slots 13/14/15
  }
  const float sA = fmaxf(slotMax64(mA) * preA, 1e-8f) / qmaxA;
  const float sB = fmaxf(slotMax64(mB), 1e-8f) / 127.0f;
  const float sAB = sA * sB;
  float lmax = 0.f;
#pragma unroll
  for (int mt = 0; mt < 2; ++mt) {
    const int n = nb * 128 + w * 32 + mt * 16 + quad * 4;
#pragma unroll
    for (int nt = 0; nt < 8; ++nt) {
      const int o = ob * 128 + nt * 16 + l15;     // global col
      const int oc = qkv ? (o & 1023) : o;        // col within region
      const float bv = bias[o];
#pragma unroll
      for (int r = 0; r < 4; ++r) {
        float v = sAB * (float)(acc[mt][nt][r]) + bv;
        if (relu) v = fmaxf(v, 0.f);
        Cf[(size_t)(n + r) * O + oc] = v;
        lmax = fmaxf(lmax, fabsf(v));
      }
    }
  }
  blockStatMax(lmax, mOut, sred, nb + (qkv ? (ob & 7) : ob) * gridDim.x);
}

// --------------------------- fused causal attention --------------------------
// R12 structure + R14 swizzle. grid 1024 = (b,h,pair,rowhalf); waves 0-1: hi
// tile (qt=15-p), waves 2-3: lo tile (qt=p), shared K/V staging; 4-buffer
// dist-3 counted-vmcnt pipeline; asm ds_read; reg P-transpose.
__global__ __launch_bounds__(256, 4) void attn_fused(
    const int8_t* __restrict__ Qq, const int8_t* __restrict__ Kq,
    const int8_t* __restrict__ Vt, float* __restrict__ ctx,
    const float* __restrict__ M, float* __restrict__ mOut) {
  __shared__ __align__(16) int8_t qtile[4096];
  __shared__ __align__(16) int8_t ktile[4][4096];
  __shared__ __align__(16) int8_t vtile[4][4096];
  __shared__ float sred[4];
  const int tid = threadIdx.x, bid = blockIdx.x;
  const int pidx = bid & 7, rh = (bid >> 3) & 1, h = (bid >> 4) & 15, b = bid >> 8;
  const int qthi = 15 - pidx, qtlo = pidx, ktmax = qthi;
  const int w = tid >> 6, lane = tid & 63, l15 = lane & 15, quad = lane >> 4;
  const int wqt = (w < 2) ? qthi : qtlo;
  const int wrow0 = rh * 32 + (w & 1) * 16;
  const float sqs = fmaxf(slotMax64(M + 13 * 64) * 0.125f, 1e-8f) / 127.0f;
  const float sk = fmaxf(slotMax64(M + 14 * 64), 1e-8f) / 127.0f;
  const float sv = fmaxf(slotMax64(M + 15 * 64), 1e-8f) / 127.0f;
  const float sqk = sqs * sk;
  const float s_attn = 1.0f / 127.0f;  // softmax global max == 1.0 exactly
  const int r0 = tid >> 2;
  const int c0 = (((tid & 3) ^ ((tid >> 2) & 3)) * 16);  // swizzled source col
  const int8_t* Kbase = Kq + (size_t)(b * 1024) * 1024 + h * 64 + c0;
  const int8_t* Vbase = Vt + (size_t)((b * 16 + h) * 64 + r0) * 1024 + c0;
  const unsigned fragoff = (unsigned)(l15 * 64 + (quad ^ (l15 & 3)) * 16);

  // ---- Phase A prologue: stage Q (1 item) + K tiles 0..2 (3 items) ----
  {
    const int qt_s = (r0 < 32) ? qthi : qtlo;
    const int qrow_g = qt_s * 64 + rh * 32 + (r0 & 31);
    gll16(Qq + ((size_t)(b * 1024 + qrow_g)) * 1024 + h * 64 + c0, qtile + tid * 16);
  }
#pragma unroll
  for (int t = 0; t < 3; ++t)
    gll16(Kbase + (size_t)(t * 64 + r0) * 1024, ktile[t] + tid * 16);
  asm volatile("s_waitcnt vmcnt(3)" ::: "memory");  // my Q landed
  asm volatile("s_barrier" ::: "memory");           // all waves' Q landed
  i32x4 aq;
  {
    const unsigned qa = ldsaddr(qtile) +
        (unsigned)((w * 16 + l15) * 64 + (quad ^ (l15 & 3)) * 16);
    asm volatile("ds_read_b128 %0, %1 offset:0" : "=v"(aq) : "v"(qa));
    asm volatile("s_waitcnt lgkmcnt(0)" ::: "memory");
  }
  const int qrow = wqt * 64 + wrow0 + l15;  // this lane's q-row (0..1023)

  // ---- Phase A: swapped QK^T; per-lane online (m,l); pipelined K staging ----
  float m_l = -1e30f, l_l = 0.f;
  for (int kt = 0; kt <= ktmax; ++kt) {
    if (kt + 2 <= ktmax)      asm volatile("s_waitcnt vmcnt(2)" ::: "memory");
    else if (kt + 1 <= ktmax) asm volatile("s_waitcnt vmcnt(1)" ::: "memory");
    else                      asm volatile("s_waitcnt vmcnt(0)" ::: "memory");
    asm volatile("s_barrier" ::: "memory");
    if (kt + 3 <= ktmax)
      gll16(Kbase + (size_t)((kt + 3) * 64 + r0) * 1024, ktile[(kt + 3) & 3] + tid * 16);
    if (kt <= wqt) {
      const unsigned ka = ldsaddr(ktile[kt & 3]) + fragoff;
      i32x4 bk[4];
      asm volatile("ds_read_b128 %0, %1 offset:0"    : "=v"(bk[0]) : "v"(ka));
      asm volatile("ds_read_b128 %0, %1 offset:1024" : "=v"(bk[1]) : "v"(ka));
      asm volatile("ds_read_b128 %0, %1 offset:2048" : "=v"(bk[2]) : "v"(ka));
      asm volatile("ds_read_b128 %0, %1 offset:3072" : "=v"(bk[3]) : "v"(ka));
      asm volatile("s_waitcnt lgkmcnt(0)" ::: "memory");
      __builtin_amdgcn_sched_barrier(0);
      const int kc0 = kt * 64 + quad * 4;
      float sc[4][4];
#pragma unroll
      for (int nt = 0; nt < 4; ++nt) {
        i32x4 z = {0, 0, 0, 0};
        i32x4 d = __builtin_amdgcn_mfma_i32_16x16x64_i8(bk[nt], aq, z, 0, 0, 0);
        if (kt == wqt) {
#pragma unroll
          for (int r = 0; r < 4; ++r)
            sc[nt][r] = (kc0 + nt * 16 + r <= qrow) ? sqk * (float)d[r] : -1e30f;
        } else {
#pragma unroll
          for (int r = 0; r < 4; ++r) sc[nt][r] = sqk * (float)d[r];
        }
      }
      float vm = sc[0][0];
#pragma unroll
      for (int nt = 0; nt < 4; ++nt)
#pragma unroll
        for (int r = 0; r < 4; ++r) vm = fmaxf(vm, sc[nt][r]);
      const float mn = fmaxf(m_l, vm);
      float sum = 0.f;
#pragma unroll
      for (int nt = 0; nt < 4; ++nt)
#pragma unroll
        for (int r = 0; r < 4; ++r) sum += __expf(sc[nt][r] - mn);
      l_l = l_l * __expf(m_l - mn) + sum;
      m_l = mn;
    }
  }
  // merge the 4 quads (lanes sharing l15 hold the same q-row)
#pragma unroll
  for (int off = 16; off <= 32; off <<= 1) {
    float om = __shfl_xor(m_l, off, 64);
    float ol = __shfl_xor(l_l, off, 64);
    float mn = fmaxf(m_l, om);
    l_l = l_l * __expf(m_l - mn) + ol * __expf(om - mn);
    m_l = mn;
  }
  const float rl127 = 127.0f / l_l;  // P*127 in [0,127] exactly -> no clamps

  // ---- Phase B: recompute, quantize P in-register, quad-transpose, PV ----
  __syncthreads();  // all waves done reading Phase-A buffers (vmcnt already 0)
#pragma unroll
  for (int t = 0; t < 3; ++t) {
    gll16(Kbase + (size_t)(t * 64 + r0) * 1024, ktile[t] + tid * 16);
    gll16(Vbase + t * 64, vtile[t] + tid * 16);
  }
  i32x4 cacc[4] = {{0, 0, 0, 0}, {0, 0, 0, 0}, {0, 0, 0, 0}, {0, 0, 0, 0}};
  for (int kt = 0; kt <= ktmax; ++kt) {
    if (kt + 2 <= ktmax)      asm volatile("s_waitcnt vmcnt(4)" ::: "memory");
    else if (kt + 1 <= ktmax) asm volatile("s_waitcnt vmcnt(2)" ::: "memory");
    else                      asm volatile("s_waitcnt vmcnt(0)" ::: "memory");
    asm volatile("s_barrier" ::: "memory");
    if (kt + 3 <= ktmax) {
      gll16(Kbase + (size_t)((kt + 3) * 64 + r0) * 1024, ktile[(kt + 3) & 3] + tid * 16);
      gll16(Vbase + (kt + 3) * 64, vtile[(kt + 3) & 3] + tid * 16);
    }
    if (kt <= wqt) {
      const unsigned ka = ldsaddr(ktile[kt & 3]) + fragoff;
      const unsigned va = ldsaddr(vtile[kt & 3]) + fragoff;
      i32x4 bk[4], bv[4];
      asm volatile("ds_read_b128 %0, %1 offset:0"    : "=v"(bk[0]) : "v"(ka));
      asm volatile("ds_read_b128 %0, %1 offset:1024" : "=v"(bk[1]) : "v"(ka));
      asm volatile("ds_read_b128 %0, %1 offset:2048" : "=v"(bk[2]) : "v"(ka));
      asm volatile("ds_read_b128 %0, %1 offset:3072" : "=v"(bk[3]) : "v"(ka));
      asm volatile("ds_read_b128 %0, %1 offset:0"    : "=v"(bv[0]) : "v"(va));
      asm volatile("ds_read_b128 %0, %1 offset:1024" : "=v"(bv[1]) : "v"(va));
      asm volatile("ds_read_b128 %0, %1 offset:2048" : "=v"(bv[2]) : "v"(va));
      asm volatile("ds_read_b128 %0, %1 offset:3072" : "=v"(bv[3]) : "v"(va));
      asm volatile("s_waitcnt lgkmcnt(0)" ::: "memory");
      __builtin_amdgcn_sched_barrier(0);
      const int kc0 = kt * 64 + quad * 4;
      unsigned Dw[4];
#pragma unroll
      for (int nt = 0; nt < 4; ++nt) {
        i32x4 z = {0, 0, 0, 0};
        i32x4 d = __builtin_amdgcn_mfma_i32_16x16x64_i8(bk[nt], aq, z, 0, 0, 0);
        unsigned wd = 0;
        if (kt == wqt) {
#pragma unroll
          for (int r = 0; r < 4; ++r) {
            float e = (kc0 + nt * 16 + r <= qrow)
                          ? __expf(sqk * (float)d[r] - m_l) * rl127 : 0.f;
            wd |= ((unsigned)(int)rintf(e)) << (8 * r);
          }
        } else {
#pragma unroll
          for (int r = 0; r < 4; ++r) {
            float e = __expf(sqk * (float)d[r] - m_l) * rl127;
            wd |= ((unsigned)(int)rintf(e)) << (8 * r);
          }
        }
        Dw[nt] = wd;
      }
      // 4x4 quad-transpose: pf[j] (k=quad*16+4j..) <- Dw[quad] @ lane quad'=j
      unsigned selfv = quadsel(Dw[0], Dw[1], Dw[2], Dw[3], quad);
      unsigned rv1 = (unsigned)__shfl_xor(
          (int)quadsel(Dw[0], Dw[1], Dw[2], Dw[3], quad ^ 1), 16, 64);
      unsigned rv2 = (unsigned)__shfl_xor(
          (int)quadsel(Dw[0], Dw[1], Dw[2], Dw[3], quad ^ 2), 32, 64);
      unsigned rv3 = (unsigned)__shfl_xor(
          (int)quadsel(Dw[0], Dw[1], Dw[2], Dw[3], quad ^ 3), 48, 64);
      i32x4 pf;
#pragma unroll
      for (int j = 0; j < 4; ++j) {
        const int t = j ^ quad;
        pf[j] = (int)((t == 0) ? selfv : (t == 1) ? rv1 : (t == 2) ? rv2 : rv3);
      }
#pragma unroll
      for (int nt = 0; nt < 4; ++nt)
        cacc[nt] = __builtin_amdgcn_mfma_i32_16x16x64_i8(pf, bv[nt], cacc[nt], 0, 0, 0);
    }
  }
  const float sc2 = s_attn * sv;
  float lmax = 0.f;
  const int orow0 = wqt * 64 + wrow0 + quad * 4;
#pragma unroll
  for (int nt = 0; nt < 4; ++nt) {
    const int d = nt * 16 + l15;
#pragma unroll
    for (int r = 0; r < 4; ++r) {
      float v = sc2 * (float)cacc[nt][r];
      ctx[((size_t)(b * 1024 + orow0 + r)) * 1024 + h * 64 + d] = v;
      lmax = fmaxf(lmax, fabsf(v));
    }
  }
  blockStatMax(lmax, mOut, sred, bid);
}

// --------------------------- residual + layernorm ---------------------------
__global__ __launch_bounds__(256) void ln_res(
    const int8_t* __restrict__ xq, const float* __restrict__ mx,
    const float* __restrict__ ao, const float* __restrict__ ma,
    float* __restrict__ x1, float* __restrict__ mOut) {
  __shared__ float red[8];
  __shared__ float sred[4];
  const int row = blockIdx.x, tid = threadIdx.x;
  const float sx = fmaxf(slotMax64(mx), 1e-8f) / 127.0f;
  const float sa = fmaxf(slotMax64(ma), 1e-8f) / 127.0f;
  char4 xv = *(const char4*)(xq + (size_t)row * 1024 + tid * 4);
  f32x4 av = *(const f32x4*)(ao + (size_t)row * 1024 + tid * 4);
  float t[4];
  t[0] = (float)xv.x * sx + fminf(fmaxf(rintf(av.x / sa), -128.f), 127.f) * sa;
  t[1] = (float)xv.y * sx + fminf(fmaxf(rintf(av.y / sa), -128.f), 127.f) * sa;
  t[2] = (float)xv.z * sx + fminf(fmaxf(rintf(av.z / sa), -128.f), 127.f) * sa;
  t[3] = (float)xv.w * sx + fminf(fmaxf(rintf(av.w / sa), -128.f), 127.f) * sa;
  float s = waveSum(t[0] + t[1] + t[2] + t[3]);
  if ((tid & 63) == 0) red[tid >> 6] = s;
  __syncthreads();
  const float mean = (red[0] + red[1] + red[2] + red[3]) * (1.0f / 1024.0f);
  float vs = 0.f;
#pragma unroll
  for (int i = 0; i < 4; ++i) { float d = t[i] - mean; vs += d * d; }
  vs = waveSum(vs);
  if ((tid & 63) == 0) red[4 + (tid >> 6)] = vs;
  __syncthreads();
  const float var = (red[4] + red[5] + red[6] + red[7]) * (1.0f / 1024.0f);
  const float rs = sqrtf(var + 1e-5f);
  f32x4 o;
  o.x = (t[0] - mean) / rs;
  o.y = (t[1] - mean) / rs;
  o.z = (t[2] - mean) / rs;
  o.w = (t[3] - mean) / rs;
  *(f32x4*)(x1 + (size_t)row * 1024 + tid * 4) = o;
  float lmax = fmaxf(fmaxf(fabsf(o.x), fabsf(o.y)), fmaxf(fabsf(o.z), fabsf(o.w)));
  blockStatMax(lmax, mOut, sred, row);
}

__global__ __launch_bounds__(256) void ln_final(
    const int8_t* __restrict__ x1q, const float* __restrict__ mx1,
    const float* __restrict__ h2, const float* __restrict__ mh2,
    float* __restrict__ out) {
  __shared__ float red[8];
  const int row = blockIdx.x, tid = threadIdx.x;
  const float s1 = fmaxf(slotMax64(mx1), 1e-8f) / 127.0f;
  const float s2 = fmaxf(slotMax64(mh2), 1e-8f) / 127.0f;
  char4 xv = *(const char4*)(x1q + (size_t)row * 1024 + tid * 4);
  f32x4 hv = *(const f32x4*)(h2 + (size_t)row * 1024 + tid * 4);
  float t[4];
  t[0] = (float)xv.x * s1 + fminf(fmaxf(rintf(hv.x / s2), -128.f), 127.f) * s2;
  t[1] = (float)xv.y * s1 + fminf(fmaxf(rintf(hv.y / s2), -128.f), 127.f) * s2;
  t[2] = (float)xv.z * s1 + fminf(fmaxf(rintf(hv.z / s2), -128.f), 127.f) * s2;
  t[3] = (float)xv.w * s1 + fminf(fmaxf(rintf(hv.w / s2), -128.f), 127.f) * s2;
  float s = waveSum(t[0] + t[1] + t[2] + t[3]);
  if ((tid & 63) == 0) red[tid >> 6] = s;
  __syncthreads();
  const float mean = (red[0] + red[1] + red[2] + red[3]) * (1.0f / 1024.0f);
  float vs = 0.f;
#pragma unroll
  for (int i = 0; i < 4; ++i) { float d = t[i] - mean; vs += d * d; }
  vs = waveSum(vs);
  if ((tid & 63) == 0) red[4 + (tid >> 6)] = vs;
  __syncthreads();
  const float var = (red[4] + red[5] + red[6] + red[7]) * (1.0f / 1024.0f);
  const float rs = sqrtf(var + 1e-5f);
  f32x4 o;
  o.x = (t[0] - mean) / rs;
  o.y = (t[1] - mean) / rs;
  o.z = (t[2] - mean) / rs;
  o.w = (t[3] - mean) / rs;
  *(f32x4*)(out + (size_t)row * 1024 + tid * 4) = o;
}

// --------------------------- workspace layout --------------------------------
static constexpr size_t MB = 1u << 20;
static constexpr size_t OFF_M     = 0;          // 21 stats x 64 f32 slots
static constexpr size_t OFF_FLAG  = 6400;
static constexpr size_t OFF_BIASQ = 8192;
static constexpr size_t OFF_BIASK = OFF_BIASQ + 4096;
static constexpr size_t OFF_BIASV = OFF_BIASK + 4096;
static constexpr size_t OFF_BIASO = OFF_BIASV + 4096;
static constexpr size_t OFF_BIAS1 = OFF_BIASO + 4096;
static constexpr size_t OFF_BIAS2 = OFF_BIAS1 + 16384;
static constexpr size_t OFF_RS    = OFF_BIAS2 + 4096;
static constexpr size_t OFF_XQ    = 65536;
static constexpr size_t OFF_WQQ   = OFF_XQ  + 4 * MB;
static constexpr size_t OFF_WKQ   = OFF_WQQ + 1 * MB;
static constexpr size_t OFF_WVQ   = OFF_WKQ + 1 * MB;
static constexpr size_t OFF_WOQ   = OFF_WVQ + 1 * MB;
static constexpr size_t OFF_W1Q   = OFF_WOQ + 1 * MB;
static constexpr size_t OFF_W2Q   = OFF_W1Q + 4 * MB;
static constexpr size_t OFF_X1Q   = OFF_W2Q + 4 * MB;
static constexpr size_t OFF_A1    = OFF_X1Q + 4 * MB;     // arena1, 16 MB
static constexpr size_t OFF_A2    = OFF_A1 + 16 * MB;     // arena2 (f32), 16 MB
static constexpr size_t OFF_HF    = OFF_A2 + 16 * MB;     // optional 64 MB f32

extern "C" void kernel_launch(void* const* d_in, const int* in_sizes, int n_in,
                              void* d_out, int out_size, void* d_ws, size_t ws_size,
                              hipStream_t stream) {
  (void)n_in; (void)out_size;
  char* ws = (char*)d_ws;
  float* M = (float*)(ws + OFF_M);
  int* FLAG = (int*)(ws + OFF_FLAG);
  float* BIASQ = (float*)(ws + OFF_BIASQ);
  float* BIASK = (float*)(ws + OFF_BIASK);
  float* BIASV = (float*)(ws + OFF_BIASV);
  float* BIASO = (float*)(ws + OFF_BIASO);
  float* BIAS1 = (float*)(ws + OFF_BIAS1);
  float* BIAS2 = (float*)(ws + OFF_BIAS2);
  int* RS = (int*)(ws + OFF_RS);
  int8_t* XQ  = (int8_t*)(ws + OFF_XQ);
  int8_t* WQQ = (int8_t*)(ws + OFF_WQQ);
  int8_t* WKQ = (int8_t*)(ws + OFF_WKQ);
  int8_t* WVQ = (int8_t*)(ws + OFF_WVQ);
  int8_t* WOQ = (int8_t*)(ws + OFF_WOQ);
  int8_t* W1Q = (int8_t*)(ws + OFF_W1Q);
  int8_t* W2Q = (int8_t*)(ws + OFF_W2Q);
  int8_t* X1Q = (int8_t*)(ws + OFF_X1Q);
  int8_t* QQ   = (int8_t*)(ws + OFF_A1);
  int8_t* KQQ  = (int8_t*)(ws + OFF_A1 + 4 * MB);
  int8_t* VT   = (int8_t*)(ws + OFF_A1 + 8 * MB);
  int8_t* CTXQ = (int8_t*)(ws + OFF_A1 + 12 * MB);
  float*  X1F  = (float*)(ws + OFF_A1);
  int8_t* HQ   = (int8_t*)(ws + OFF_A1);
  float* FBUF = (float*)(ws + OFF_A2);   // serial reuse: QF/KF/VF/ctx/ao/h2
  const bool bigws = ws_size >= OFF_HF + 64 * MB;

  hipMemsetAsync(M, 0, 8192, stream);
  detect_f32<<<1, 64, 0, stream>>>((const u16*)d_in[0], FLAG);

  AJobs aj;
  const int ablk[13] = {512, 128, 1, 128, 1, 128, 1, 128, 1, 512, 2, 512, 1};
  int bs = 0;
  for (int i = 0; i < 13; ++i) {
    aj.p[i] = d_in[i];
    aj.n4[i] = in_sizes[i] / 4;
    aj.bstart[i] = bs;
    bs += ablk[i];
  }
  aj.bstart[13] = bs;
  absmax_multi<<<bs, 256, 0, stream>>>(aj, M, FLAG);

  quant_in_signed<<<1024, 256, 0, stream>>>(d_in[0], XQ, M + 0 * 64, FLAG, in_sizes[0] / 4);

  WJobs wj;
  const int widx[5] = {1, 3, 5, 7, 9};
  int8_t* wout[5] = {WQQ, WKQ, WVQ, WOQ, W1Q};
  const int wblk[5] = {128, 128, 128, 128, 512};
  int wb = 0;
  for (int j = 0; j < 5; ++j) {
    wj.in[j] = d_in[widx[j]];
    wj.out[j] = wout[j];
    wj.mslot[j] = widx[j];
    wj.n4[j] = in_sizes[widx[j]] / 4;
    wj.bstart[j] = wb;
    wb += wblk[j];
  }
  wj.bstart[5] = wb;
  quant_w_multi<<<wb, 256, 0, stream>>>(wj, M, FLAG);
  quant_w2_rs<<<1024, 256, 0, stream>>>(d_in[11], W2Q, M + 11 * 64, FLAG, RS);

  BJobs bj;
  const int bidx[6] = {2, 4, 6, 8, 10, 12};
  float* bout[6] = {BIASQ, BIASK, BIASV, BIASO, BIAS1, BIAS2};
  for (int j = 0; j < 6; ++j) {
    bj.in[j] = d_in[bidx[j]];
    bj.out[j] = bout[j];
    bj.mslot[j] = bidx[j];
    bj.n4[j] = in_sizes[bidx[j]] / 4;
  }
  fq_bias_multi<<<6, 256, 0, stream>>>(bj, M, FLAG);

  if (bigws) {
    // Fused Q/K/V projection (128x128 tiles): one dispatch, B = [WQ;WK;WV],
    // outputs to HF + region*16MB (48MB of the 64MB scratch).
    float* HF = (float*)(ws + OFF_HF);
    gemm_i8_128<<<dim3(32, 24), 256, 0, stream>>>(XQ, WQQ, HF, M + 0 * 64, 1.f, 127.f, M + 1 * 64, BIASQ, 0, 1, M + 13 * 64, 1024, 1024);
    quant_f32_signed<<<2048, 256, 0, stream>>>(HF, QQ, M + 13 * 64, 0.125f, 1024 * 1024);
    quant_f32_signed<<<2048, 256, 0, stream>>>(HF + (1u << 22), KQQ, M + 14 * 64, 1.0f, 1024 * 1024);
    quant_v_t<<<dim3(64, 16), 256, 0, stream>>>(HF + (2u << 22), VT, M + 15 * 64);
  } else {
    gemm_i8<<<dim3(32, 16), 256, 0, stream>>>(XQ, WQQ, FBUF, nullptr, M + 0 * 64, 1.f, 127.f, M + 1 * 64, BIASQ, nullptr, 0, 0, M + 13 * 64, 1024, 1024);
    quant_f32_signed<<<2048, 256, 0, stream>>>(FBUF, QQ, M + 13 * 64, 0.125f, 1024 * 1024);
    gemm_i8<<<dim3(32, 16), 256, 0, stream>>>(XQ, WKQ, FBUF, nullptr, M + 0 * 64, 1.f, 127.f, M + 3 * 64, BIASK, nullptr, 0, 0, M + 14 * 64, 1024, 1024);
    quant_f32_signed<<<2048, 256, 0, stream>>>(FBUF, KQQ, M + 14 * 64, 1.0f, 1024 * 1024);
    gemm_i8<<<dim3(32, 16), 256, 0, stream>>>(XQ, WVQ, FBUF, nullptr, M + 0 * 64, 1.f, 127.f, M + 5 * 64, BIASV, nullptr, 0, 0, M + 15 * 64, 1024, 1024);
    quant_v_t<<<dim3(64, 16), 256, 0, stream>>>(FBUF, VT, M + 15 * 64);
  }

  attn_fused<<<1024, 256, 0, stream>>>(QQ, KQQ, VT, FBUF, M, M + 16 * 64);
  quant_f32_signed<<<2048, 256, 0, stream>>>(FBUF, CTXQ, M + 16 * 64, 1.0f, 1024 * 1024);

  gemm_i8<<<dim3(32, 16), 256, 0, stream>>>(CTXQ, WOQ, FBUF, nullptr, M + 16 * 64, 1.f, 127.f, M + 7 * 64, BIASO, nullptr, 0, 0, M + 17 * 64, 1024, 1024);

  ln_res<<<4096, 256, 0, stream>>>(XQ, M + 0 * 64, FBUF, M + 17 * 64, X1F, M + 18 * 64);
  quant_f32_signed<<<2048, 256, 0, stream>>>(X1F, X1Q, M + 18 * 64, 1.0f, 1024 * 1024);

  if (bigws) {
    // MLP1 once (128x128 tiles): mode-0 f32 h + stats, then exact u8 requant.
    float* HF = (float*)(ws + OFF_HF);
    gemm_i8_128<<<dim3(32, 32), 256, 0, stream>>>(X1Q, W1Q, HF, M + 18 * 64, 1.f, 127.f, M + 9 * 64, BIAS1, 1, 0, M + 19 * 64, 1024, 4096);
    quant_f32_u8<<<2048, 256, 0, stream>>>(HF, HQ, M + 19 * 64, 4096 * 1024);
  } else {
    gemm_i8<<<dim3(32, 64), 256, 0, stream>>>(X1Q, W1Q, nullptr, nullptr, M + 18 * 64, 1.f, 127.f, M + 9 * 64, BIAS1, nullptr, 1, 1, M + 19 * 64, 1024, 4096);
    gemm_i8<<<dim3(32, 64), 256, 0, stream>>>(X1Q, W1Q, nullptr, HQ,      M + 18 * 64, 1.f, 127.f, M + 9 * 64, BIAS1, nullptr, 1, 2, M + 19 * 64, 1024, 4096);
  }

  gemm_i8<<<dim3(32, 16), 256, 0, stream>>>(HQ, W2Q, FBUF, nullptr, M + 19 * 64, 1.f, 255.f, M + 11 * 64, BIAS2, RS, 0, 0, M + 20 * 64, 4096, 1024);

  ln_final<<<4096, 256, 0, stream>>>(X1Q, M + 18 * 64, FBUF, M + 20 * 64, (float*)d_out);
}